// Round 1
// baseline (313.707 us; speedup 1.0000x reference)
//
#include <hip/hip_runtime.h>
#include <stdint.h>

// Problem constants
#define Bn 4
#define Tn 2048
#define En 1024
#define Hn 16
#define HSn 64
#define BHn (Bn*Hn)   // 64
#define NRn (Bn*Tn)   // 8192

typedef __attribute__((ext_vector_type(8))) short short8;
typedef __attribute__((ext_vector_type(4))) float f32x4;
typedef __attribute__((ext_vector_type(4))) unsigned int uint4w;

__device__ __forceinline__ unsigned short f2b(float f){
  union { float f; unsigned int u; } c; c.f = f;
  unsigned int u = c.u + 0x7FFFu + ((c.u >> 16) & 1u);
  return (unsigned short)(u >> 16);
}

__device__ __forceinline__ f32x4 mfma16(short8 a, short8 b, f32x4 c){
  return __builtin_amdgcn_mfma_f32_16x16x32_bf16(a, b, c, 0, 0, 0);
}

// ---------------- kernel 0: x fp32 -> bf16 ----------------
__global__ void k_cvt_x(const float* __restrict__ x, unsigned short* __restrict__ xb){
  int i = (blockIdx.x * blockDim.x + threadIdx.x) * 8;
  float4 a = *(const float4*)(x + i);
  float4 b = *(const float4*)(x + i + 4);
  alignas(16) unsigned short o[8] = {f2b(a.x),f2b(a.y),f2b(a.z),f2b(a.w),
                                     f2b(b.x),f2b(b.y),f2b(b.z),f2b(b.w)};
  *(uint4w*)(xb + i) = *(const uint4w*)o;
}

// ---------------- kernel 1: QKV projection GEMM ----------------
// C(8192 x 3072) = xb(8192x1024) @ [Wq|Wk|Wv]; output scattered to (B,H,T,64) bf16.
// 128x128 tile, BK=32, 4 waves (2x2), each wave 64x64 = 4x4 16x16 frags.
__global__ void k_qkv(const unsigned short* __restrict__ xb,
                      const float* __restrict__ Wq, const float* __restrict__ Wk,
                      const float* __restrict__ Wv,
                      unsigned short* __restrict__ Qb, unsigned short* __restrict__ Kb,
                      unsigned short* __restrict__ Vb)
{
  __shared__ unsigned short As[128*40];  // padded stride 40 (2-way max conflicts)
  __shared__ unsigned short Bs[128*40];  // B^T layout: Bs[col][k]
  const int tid = threadIdx.x;
  const int lane = tid & 63, wid = tid >> 6;
  const int wr = wid >> 1, wc = wid & 1;
  const int mb = blockIdx.x, nb = blockIdx.y;
  const int n0 = nb * 128;
  const int sel = n0 >> 10;             // 0=Q 1=K 2=V (BN=128 divides 1024)
  const float* W = (sel == 0) ? Wq : (sel == 1 ? Wk : Wv);
  unsigned short* Out = (sel == 0) ? Qb : (sel == 1 ? Kb : Vb);
  const int nj0 = n0 & 1023;

  const int arow = tid >> 1;            // 0..127
  const int akh  = (tid & 1) * 16;      // 0 / 16
  const int bcol = tid & 127;           // 0..127
  const int bkh  = (tid >> 7) * 16;     // 0 / 16
  const int wh = (nj0 + bcol) >> 6;
  const int wd = (nj0 + bcol) & 63;
  const float* Wcol = W + wh * (En * HSn) + wd;   // + e*64

  f32x4 acc[4][4];
#pragma unroll
  for (int i = 0; i < 4; i++)
#pragma unroll
    for (int j = 0; j < 4; j++) acc[i][j] = (f32x4){0.f,0.f,0.f,0.f};

  const unsigned short* xrow = xb + (mb*128 + arow)*En;
  const int kofs = 8 * (lane >> 4);

  for (int k0 = 0; k0 < En; k0 += 32){
    // A stage: already bf16, straight copy
    *(uint4w*)&As[arow*40 + akh]     = *(const uint4w*)(xrow + k0 + akh);
    *(uint4w*)&As[arow*40 + akh + 8] = *(const uint4w*)(xrow + k0 + akh + 8);
    // B stage: gather fp32 weights (coalesced across lanes per kk), convert
    alignas(16) unsigned short tb[16];
#pragma unroll
    for (int kk = 0; kk < 16; kk++) tb[kk] = f2b(Wcol[(k0 + bkh + kk)*HSn]);
    *(uint4w*)&Bs[bcol*40 + bkh]     = *(const uint4w*)(tb);
    *(uint4w*)&Bs[bcol*40 + bkh + 8] = *(const uint4w*)(tb + 8);
    __syncthreads();

    short8 af[4], bf[4];
#pragma unroll
    for (int mf = 0; mf < 4; mf++)
      af[mf] = *(const short8*)&As[(wr*64 + mf*16 + (lane&15))*40 + kofs];
#pragma unroll
    for (int nf = 0; nf < 4; nf++)
      bf[nf] = *(const short8*)&Bs[(wc*64 + nf*16 + (lane&15))*40 + kofs];
#pragma unroll
    for (int mf = 0; mf < 4; mf++)
#pragma unroll
      for (int nf = 0; nf < 4; nf++)
        acc[mf][nf] = mfma16(af[mf], bf[nf], acc[mf][nf]);
    __syncthreads();
  }

  // epilogue: scatter to (B,H,T,HS) bf16
#pragma unroll
  for (int mf = 0; mf < 4; mf++){
#pragma unroll
    for (int nf = 0; nf < 4; nf++){
      int jj = nj0 + wc*64 + nf*16 + (lane & 15);
      int hh = jj >> 6, dd = jj & 63;
#pragma unroll
      for (int q = 0; q < 4; q++){
        int r = mb*128 + wr*64 + mf*16 + (lane>>4)*4 + q;
        int bb = r >> 11, tt = r & 2047;
        Out[((bb*Hn + hh)*Tn + tt)*HSn + dd] = f2b(acc[mf][nf][q]);
      }
    }
  }
}

// ---------------- kernel 2: column exp-sums ----------------
// Quirk: softmax over QUERY axis. L[s] = sum_{t>=s} exp(S[t,s]/1) with S=QK^T/32.
// Block = (bh, s-block of 64 cols); stream t-tiles from s0 to T.
__global__ void k_colsum(const unsigned short* __restrict__ Qb,
                         const unsigned short* __restrict__ Kb,
                         float* __restrict__ Linv)
{
  __shared__ unsigned short Ks[64*72];   // Ks[c][d] = K[s0+c][d] (B^T layout)
  __shared__ unsigned short Qs[64*72];
  __shared__ float red[4][64];
  const int bh = blockIdx.x, sb = blockIdx.y;
  const int s0 = sb * 64;
  const int tid = threadIdx.x, lane = tid & 63, w = tid >> 6;
  const int c = tid >> 2, part = (tid & 3) * 16;
  const int arow = w*16 + (lane & 15);
  const int kofs = 8 * (lane >> 4);

  {
    const unsigned short* kp = Kb + (bh*Tn + s0 + c)*HSn + part;
    *(uint4w*)&Ks[c*72 + part]     = *(const uint4w*)kp;
    *(uint4w*)&Ks[c*72 + part + 8] = *(const uint4w*)(kp + 8);
  }

  float Lp[4] = {0.f, 0.f, 0.f, 0.f};

  for (int t0 = s0; t0 < Tn; t0 += 64){
    const unsigned short* qp = Qb + (bh*Tn + t0 + c)*HSn + part;
    *(uint4w*)&Qs[c*72 + part]     = *(const uint4w*)qp;
    *(uint4w*)&Qs[c*72 + part + 8] = *(const uint4w*)(qp + 8);
    __syncthreads();   // covers Ks on first iteration too

    short8 a0 = *(const short8*)&Qs[arow*72 + kofs];
    short8 a1 = *(const short8*)&Qs[arow*72 + 32 + kofs];
    const int trow = t0 + w*16 + ((lane>>4)<<2);
#pragma unroll
    for (int cf = 0; cf < 4; cf++){
      short8 b0 = *(const short8*)&Ks[(cf*16 + (lane&15))*72 + kofs];
      short8 b1 = *(const short8*)&Ks[(cf*16 + (lane&15))*72 + 32 + kofs];
      f32x4 s = (f32x4){0.f,0.f,0.f,0.f};
      s = mfma16(a0, b0, s);
      s = mfma16(a1, b1, s);
      const int scol = s0 + cf*16 + (lane & 15);
#pragma unroll
      for (int q = 0; q < 4; q++){
        if (trow + q >= scol) Lp[cf] += __expf(s[q] * 0.03125f);
      }
    }
    __syncthreads();
  }

#pragma unroll
  for (int cf = 0; cf < 4; cf++){
    float v = Lp[cf];
    v += __shfl_xor(v, 16);
    v += __shfl_xor(v, 32);
    if (lane < 16) red[w][cf*16 + lane] = v;
  }
  __syncthreads();
  if (tid < 64){
    float tot = red[0][tid] + red[1][tid] + red[2][tid] + red[3][tid];
    Linv[bh*Tn + s0 + tid] = 1.0f / tot;
  }
}

// ---------------- kernel 3: attention output ----------------
// Block = (bh, t-block of 64 queries). out[t] = sum_{s<=t} exp(S[t,s])*Linv[s]*V[s].
__global__ void k_attn(const unsigned short* __restrict__ Qb,
                       const unsigned short* __restrict__ Kb,
                       const unsigned short* __restrict__ Vb,
                       const float* __restrict__ Linv,
                       unsigned short* __restrict__ Att)
{
  __shared__ unsigned short Ks[64*72];   // Ks[c][d]
  __shared__ unsigned short Vts[64*72];  // Vts[d][s_local] (transposed for B-frags)
  __shared__ unsigned short Ps[64*72];   // Q (once), then P tiles
  const int bh = blockIdx.x, tb = blockIdx.y;
  const int t0 = tb * 64;
  const int tid = threadIdx.x, lane = tid & 63, w = tid >> 6;
  const int c = tid >> 2, part = (tid & 3) * 16;
  const int arow = w*16 + (lane & 15);
  const int kofs = 8 * (lane >> 4);

  // stage Q through Ps, capture A-frags in regs
  {
    const unsigned short* qp = Qb + (bh*Tn + t0 + c)*HSn + part;
    *(uint4w*)&Ps[c*72 + part]     = *(const uint4w*)qp;
    *(uint4w*)&Ps[c*72 + part + 8] = *(const uint4w*)(qp + 8);
  }
  __syncthreads();
  short8 qa0 = *(const short8*)&Ps[arow*72 + kofs];
  short8 qa1 = *(const short8*)&Ps[arow*72 + 32 + kofs];

  f32x4 oacc[4];
#pragma unroll
  for (int i = 0; i < 4; i++) oacc[i] = (f32x4){0.f,0.f,0.f,0.f};

  const int trow = t0 + w*16 + ((lane>>4)<<2);

  for (int s0 = 0; s0 <= t0; s0 += 64){
    // stage K (row-major) and V (transposed)
    const unsigned short* kp = Kb + (bh*Tn + s0 + c)*HSn + part;
    uint4w kv0 = *(const uint4w*)kp;
    uint4w kv1 = *(const uint4w*)(kp + 8);
    const unsigned short* vp = Vb + (bh*Tn + s0 + c)*HSn + part;
    uint4w vv0 = *(const uint4w*)vp;
    uint4w vv1 = *(const uint4w*)(vp + 8);
    *(uint4w*)&Ks[c*72 + part]     = kv0;
    *(uint4w*)&Ks[c*72 + part + 8] = kv1;
    alignas(16) unsigned short vt[16];
    *(uint4w*)vt = vv0; *(uint4w*)(vt + 8) = vv1;
#pragma unroll
    for (int i = 0; i < 16; i++) Vts[(part + i)*72 + c] = vt[i];
    __syncthreads();

    // S = Q K^T
    f32x4 sfr[4];
#pragma unroll
    for (int cf = 0; cf < 4; cf++){
      short8 b0 = *(const short8*)&Ks[(cf*16 + (lane&15))*72 + kofs];
      short8 b1 = *(const short8*)&Ks[(cf*16 + (lane&15))*72 + 32 + kofs];
      f32x4 s = (f32x4){0.f,0.f,0.f,0.f};
      s = mfma16(qa0, b0, s);
      s = mfma16(qa1, b1, s);
      sfr[cf] = s;
    }
    // P = exp(S/32) * Linv[s], causal mask t>=s; write bf16 to Ps (wave-private rows)
#pragma unroll
    for (int cf = 0; cf < 4; cf++){
      const int scol = s0 + cf*16 + (lane & 15);
      const float inv = Linv[bh*Tn + scol];
#pragma unroll
      for (int q = 0; q < 4; q++){
        float p = (trow + q >= scol) ? __expf(sfr[cf][q] * 0.03125f) * inv : 0.f;
        Ps[(w*16 + (lane>>4)*4 + q)*72 + cf*16 + (lane & 15)] = f2b(p);
      }
    }
    __syncthreads();

    // PV: A = P (t x s), B = V (s x d) via Vts
    short8 pa0 = *(const short8*)&Ps[arow*72 + kofs];
    short8 pa1 = *(const short8*)&Ps[arow*72 + 32 + kofs];
#pragma unroll
    for (int cf = 0; cf < 4; cf++){
      short8 vb0 = *(const short8*)&Vts[(cf*16 + (lane&15))*72 + kofs];
      short8 vb1 = *(const short8*)&Vts[(cf*16 + (lane&15))*72 + 32 + kofs];
      oacc[cf] = mfma16(pa0, vb0, oacc[cf]);
      oacc[cf] = mfma16(pa1, vb1, oacc[cf]);
    }
    __syncthreads();
  }

  // store att tile (B,H,T,HS) bf16
#pragma unroll
  for (int cf = 0; cf < 4; cf++){
#pragma unroll
    for (int q = 0; q < 4; q++){
      int t = t0 + w*16 + (lane>>4)*4 + q;
      Att[(bh*Tn + t)*HSn + cf*16 + (lane & 15)] = f2b(oacc[cf][q]);
    }
  }
}

// ---------------- kernel 4: output projection ----------------
// out(8192x1024) = att_concat @ Wo + bo, fp32 out.
__global__ void k_oproj(const unsigned short* __restrict__ Att,
                        const float* __restrict__ Wo, const float* __restrict__ bo,
                        float* __restrict__ out)
{
  __shared__ unsigned short As[128*40];
  __shared__ unsigned short Bs[128*40];
  const int tid = threadIdx.x, lane = tid & 63, wid = tid >> 6;
  const int wr = wid >> 1, wc = wid & 1;
  const int mb = blockIdx.x, nb = blockIdx.y;
  const int n0 = nb * 128;
  const int arow = tid >> 1, akh = (tid & 1) * 16;
  const int bcol = tid & 127, bkh = (tid >> 7) * 16;
  const int r = mb*128 + arow;
  const int bb = r >> 11, tt = r & 2047;
  const int kofs = 8 * (lane >> 4);

  f32x4 acc[4][4];
#pragma unroll
  for (int i = 0; i < 4; i++)
#pragma unroll
    for (int j = 0; j < 4; j++) acc[i][j] = (f32x4){0.f,0.f,0.f,0.f};

  for (int k0 = 0; k0 < En; k0 += 32){
    int e0 = k0 + akh;
    int hh = e0 >> 6, d0 = e0 & 63;   // 16-chunk stays within one head
    const unsigned short* ap = Att + ((bb*Hn + hh)*Tn + tt)*HSn + d0;
    *(uint4w*)&As[arow*40 + akh]     = *(const uint4w*)ap;
    *(uint4w*)&As[arow*40 + akh + 8] = *(const uint4w*)(ap + 8);
    alignas(16) unsigned short tb[16];
#pragma unroll
    for (int kk = 0; kk < 16; kk++) tb[kk] = f2b(Wo[(k0 + bkh + kk)*En + n0 + bcol]);
    *(uint4w*)&Bs[bcol*40 + bkh]     = *(const uint4w*)(tb);
    *(uint4w*)&Bs[bcol*40 + bkh + 8] = *(const uint4w*)(tb + 8);
    __syncthreads();

    short8 af[4], bf[4];
#pragma unroll
    for (int mf = 0; mf < 4; mf++)
      af[mf] = *(const short8*)&As[(wr*64 + mf*16 + (lane&15))*40 + kofs];
#pragma unroll
    for (int nf = 0; nf < 4; nf++)
      bf[nf] = *(const short8*)&Bs[(wc*64 + nf*16 + (lane&15))*40 + kofs];
#pragma unroll
    for (int mf = 0; mf < 4; mf++)
#pragma unroll
      for (int nf = 0; nf < 4; nf++)
        acc[mf][nf] = mfma16(af[mf], bf[nf], acc[mf][nf]);
    __syncthreads();
  }

#pragma unroll
  for (int nf = 0; nf < 4; nf++){
    int j = n0 + wc*64 + nf*16 + (lane & 15);
    float bias = bo[j];
#pragma unroll
    for (int mf = 0; mf < 4; mf++){
#pragma unroll
      for (int q = 0; q < 4; q++){
        int rr = mb*128 + wr*64 + mf*16 + (lane>>4)*4 + q;
        out[rr*En + j] = acc[mf][nf][q] + bias;
      }
    }
  }
}

extern "C" void kernel_launch(void* const* d_in, const int* in_sizes, int n_in,
                              void* d_out, int out_size, void* d_ws, size_t ws_size,
                              hipStream_t stream)
{
  (void)in_sizes; (void)n_in; (void)out_size; (void)ws_size;
  const float* x  = (const float*)d_in[0];
  const float* Wq = (const float*)d_in[1];
  const float* Wk = (const float*)d_in[2];
  const float* Wv = (const float*)d_in[3];
  const float* Wo = (const float*)d_in[4];
  const float* bo = (const float*)d_in[5];
  float* out = (float*)d_out;

  // workspace layout (bytes): Qb[0,16M) Kb[16M,32M) Vb[32M,48M)
  // xb/Att alias [48M,64M) (xb dead before Att written), Linv[64M,64.5M)
  uint8_t* w = (uint8_t*)d_ws;
  unsigned short* Qb  = (unsigned short*)(w);
  unsigned short* Kb  = (unsigned short*)(w + (16u << 20));
  unsigned short* Vb  = (unsigned short*)(w + (32u << 20));
  unsigned short* xb  = (unsigned short*)(w + (48u << 20));
  unsigned short* Att = (unsigned short*)(w + (48u << 20));
  float* Linv         = (float*)(w + (64u << 20));

  hipLaunchKernelGGL(k_cvt_x,  dim3(4096),   dim3(256), 0, stream, x, xb);
  hipLaunchKernelGGL(k_qkv,    dim3(64, 24), dim3(256), 0, stream, xb, Wq, Wk, Wv, Qb, Kb, Vb);
  hipLaunchKernelGGL(k_colsum, dim3(64, 32), dim3(256), 0, stream, Qb, Kb, Linv);
  hipLaunchKernelGGL(k_attn,   dim3(64, 32), dim3(256), 0, stream, Qb, Kb, Vb, Linv, Att);
  hipLaunchKernelGGL(k_oproj,  dim3(64, 8),  dim3(256), 0, stream, Att, Wo, bo, out);
}

// Round 2
// 299.743 us; speedup vs baseline: 1.0466x; 1.0466x over previous
//
#include <hip/hip_runtime.h>
#include <stdint.h>

// Problem constants
#define Bn 4
#define Tn 2048
#define En 1024
#define Hn 16
#define HSn 64
#define BHn (Bn*Hn)   // 64
#define NRn (Bn*Tn)   // 8192

// exp(x/32) = exp2(x * 0.03125 * log2(e))
#define CEXP 0.0450840831f

typedef __attribute__((ext_vector_type(8))) short short8;
typedef __attribute__((ext_vector_type(4))) float f32x4;
typedef __attribute__((ext_vector_type(16))) float f32x16;
typedef __attribute__((ext_vector_type(4))) unsigned int uint4w;

__device__ __forceinline__ unsigned short f2b(float f){
  union { float f; unsigned int u; } c; c.f = f;
  unsigned int u = c.u + 0x7FFFu + ((c.u >> 16) & 1u);
  return (unsigned short)(u >> 16);
}
__device__ __forceinline__ float b2f(unsigned short s){
  union { unsigned int u; float f; } c; c.u = ((unsigned int)s) << 16;
  return c.f;
}
// v_cvt_pk_bf16_f32: D[15:0]=bf16(lo), D[31:16]=bf16(hi)
__device__ __forceinline__ unsigned int cvtpk(float lo, float hi){
  unsigned int r;
  asm("v_cvt_pk_bf16_f32 %0, %1, %2" : "=v"(r) : "v"(lo), "v"(hi));
  return r;
}
__device__ __forceinline__ f32x4 mfma16(short8 a, short8 b, f32x4 c){
  return __builtin_amdgcn_mfma_f32_16x16x32_bf16(a, b, c, 0, 0, 0);
}
__device__ __forceinline__ f32x16 mfma32(short8 a, short8 b, f32x16 c){
  return __builtin_amdgcn_mfma_f32_32x32x16_bf16(a, b, c, 0, 0, 0);
}
// async global->LDS, 16B per lane; lds ptr must be wave-uniform (HW adds lane*16)
__device__ __forceinline__ void gl16(const void* g, void* s){
  __builtin_amdgcn_global_load_lds((const __attribute__((address_space(1))) unsigned int*)g,
                                   (__attribute__((address_space(3))) unsigned int*)s, 16, 0, 0);
}

// ---------------- kernel 0: x fp32 -> bf16 ----------------
__global__ void k_cvt_x(const float* __restrict__ x, unsigned short* __restrict__ xb){
  int i = (blockIdx.x * blockDim.x + threadIdx.x) * 8;
  float4 a = *(const float4*)(x + i);
  float4 b = *(const float4*)(x + i + 4);
  alignas(16) unsigned short o[8] = {f2b(a.x),f2b(a.y),f2b(a.z),f2b(a.w),
                                     f2b(b.x),f2b(b.y),f2b(b.z),f2b(b.w)};
  *(uint4w*)(xb + i) = *(const uint4w*)o;
}

// ---------------- kernel 1: QKV projection GEMM ----------------
// Q,K -> (B,H,T,64) bf16; V -> TRANSPOSED (B,H,64,T) bf16 (for attn PV a-frags).
__global__ void k_qkv(const unsigned short* __restrict__ xb,
                      const float* __restrict__ Wq, const float* __restrict__ Wk,
                      const float* __restrict__ Wv,
                      unsigned short* __restrict__ Qb, unsigned short* __restrict__ Kb,
                      unsigned short* __restrict__ Vt)
{
  __shared__ unsigned short As[128*40];
  __shared__ unsigned short Bs[128*40];
  const int tid = threadIdx.x;
  const int lane = tid & 63, wid = tid >> 6;
  const int wr = wid >> 1, wc = wid & 1;
  const int mb = blockIdx.x, nb = blockIdx.y;
  const int n0 = nb * 128;
  const int sel = n0 >> 10;
  const float* W = (sel == 0) ? Wq : (sel == 1 ? Wk : Wv);
  const int nj0 = n0 & 1023;

  const int arow = tid >> 1;
  const int akh  = (tid & 1) * 16;
  const int bcol = tid & 127;
  const int bkh  = (tid >> 7) * 16;
  const int wh = (nj0 + bcol) >> 6;
  const int wd = (nj0 + bcol) & 63;
  const float* Wcol = W + wh * (En * HSn) + wd;

  f32x4 acc[4][4];
#pragma unroll
  for (int i = 0; i < 4; i++)
#pragma unroll
    for (int j = 0; j < 4; j++) acc[i][j] = (f32x4){0.f,0.f,0.f,0.f};

  const unsigned short* xrow = xb + (mb*128 + arow)*En;
  const int kofs = 8 * (lane >> 4);

  for (int k0 = 0; k0 < En; k0 += 32){
    *(uint4w*)&As[arow*40 + akh]     = *(const uint4w*)(xrow + k0 + akh);
    *(uint4w*)&As[arow*40 + akh + 8] = *(const uint4w*)(xrow + k0 + akh + 8);
    alignas(16) unsigned short tb[16];
#pragma unroll
    for (int kk = 0; kk < 16; kk++) tb[kk] = f2b(Wcol[(k0 + bkh + kk)*HSn]);
    *(uint4w*)&Bs[bcol*40 + bkh]     = *(const uint4w*)(tb);
    *(uint4w*)&Bs[bcol*40 + bkh + 8] = *(const uint4w*)(tb + 8);
    __syncthreads();

    short8 af[4], bf[4];
#pragma unroll
    for (int mf = 0; mf < 4; mf++)
      af[mf] = *(const short8*)&As[(wr*64 + mf*16 + (lane&15))*40 + kofs];
#pragma unroll
    for (int nf = 0; nf < 4; nf++)
      bf[nf] = *(const short8*)&Bs[(wc*64 + nf*16 + (lane&15))*40 + kofs];
#pragma unroll
    for (int mf = 0; mf < 4; mf++)
#pragma unroll
      for (int nf = 0; nf < 4; nf++)
        acc[mf][nf] = mfma16(af[mf], bf[nf], acc[mf][nf]);
    __syncthreads();
  }

#pragma unroll
  for (int mf = 0; mf < 4; mf++){
#pragma unroll
    for (int nf = 0; nf < 4; nf++){
      int jj = nj0 + wc*64 + nf*16 + (lane & 15);
      int hh = jj >> 6, dd = jj & 63;
#pragma unroll
      for (int q = 0; q < 4; q++){
        int r = mb*128 + wr*64 + mf*16 + (lane>>4)*4 + q;
        int bb = r >> 11, tt = r & 2047;
        if (sel == 2)
          Vt[((bb*Hn + hh)*HSn + dd)*Tn + tt] = f2b(acc[mf][nf][q]);
        else if (sel == 1)
          Kb[((bb*Hn + hh)*Tn + tt)*HSn + dd] = f2b(acc[mf][nf][q]);
        else
          Qb[((bb*Hn + hh)*Tn + tt)*HSn + dd] = f2b(acc[mf][nf][q]);
      }
    }
  }
}

// ---------------- kernel 2: column exp-sums (softmax over QUERY axis) ----------
// L[s] = sum_{t>=s} exp(S[t,s]*1/32). Swapped 32x32 MFMA: St[s][t], col=t.
// Block (bh, pair i): s-blocks {64*i, 64*(31-i)}. K-frags hoisted; Q streamed.
__global__ void k_colsum(const unsigned short* __restrict__ Qb,
                         const unsigned short* __restrict__ Kb,
                         float* __restrict__ Linv)
{
  __shared__ unsigned short Qs[2][128*64];  // 16KB each, swizzled chunk^=(row&7)
  __shared__ float Lred[64];
  const int bh = blockIdx.x, ipair = blockIdx.y;
  const int tid = threadIdx.x, lane = tid & 63, w = tid >> 6;
  const int l5 = lane >> 5, l31 = lane & 31;

  for (int ph = 0; ph < 2; ph++){
    const int sb = ph ? (31 - ipair) : ipair;
    const int s0 = sb * 64;

    // hoist K a-frags (A[row=s][k=d]) from global
    short8 kf[2][4];
#pragma unroll
    for (int sf = 0; sf < 2; sf++){
      const unsigned short* kr = Kb + (bh*Tn + s0 + sf*32 + l31)*HSn + 8*l5;
#pragma unroll
      for (int ks = 0; ks < 4; ks++) kf[sf][ks] = *(const short8*)(kr + 16*ks);
    }

    float ls[2][16];
#pragma unroll
    for (int sf = 0; sf < 2; sf++)
#pragma unroll
      for (int r = 0; r < 16; r++) ls[sf][r] = 0.f;

    if (tid < 64) Lred[tid] = 0.f;

    const int t0s = (s0 >> 7) << 7;             // floor to 128
    const int ntl = (Tn - t0s) >> 7;

    // stage tile 0
    {
      const int c = lane & 7;
#pragma unroll
      for (int i = 0; i < 4; i++){
        int row = (w*4 + i)*8 + (lane >> 3);
        gl16(Qb + (bh*Tn + t0s + row)*HSn + ((c ^ (row & 7))*8), &Qs[0][(w*4 + i)*512]);
      }
    }
    asm volatile("s_waitcnt vmcnt(0)" ::: "memory");
    __syncthreads();

    for (int it = 0; it < ntl; it++){
      const int cur = it & 1;
      if (it + 1 < ntl){
        const int tn = t0s + (it + 1)*128;
        const int c = lane & 7;
#pragma unroll
        for (int i = 0; i < 4; i++){
          int row = (w*4 + i)*8 + (lane >> 3);
          gl16(Qb + (bh*Tn + tn + row)*HSn + ((c ^ (row & 7))*8), &Qs[cur^1][(w*4 + i)*512]);
        }
      }
      const int t0 = t0s + it*128;
      const int tw = t0 + 32*w;                 // wave's t base
      if (tw + 31 >= s0){
        f32x16 st[2];
#pragma unroll
        for (int sf = 0; sf < 2; sf++)
#pragma unroll
          for (int r = 0; r < 16; r++) st[sf][r] = 0.f;
        const int qrow = w*32 + l31;
        const unsigned short* Qc = &Qs[cur][qrow*64];
        const int sw = qrow & 7;
#pragma unroll
        for (int ks = 0; ks < 4; ks++){
          short8 qb = *(const short8*)&Qc[((l5 + 2*ks) ^ sw)*8];
          st[0] = mfma32(kf[0][ks], qb, st[0]);
          st[1] = mfma32(kf[1][ks], qb, st[1]);
        }
        const int tg = tw + l31;
        if (s0 + 63 <= tw){                      // interior: no mask
#pragma unroll
          for (int sf = 0; sf < 2; sf++)
#pragma unroll
            for (int r = 0; r < 16; r++)
              ls[sf][r] += __builtin_amdgcn_exp2f(st[sf][r] * CEXP);
        } else {
#pragma unroll
          for (int sf = 0; sf < 2; sf++)
#pragma unroll
            for (int r = 0; r < 16; r++){
              int sg = s0 + 32*sf + (r & 3) + 8*(r >> 2) + 4*l5;
              float e = __builtin_amdgcn_exp2f(st[sf][r] * CEXP);
              ls[sf][r] += (tg >= sg) ? e : 0.f;
            }
        }
      }
      asm volatile("s_waitcnt vmcnt(0)" ::: "memory");
      __syncthreads();
    }

    // reduce over t (lanes l31) via butterfly, then cross-wave via LDS atomics
#pragma unroll
    for (int sf = 0; sf < 2; sf++)
#pragma unroll
      for (int r = 0; r < 16; r++){
        float v = ls[sf][r];
        v += __shfl_xor(v, 1);  v += __shfl_xor(v, 2);
        v += __shfl_xor(v, 4);  v += __shfl_xor(v, 8);
        v += __shfl_xor(v, 16);
        ls[sf][r] = v;
      }
    if (l31 == 0){
#pragma unroll
      for (int sf = 0; sf < 2; sf++)
#pragma unroll
        for (int r = 0; r < 16; r++){
          int sl = 32*sf + (r & 3) + 8*(r >> 2) + 4*l5;
          atomicAdd(&Lred[sl], ls[sf][r]);
        }
    }
    __syncthreads();
    if (tid < 64) Linv[bh*Tn + s0 + tid] = 1.0f / Lred[tid];
    if (ph == 0) __syncthreads();
  }
}

// ---------------- kernel 2b: Vt *= Linv (fold denominator into V) -------------
__global__ void k_vscale(unsigned short* __restrict__ Vt, const float* __restrict__ Linv){
  int i = (blockIdx.x * blockDim.x + threadIdx.x) * 8;
  int bh = i >> 17, t = i & 2047;
  short8 v = *(const short8*)(Vt + i);
  float4 L0 = *(const float4*)(Linv + bh*Tn + t);
  float4 L1 = *(const float4*)(Linv + bh*Tn + t + 4);
  unsigned int r0 = cvtpk(b2f((unsigned short)v[0])*L0.x, b2f((unsigned short)v[1])*L0.y);
  unsigned int r1 = cvtpk(b2f((unsigned short)v[2])*L0.z, b2f((unsigned short)v[3])*L0.w);
  unsigned int r2 = cvtpk(b2f((unsigned short)v[4])*L1.x, b2f((unsigned short)v[5])*L1.y);
  unsigned int r3 = cvtpk(b2f((unsigned short)v[6])*L1.z, b2f((unsigned short)v[7])*L1.w);
  uint4w o; o[0]=r0; o[1]=r1; o[2]=r2; o[3]=r3;
  *(uint4w*)(Vt + i) = o;
}

// ---------------- kernel 3: attention output ----------------
// Swapped 32x32: St[s][t] = K·Q^T; P row-major per-wave in LDS (b64 writes);
// out^T[d][t] = Vlt[d][s]·P^T[s][t] with Vlt = Linv*V pre-transposed in global.
// Block (bh, pair i): t-blocks {128*i, 128*(15-i)} -> 34 s-tiles each (balanced).
__global__ void k_attn(const unsigned short* __restrict__ Qb,
                       const unsigned short* __restrict__ Kb,
                       const unsigned short* __restrict__ Vlt,
                       unsigned short* __restrict__ Att)
{
  __shared__ unsigned short Ks[2][64*64];   // rows s, swizzled chunk^=(row&7)
  __shared__ unsigned short Vs[2][64*64];   // rows d, swizzled
  __shared__ unsigned short Ps[4][32*64];   // per-wave P[t_local][s], swizzled
  const int bh = blockIdx.x, ipair = blockIdx.y;
  const int tid = threadIdx.x, lane = tid & 63, w = tid >> 6;
  const int l5 = lane >> 5, l31 = lane & 31;
  const int c7 = lane & 7, r8 = lane >> 3;

  for (int ph = 0; ph < 2; ph++){
    const int tb = ph ? (15 - ipair) : ipair;
    const int t0 = tb * 128;
    const int tbase = t0 + w*32;
    const int nt = (t0 >> 6) + 2;

    // hoist Q b-frags (B[k=d][col=t] read from Q row-major)
    short8 qf[4];
    {
      const unsigned short* qr = Qb + (bh*Tn + tbase + l31)*HSn + 8*l5;
#pragma unroll
      for (int ks = 0; ks < 4; ks++) qf[ks] = *(const short8*)(qr + 16*ks);
    }

    f32x16 oacc[2];
#pragma unroll
    for (int df = 0; df < 2; df++)
#pragma unroll
      for (int r = 0; r < 16; r++) oacc[df][r] = 0.f;

    // stage tile 0 (K rows s from (b,h,s,d); Vlt rows d from (b,h,d,t))
    {
#pragma unroll
      for (int i = 0; i < 2; i++){
        int row = (w*2 + i)*8 + r8;
        gl16(Kb  + (bh*Tn + row)*HSn + ((c7 ^ (row & 7))*8), &Ks[0][(w*2 + i)*512]);
        gl16(Vlt + (bh*HSn + row)*Tn + ((c7 ^ (row & 7))*8), &Vs[0][(w*2 + i)*512]);
      }
    }
    asm volatile("s_waitcnt vmcnt(0)" ::: "memory");
    __syncthreads();

    for (int it = 0; it < nt; it++){
      const int cur = it & 1;
      if (it + 1 < nt){
        const int sn = (it + 1)*64;
#pragma unroll
        for (int i = 0; i < 2; i++){
          int row = (w*2 + i)*8 + r8;
          gl16(Kb  + (bh*Tn + sn + row)*HSn + ((c7 ^ (row & 7))*8), &Ks[cur^1][(w*2 + i)*512]);
          gl16(Vlt + (bh*HSn + row)*Tn + sn + ((c7 ^ (row & 7))*8), &Vs[cur^1][(w*2 + i)*512]);
        }
      }
      const int s0 = it * 64;
      if (s0 <= tbase + 31){
        const unsigned short* Kc = &Ks[cur][0];
        const int sw = l31 & 7;
        // S^T = K·Q^T
        f32x16 st[2];
#pragma unroll
        for (int sf = 0; sf < 2; sf++)
#pragma unroll
          for (int r = 0; r < 16; r++) st[sf][r] = 0.f;
#pragma unroll
        for (int ks = 0; ks < 4; ks++){
#pragma unroll
          for (int sf = 0; sf < 2; sf++){
            int row = sf*32 + l31;
            short8 ka = *(const short8*)&Kc[row*64 + (((l5 + 2*ks) ^ (row & 7))*8)];
            st[sf] = mfma32(ka, qf[ks], st[sf]);
          }
        }
        // softmax numerator -> P (bf16, per-wave LDS, b64 writes)
        unsigned short* Pw = &Ps[w][0];
        const int tg = tbase + l31;
        if (s0 + 63 <= tbase){                  // interior: no mask
#pragma unroll
          for (int sf = 0; sf < 2; sf++)
#pragma unroll
            for (int r2 = 0; r2 < 4; r2++){
              unsigned int a = cvtpk(__builtin_amdgcn_exp2f(st[sf][r2*4+0]*CEXP),
                                     __builtin_amdgcn_exp2f(st[sf][r2*4+1]*CEXP));
              unsigned int b = cvtpk(__builtin_amdgcn_exp2f(st[sf][r2*4+2]*CEXP),
                                     __builtin_amdgcn_exp2f(st[sf][r2*4+3]*CEXP));
              uint2 u; u.x = a; u.y = b;
              *(uint2*)&Pw[l31*64 + (((4*sf + r2) ^ sw)*8) + 4*l5] = u;
            }
        } else {
#pragma unroll
          for (int sf = 0; sf < 2; sf++)
#pragma unroll
            for (int r2 = 0; r2 < 4; r2++){
              int sg = s0 + 32*sf + 8*r2 + 4*l5;
              float p0 = (tg >= sg+0) ? __builtin_amdgcn_exp2f(st[sf][r2*4+0]*CEXP) : 0.f;
              float p1 = (tg >= sg+1) ? __builtin_amdgcn_exp2f(st[sf][r2*4+1]*CEXP) : 0.f;
              float p2 = (tg >= sg+2) ? __builtin_amdgcn_exp2f(st[sf][r2*4+2]*CEXP) : 0.f;
              float p3 = (tg >= sg+3) ? __builtin_amdgcn_exp2f(st[sf][r2*4+3]*CEXP) : 0.f;
              uint2 u; u.x = cvtpk(p0, p1); u.y = cvtpk(p2, p3);
              *(uint2*)&Pw[l31*64 + (((4*sf + r2) ^ sw)*8) + 4*l5] = u;
            }
        }
        // PV: out^T += Vlt · P^T
        const unsigned short* Vc = &Vs[cur][0];
#pragma unroll
        for (int ks = 0; ks < 4; ks++){
          short8 pb = *(const short8*)&Pw[l31*64 + (((2*ks + l5) ^ sw)*8)];
#pragma unroll
          for (int df = 0; df < 2; df++){
            int row = df*32 + l31;
            short8 va = *(const short8*)&Vc[row*64 + (((l5 + 2*ks) ^ (row & 7))*8)];
            oacc[df] = mfma32(va, pb, oacc[df]);
          }
        }
      }
      asm volatile("s_waitcnt vmcnt(0)" ::: "memory");
      __syncthreads();
    }

    // store out^T fragment: lane holds 16 d-values for t = tbase+l31
    {
      const int tg = tbase + l31;
      unsigned short* ob = Att + (bh*Tn + tg)*HSn;
#pragma unroll
      for (int df = 0; df < 2; df++)
#pragma unroll
        for (int r2 = 0; r2 < 4; r2++){
          uint2 u;
          u.x = cvtpk(oacc[df][r2*4+0], oacc[df][r2*4+1]);
          u.y = cvtpk(oacc[df][r2*4+2], oacc[df][r2*4+3]);
          *(uint2*)&ob[32*df + 8*r2 + 4*l5] = u;
        }
    }
  }
}

// ---------------- kernel 4: output projection ----------------
__global__ void k_oproj(const unsigned short* __restrict__ Att,
                        const float* __restrict__ Wo, const float* __restrict__ bo,
                        float* __restrict__ out)
{
  __shared__ unsigned short As[128*40];
  __shared__ unsigned short Bs[128*40];
  const int tid = threadIdx.x, lane = tid & 63, wid = tid >> 6;
  const int wr = wid >> 1, wc = wid & 1;
  const int mb = blockIdx.x, nb = blockIdx.y;
  const int n0 = nb * 128;
  const int arow = tid >> 1, akh = (tid & 1) * 16;
  const int bcol = tid & 127, bkh = (tid >> 7) * 16;
  const int r = mb*128 + arow;
  const int bb = r >> 11, tt = r & 2047;
  const int kofs = 8 * (lane >> 4);

  f32x4 acc[4][4];
#pragma unroll
  for (int i = 0; i < 4; i++)
#pragma unroll
    for (int j = 0; j < 4; j++) acc[i][j] = (f32x4){0.f,0.f,0.f,0.f};

  for (int k0 = 0; k0 < En; k0 += 32){
    int e0 = k0 + akh;
    int hh = e0 >> 6, d0 = e0 & 63;
    const unsigned short* ap = Att + ((bb*Hn + hh)*Tn + tt)*HSn + d0;
    *(uint4w*)&As[arow*40 + akh]     = *(const uint4w*)ap;
    *(uint4w*)&As[arow*40 + akh + 8] = *(const uint4w*)(ap + 8);
    alignas(16) unsigned short tb[16];
#pragma unroll
    for (int kk = 0; kk < 16; kk++) tb[kk] = f2b(Wo[(k0 + bkh + kk)*En + n0 + bcol]);
    *(uint4w*)&Bs[bcol*40 + bkh]     = *(const uint4w*)(tb);
    *(uint4w*)&Bs[bcol*40 + bkh + 8] = *(const uint4w*)(tb + 8);
    __syncthreads();

    short8 af[4], bf[4];
#pragma unroll
    for (int mf = 0; mf < 4; mf++)
      af[mf] = *(const short8*)&As[(wr*64 + mf*16 + (lane&15))*40 + kofs];
#pragma unroll
    for (int nf = 0; nf < 4; nf++)
      bf[nf] = *(const short8*)&Bs[(wc*64 + nf*16 + (lane&15))*40 + kofs];
#pragma unroll
    for (int mf = 0; mf < 4; mf++)
#pragma unroll
      for (int nf = 0; nf < 4; nf++)
        acc[mf][nf] = mfma16(af[mf], bf[nf], acc[mf][nf]);
    __syncthreads();
  }

#pragma unroll
  for (int nf = 0; nf < 4; nf++){
    int j = n0 + wc*64 + nf*16 + (lane & 15);
    float bias = bo[j];
#pragma unroll
    for (int mf = 0; mf < 4; mf++){
#pragma unroll
      for (int q = 0; q < 4; q++){
        int rr = mb*128 + wr*64 + mf*16 + (lane>>4)*4 + q;
        out[rr*En + j] = acc[mf][nf][q] + bias;
      }
    }
  }
}

extern "C" void kernel_launch(void* const* d_in, const int* in_sizes, int n_in,
                              void* d_out, int out_size, void* d_ws, size_t ws_size,
                              hipStream_t stream)
{
  (void)in_sizes; (void)n_in; (void)out_size; (void)ws_size;
  const float* x  = (const float*)d_in[0];
  const float* Wq = (const float*)d_in[1];
  const float* Wk = (const float*)d_in[2];
  const float* Wv = (const float*)d_in[3];
  const float* Wo = (const float*)d_in[4];
  const float* bo = (const float*)d_in[5];
  float* out = (float*)d_out;

  // ws: Qb[0,16M) Kb[16M,32M) Vt[32M,48M) xb/Att alias [48M,64M) Linv[64M,+32K)
  uint8_t* w = (uint8_t*)d_ws;
  unsigned short* Qb  = (unsigned short*)(w);
  unsigned short* Kb  = (unsigned short*)(w + (16u << 20));
  unsigned short* Vt  = (unsigned short*)(w + (32u << 20));
  unsigned short* xb  = (unsigned short*)(w + (48u << 20));
  unsigned short* Att = (unsigned short*)(w + (48u << 20));
  float* Linv         = (float*)(w + (64u << 20));

  hipLaunchKernelGGL(k_cvt_x,  dim3(4096),   dim3(256), 0, stream, x, xb);
  hipLaunchKernelGGL(k_qkv,    dim3(64, 24), dim3(256), 0, stream, xb, Wq, Wk, Wv, Qb, Kb, Vt);
  hipLaunchKernelGGL(k_colsum, dim3(64, 16), dim3(256), 0, stream, Qb, Kb, Linv);
  hipLaunchKernelGGL(k_vscale, dim3(4096),   dim3(256), 0, stream, Vt, Linv);
  hipLaunchKernelGGL(k_attn,   dim3(64, 8),  dim3(256), 0, stream, Qb, Kb, Vt, Att);
  hipLaunchKernelGGL(k_oproj,  dim3(64, 8),  dim3(256), 0, stream, Att, Wo, bo, out);
}

// Round 3
// 264.391 us; speedup vs baseline: 1.1865x; 1.1337x over previous
//
#include <hip/hip_runtime.h>
#include <stdint.h>

// Problem constants
#define Bn 4
#define Tn 2048
#define En 1024
#define Hn 16
#define HSn 64
#define BHn (Bn*Hn)   // 64
#define NRn (Bn*Tn)   // 8192

// exp(x/32) = exp2(x * 0.03125 * log2(e))
#define CEXP 0.0450840831f

typedef __attribute__((ext_vector_type(8))) short short8;
typedef __attribute__((ext_vector_type(4))) float f32x4;
typedef __attribute__((ext_vector_type(16))) float f32x16;
typedef __attribute__((ext_vector_type(4))) unsigned int uint4w;

__device__ __forceinline__ unsigned short f2b(float f){
  union { float f; unsigned int u; } c; c.f = f;
  unsigned int u = c.u + 0x7FFFu + ((c.u >> 16) & 1u);
  return (unsigned short)(u >> 16);
}
__device__ __forceinline__ float b2f(unsigned short s){
  union { unsigned int u; float f; } c; c.u = ((unsigned int)s) << 16;
  return c.f;
}
__device__ __forceinline__ unsigned int cvtpk(float lo, float hi){
  unsigned int r;
  asm("v_cvt_pk_bf16_f32 %0, %1, %2" : "=v"(r) : "v"(lo), "v"(hi));
  return r;
}
__device__ __forceinline__ f32x4 mfma16(short8 a, short8 b, f32x4 c){
  return __builtin_amdgcn_mfma_f32_16x16x32_bf16(a, b, c, 0, 0, 0);
}
__device__ __forceinline__ f32x16 mfma32(short8 a, short8 b, f32x16 c){
  return __builtin_amdgcn_mfma_f32_32x32x16_bf16(a, b, c, 0, 0, 0);
}
__device__ __forceinline__ void gl16(const void* g, void* s){
  __builtin_amdgcn_global_load_lds((const __attribute__((address_space(1))) unsigned int*)g,
                                   (__attribute__((address_space(3))) unsigned int*)s, 16, 0, 0);
}

// ---------------- kernel 0: x fp32 -> bf16 ----------------
__global__ void k_cvt_x(const float* __restrict__ x, unsigned short* __restrict__ xb){
  int i = (blockIdx.x * blockDim.x + threadIdx.x) * 8;
  float4 a = *(const float4*)(x + i);
  float4 b = *(const float4*)(x + i + 4);
  alignas(16) unsigned short o[8] = {f2b(a.x),f2b(a.y),f2b(a.z),f2b(a.w),
                                     f2b(b.x),f2b(b.y),f2b(b.z),f2b(b.w)};
  *(uint4w*)(xb + i) = *(const uint4w*)o;
}

// ---------------- kernel 0b: weight convert+transpose ----------------
// Wt[j][e] bf16, j = sel*1024 + h*64 + d (3072 rows); Wot[j][e] bf16 (1024 rows).
__global__ void k_wT(const float* __restrict__ Wq, const float* __restrict__ Wk,
                     const float* __restrict__ Wv, const float* __restrict__ Wo,
                     unsigned short* __restrict__ Wt, unsigned short* __restrict__ Wot)
{
  __shared__ unsigned short Ls[64*80];
  const int tid = threadIdx.x;
  const int ey = blockIdx.x, jt = blockIdx.y;
  const int e0 = ey*64;
  const float* src; int R, c0; unsigned short* outp;
  if (jt < 48){
    int sel = jt >> 4, h = jt & 15;
    const float* W = (sel==0)?Wq:((sel==1)?Wk:Wv);
    src = W + h*(En*HSn); R = HSn; c0 = 0;
    outp = Wt + jt*64*En;
  } else {
    src = Wo; R = En; c0 = (jt-48)*64;
    outp = Wot + (jt-48)*64*En;
  }
  {
    const int e = tid >> 2, cq = (tid & 3)*16;
    const float* p = src + (e0 + e)*R + c0 + cq;
    float vv[16];
    *(float4*)&vv[0]  = *(const float4*)(p);
    *(float4*)&vv[4]  = *(const float4*)(p+4);
    *(float4*)&vv[8]  = *(const float4*)(p+8);
    *(float4*)&vv[12] = *(const float4*)(p+12);
#pragma unroll
    for (int i = 0; i < 16; i++) Ls[(cq+i)*80 + e] = f2b(vv[i]);
  }
  __syncthreads();
  {
    const int c8 = tid & 7, r = tid >> 3;   // r 0..31
#pragma unroll
    for (int rr0 = 0; rr0 < 2; rr0++){
      int rr = r + rr0*32;
      *(uint4w*)(outp + rr*En + e0 + c8*8) = *(const uint4w*)&Ls[rr*80 + c8*8];
    }
  }
}

// ---------------- kernel 1: QKV projection GEMM (m97 structure) ----------------
// C(8192 x 3072) = xb(8192x1024) @ Wt^T; both operands bf16, gl16-staged,
// swizzled LDS (chunk ^= (row>>1)&3). Q,K -> (B,H,T,64); V -> (B,H,64,T).
__global__ void k_qkv(const unsigned short* __restrict__ xb,
                      const unsigned short* __restrict__ Wt,
                      unsigned short* __restrict__ Qb, unsigned short* __restrict__ Kb,
                      unsigned short* __restrict__ Vt)
{
  __shared__ unsigned short As[128*32];
  __shared__ unsigned short Bs[128*32];
  const int tid = threadIdx.x, lane = tid & 63, w = tid >> 6;
  const int wr = w >> 1, wc = w & 1;
  const int mb = blockIdx.x, nb = blockIdx.y;
  const int n0 = nb*128;
  const int srow0 = w*32 + (lane >> 2);
  const int sc = lane & 3;
  const int l15 = lane & 15, kc = lane >> 4;

  f32x4 acc[4][4];
#pragma unroll
  for (int i = 0; i < 4; i++)
#pragma unroll
    for (int j = 0; j < 4; j++) acc[i][j] = (f32x4){0.f,0.f,0.f,0.f};

  const unsigned short* xbase = xb + (mb*128)*En;
  const unsigned short* wbase = Wt + n0*En;

  for (int k0 = 0; k0 < En; k0 += 32){
#pragma unroll
    for (int i = 0; i < 2; i++){
      int r = srow0 + i*16;
      int cx = (sc ^ ((r >> 1) & 3)) * 8;
      gl16(xbase + r*En + k0 + cx, &As[(w*32 + i*16)*32]);
      gl16(wbase + r*En + k0 + cx, &Bs[(w*32 + i*16)*32]);
    }
    __syncthreads();
    short8 af[4], bf[4];
#pragma unroll
    for (int mf = 0; mf < 4; mf++){
      int ar = wr*64 + mf*16 + l15;
      af[mf] = *(const short8*)&As[ar*32 + ((kc ^ ((ar >> 1) & 3))*8)];
    }
#pragma unroll
    for (int nf = 0; nf < 4; nf++){
      int br = wc*64 + nf*16 + l15;
      bf[nf] = *(const short8*)&Bs[br*32 + ((kc ^ ((br >> 1) & 3))*8)];
    }
#pragma unroll
    for (int mf = 0; mf < 4; mf++)
#pragma unroll
      for (int nf = 0; nf < 4; nf++)
        acc[mf][nf] = mfma16(af[mf], bf[nf], acc[mf][nf]);
    __syncthreads();
  }

  const int q4 = (lane >> 4)*4;
#pragma unroll
  for (int nf = 0; nf < 4; nf++){
    int j = n0 + wc*64 + nf*16 + l15;
    int sel = j >> 10, jj = j & 1023, hh = jj >> 6, dd = jj & 63;
#pragma unroll
    for (int mf = 0; mf < 4; mf++){
#pragma unroll
      for (int q = 0; q < 4; q++){
        int rg = mb*128 + wr*64 + mf*16 + q4 + q;
        int bb = rg >> 11, tt = rg & 2047;
        unsigned short val = f2b(acc[mf][nf][q]);
        if (sel == 2)      Vt[((bb*Hn + hh)*HSn + dd)*Tn + tt] = val;
        else if (sel == 1) Kb[((bb*Hn + hh)*Tn + tt)*HSn + dd] = val;
        else               Qb[((bb*Hn + hh)*Tn + tt)*HSn + dd] = val;
      }
    }
  }
}

// ---------------- kernel 2: column exp-sums (softmax over QUERY axis) ----------
__global__ void k_colsum(const unsigned short* __restrict__ Qb,
                         const unsigned short* __restrict__ Kb,
                         float* __restrict__ Linv)
{
  __shared__ unsigned short Qs[2][128*64];
  __shared__ float Lred[64];
  const int bh = blockIdx.x, ipair = blockIdx.y;
  const int tid = threadIdx.x, lane = tid & 63, w = tid >> 6;
  const int l5 = lane >> 5, l31 = lane & 31;

  for (int ph = 0; ph < 2; ph++){
    const int sb = ph ? (31 - ipair) : ipair;
    const int s0 = sb * 64;

    short8 kf[2][4];
#pragma unroll
    for (int sf = 0; sf < 2; sf++){
      const unsigned short* kr = Kb + (bh*Tn + s0 + sf*32 + l31)*HSn + 8*l5;
#pragma unroll
      for (int ks = 0; ks < 4; ks++) kf[sf][ks] = *(const short8*)(kr + 16*ks);
    }

    float ls[2][16];
#pragma unroll
    for (int sf = 0; sf < 2; sf++)
#pragma unroll
      for (int r = 0; r < 16; r++) ls[sf][r] = 0.f;

    if (tid < 64) Lred[tid] = 0.f;

    const int t0s = (s0 >> 7) << 7;
    const int ntl = (Tn - t0s) >> 7;

    {
      const int c = lane & 7;
#pragma unroll
      for (int i = 0; i < 4; i++){
        int row = (w*4 + i)*8 + (lane >> 3);
        gl16(Qb + (bh*Tn + t0s + row)*HSn + ((c ^ (row & 7))*8), &Qs[0][(w*4 + i)*512]);
      }
    }
    asm volatile("s_waitcnt vmcnt(0)" ::: "memory");
    __syncthreads();

    for (int it = 0; it < ntl; it++){
      const int cur = it & 1;
      if (it + 1 < ntl){
        const int tn = t0s + (it + 1)*128;
        const int c = lane & 7;
#pragma unroll
        for (int i = 0; i < 4; i++){
          int row = (w*4 + i)*8 + (lane >> 3);
          gl16(Qb + (bh*Tn + tn + row)*HSn + ((c ^ (row & 7))*8), &Qs[cur^1][(w*4 + i)*512]);
        }
      }
      const int t0 = t0s + it*128;
      const int tw = t0 + 32*w;
      if (tw + 31 >= s0){
        f32x16 st[2];
#pragma unroll
        for (int sf = 0; sf < 2; sf++)
#pragma unroll
          for (int r = 0; r < 16; r++) st[sf][r] = 0.f;
        const int qrow = w*32 + l31;
        const unsigned short* Qc = &Qs[cur][qrow*64];
        const int sw = qrow & 7;
#pragma unroll
        for (int ks = 0; ks < 4; ks++){
          short8 qb = *(const short8*)&Qc[((l5 + 2*ks) ^ sw)*8];
          st[0] = mfma32(kf[0][ks], qb, st[0]);
          st[1] = mfma32(kf[1][ks], qb, st[1]);
        }
        const int tg = tw + l31;
        if (s0 + 63 <= tw){
#pragma unroll
          for (int sf = 0; sf < 2; sf++)
#pragma unroll
            for (int r = 0; r < 16; r++)
              ls[sf][r] += __builtin_amdgcn_exp2f(st[sf][r] * CEXP);
        } else {
#pragma unroll
          for (int sf = 0; sf < 2; sf++)
#pragma unroll
            for (int r = 0; r < 16; r++){
              int sg = s0 + 32*sf + (r & 3) + 8*(r >> 2) + 4*l5;
              float e = __builtin_amdgcn_exp2f(st[sf][r] * CEXP);
              ls[sf][r] += (tg >= sg) ? e : 0.f;
            }
        }
      }
      asm volatile("s_waitcnt vmcnt(0)" ::: "memory");
      __syncthreads();
    }

#pragma unroll
    for (int sf = 0; sf < 2; sf++)
#pragma unroll
      for (int r = 0; r < 16; r++){
        float v = ls[sf][r];
        v += __shfl_xor(v, 1);  v += __shfl_xor(v, 2);
        v += __shfl_xor(v, 4);  v += __shfl_xor(v, 8);
        v += __shfl_xor(v, 16);
        ls[sf][r] = v;
      }
    if (l31 == 0){
#pragma unroll
      for (int sf = 0; sf < 2; sf++)
#pragma unroll
        for (int r = 0; r < 16; r++){
          int sl = 32*sf + (r & 3) + 8*(r >> 2) + 4*l5;
          atomicAdd(&Lred[sl], ls[sf][r]);
        }
    }
    __syncthreads();
    if (tid < 64) Linv[bh*Tn + s0 + tid] = 1.0f / Lred[tid];
    if (ph == 0) __syncthreads();
  }
}

// ---------------- kernel 2b: Vt *= Linv ----------------
__global__ void k_vscale(unsigned short* __restrict__ Vt, const float* __restrict__ Linv){
  int i = (blockIdx.x * blockDim.x + threadIdx.x) * 8;
  int bh = i >> 17, t = i & 2047;
  short8 v = *(const short8*)(Vt + i);
  float4 L0 = *(const float4*)(Linv + bh*Tn + t);
  float4 L1 = *(const float4*)(Linv + bh*Tn + t + 4);
  unsigned int r0 = cvtpk(b2f((unsigned short)v[0])*L0.x, b2f((unsigned short)v[1])*L0.y);
  unsigned int r1 = cvtpk(b2f((unsigned short)v[2])*L0.z, b2f((unsigned short)v[3])*L0.w);
  unsigned int r2 = cvtpk(b2f((unsigned short)v[4])*L1.x, b2f((unsigned short)v[5])*L1.y);
  unsigned int r3 = cvtpk(b2f((unsigned short)v[6])*L1.z, b2f((unsigned short)v[7])*L1.w);
  uint4w o; o[0]=r0; o[1]=r1; o[2]=r2; o[3]=r3;
  *(uint4w*)(Vt + i) = o;
}

// ---------------- kernel 3: attention output ----------------
__global__ void k_attn(const unsigned short* __restrict__ Qb,
                       const unsigned short* __restrict__ Kb,
                       const unsigned short* __restrict__ Vlt,
                       unsigned short* __restrict__ Att)
{
  __shared__ unsigned short Ks[2][64*64];
  __shared__ unsigned short Vs[2][64*64];
  __shared__ unsigned short Ps[4][32*64];
  const int bh = blockIdx.x, ipair = blockIdx.y;
  const int tid = threadIdx.x, lane = tid & 63, w = tid >> 6;
  const int l5 = lane >> 5, l31 = lane & 31;
  const int c7 = lane & 7, r8 = lane >> 3;

  for (int ph = 0; ph < 2; ph++){
    const int tb = ph ? (15 - ipair) : ipair;
    const int t0 = tb * 128;
    const int tbase = t0 + w*32;
    const int nt = (t0 >> 6) + 2;

    short8 qf[4];
    {
      const unsigned short* qr = Qb + (bh*Tn + tbase + l31)*HSn + 8*l5;
#pragma unroll
      for (int ks = 0; ks < 4; ks++) qf[ks] = *(const short8*)(qr + 16*ks);
    }

    f32x16 oacc[2];
#pragma unroll
    for (int df = 0; df < 2; df++)
#pragma unroll
      for (int r = 0; r < 16; r++) oacc[df][r] = 0.f;

    {
#pragma unroll
      for (int i = 0; i < 2; i++){
        int row = (w*2 + i)*8 + r8;
        gl16(Kb  + (bh*Tn + row)*HSn + ((c7 ^ (row & 7))*8), &Ks[0][(w*2 + i)*512]);
        gl16(Vlt + (bh*HSn + row)*Tn + ((c7 ^ (row & 7))*8), &Vs[0][(w*2 + i)*512]);
      }
    }
    asm volatile("s_waitcnt vmcnt(0)" ::: "memory");
    __syncthreads();

    for (int it = 0; it < nt; it++){
      const int cur = it & 1;
      if (it + 1 < nt){
        const int sn = (it + 1)*64;
#pragma unroll
        for (int i = 0; i < 2; i++){
          int row = (w*2 + i)*8 + r8;
          gl16(Kb  + (bh*Tn + sn + row)*HSn + ((c7 ^ (row & 7))*8), &Ks[cur^1][(w*2 + i)*512]);
          gl16(Vlt + (bh*HSn + row)*Tn + sn + ((c7 ^ (row & 7))*8), &Vs[cur^1][(w*2 + i)*512]);
        }
      }
      const int s0 = it * 64;
      if (s0 <= tbase + 31){
        const unsigned short* Kc = &Ks[cur][0];
        const int sw = l31 & 7;
        f32x16 st[2];
#pragma unroll
        for (int sf = 0; sf < 2; sf++)
#pragma unroll
          for (int r = 0; r < 16; r++) st[sf][r] = 0.f;
#pragma unroll
        for (int ks = 0; ks < 4; ks++){
#pragma unroll
          for (int sf = 0; sf < 2; sf++){
            int row = sf*32 + l31;
            short8 ka = *(const short8*)&Kc[row*64 + (((l5 + 2*ks) ^ (row & 7))*8)];
            st[sf] = mfma32(ka, qf[ks], st[sf]);
          }
        }
        unsigned short* Pw = &Ps[w][0];
        const int tg = tbase + l31;
        if (s0 + 63 <= tbase){
#pragma unroll
          for (int sf = 0; sf < 2; sf++)
#pragma unroll
            for (int r2 = 0; r2 < 4; r2++){
              unsigned int a = cvtpk(__builtin_amdgcn_exp2f(st[sf][r2*4+0]*CEXP),
                                     __builtin_amdgcn_exp2f(st[sf][r2*4+1]*CEXP));
              unsigned int b = cvtpk(__builtin_amdgcn_exp2f(st[sf][r2*4+2]*CEXP),
                                     __builtin_amdgcn_exp2f(st[sf][r2*4+3]*CEXP));
              uint2 u; u.x = a; u.y = b;
              *(uint2*)&Pw[l31*64 + (((4*sf + r2) ^ sw)*8) + 4*l5] = u;
            }
        } else {
#pragma unroll
          for (int sf = 0; sf < 2; sf++)
#pragma unroll
            for (int r2 = 0; r2 < 4; r2++){
              int sg = s0 + 32*sf + 8*r2 + 4*l5;
              float p0 = (tg >= sg+0) ? __builtin_amdgcn_exp2f(st[sf][r2*4+0]*CEXP) : 0.f;
              float p1 = (tg >= sg+1) ? __builtin_amdgcn_exp2f(st[sf][r2*4+1]*CEXP) : 0.f;
              float p2 = (tg >= sg+2) ? __builtin_amdgcn_exp2f(st[sf][r2*4+2]*CEXP) : 0.f;
              float p3 = (tg >= sg+3) ? __builtin_amdgcn_exp2f(st[sf][r2*4+3]*CEXP) : 0.f;
              uint2 u; u.x = cvtpk(p0, p1); u.y = cvtpk(p2, p3);
              *(uint2*)&Pw[l31*64 + (((4*sf + r2) ^ sw)*8) + 4*l5] = u;
            }
        }
        const unsigned short* Vc = &Vs[cur][0];
#pragma unroll
        for (int ks = 0; ks < 4; ks++){
          short8 pb = *(const short8*)&Pw[l31*64 + (((2*ks + l5) ^ sw)*8)];
#pragma unroll
          for (int df = 0; df < 2; df++){
            int row = df*32 + l31;
            short8 va = *(const short8*)&Vc[row*64 + (((l5 + 2*ks) ^ (row & 7))*8)];
            oacc[df] = mfma32(va, pb, oacc[df]);
          }
        }
      }
      asm volatile("s_waitcnt vmcnt(0)" ::: "memory");
      __syncthreads();
    }

    {
      const int tg = tbase + l31;
      unsigned short* ob = Att + (bh*Tn + tg)*HSn;
#pragma unroll
      for (int df = 0; df < 2; df++)
#pragma unroll
        for (int r2 = 0; r2 < 4; r2++){
          uint2 u;
          u.x = cvtpk(oacc[df][r2*4+0], oacc[df][r2*4+1]);
          u.y = cvtpk(oacc[df][r2*4+2], oacc[df][r2*4+3]);
          *(uint2*)&ob[32*df + 8*r2 + 4*l5] = u;
        }
    }
  }
}

// ---------------- kernel 4: output projection (m97 structure) ----------------
__global__ void k_oproj(const unsigned short* __restrict__ Att,
                        const unsigned short* __restrict__ Wot,
                        const float* __restrict__ bo, float* __restrict__ out)
{
  __shared__ unsigned short As[128*32];
  __shared__ unsigned short Bs[128*32];
  const int tid = threadIdx.x, lane = tid & 63, w = tid >> 6;
  const int wr = w >> 1, wc = w & 1;
  const int mb = blockIdx.x, nb = blockIdx.y;
  const int n0 = nb*128;
  const int srow0 = w*32 + (lane >> 2);
  const int sc = lane & 3;
  const int l15 = lane & 15, kc = lane >> 4;
  const int bb = (mb*128) >> 11;
  const int t0 = (mb*128) & 2047;

  f32x4 acc[4][4];
#pragma unroll
  for (int i = 0; i < 4; i++)
#pragma unroll
    for (int j = 0; j < 4; j++) acc[i][j] = (f32x4){0.f,0.f,0.f,0.f};

  const unsigned short* wbase = Wot + n0*En;

  for (int k0 = 0; k0 < En; k0 += 32){
    const int hh = k0 >> 6, koff = k0 & 63;
    const unsigned short* abase = Att + ((bb*Hn + hh)*Tn + t0)*HSn + koff;
#pragma unroll
    for (int i = 0; i < 2; i++){
      int r = srow0 + i*16;
      int cx = (sc ^ ((r >> 1) & 3)) * 8;
      gl16(abase + r*HSn + cx, &As[(w*32 + i*16)*32]);
      gl16(wbase + r*En + k0 + cx, &Bs[(w*32 + i*16)*32]);
    }
    __syncthreads();
    short8 af[4], bf[4];
#pragma unroll
    for (int mf = 0; mf < 4; mf++){
      int ar = wr*64 + mf*16 + l15;
      af[mf] = *(const short8*)&As[ar*32 + ((kc ^ ((ar >> 1) & 3))*8)];
    }
#pragma unroll
    for (int nf = 0; nf < 4; nf++){
      int br = wc*64 + nf*16 + l15;
      bf[nf] = *(const short8*)&Bs[br*32 + ((kc ^ ((br >> 1) & 3))*8)];
    }
#pragma unroll
    for (int mf = 0; mf < 4; mf++)
#pragma unroll
      for (int nf = 0; nf < 4; nf++)
        acc[mf][nf] = mfma16(af[mf], bf[nf], acc[mf][nf]);
    __syncthreads();
  }

  const int q4 = (lane >> 4)*4;
#pragma unroll
  for (int nf = 0; nf < 4; nf++){
    int j = n0 + wc*64 + nf*16 + l15;
    float bias = bo[j];
#pragma unroll
    for (int mf = 0; mf < 4; mf++){
#pragma unroll
      for (int q = 0; q < 4; q++){
        int rr = mb*128 + wr*64 + mf*16 + q4 + q;
        out[rr*En + j] = acc[mf][nf][q] + bias;
      }
    }
  }
}

extern "C" void kernel_launch(void* const* d_in, const int* in_sizes, int n_in,
                              void* d_out, int out_size, void* d_ws, size_t ws_size,
                              hipStream_t stream)
{
  (void)in_sizes; (void)n_in; (void)out_size; (void)ws_size;
  const float* x  = (const float*)d_in[0];
  const float* Wq = (const float*)d_in[1];
  const float* Wk = (const float*)d_in[2];
  const float* Wv = (const float*)d_in[3];
  const float* Wo = (const float*)d_in[4];
  const float* bo = (const float*)d_in[5];
  float* out = (float*)d_out;

  // ws layout (MB): Qb[0,16) Kb[16,32) Vt[32,48) xb/Att[48,64) Wt[64,70) Wot[70,72) Linv[72,72.5)
  uint8_t* w = (uint8_t*)d_ws;
  unsigned short* Qb  = (unsigned short*)(w);
  unsigned short* Kb  = (unsigned short*)(w + (16u << 20));
  unsigned short* Vt  = (unsigned short*)(w + (32u << 20));
  unsigned short* xb  = (unsigned short*)(w + (48u << 20));
  unsigned short* Att = (unsigned short*)(w + (48u << 20));
  unsigned short* Wt  = (unsigned short*)(w + (64u << 20));
  unsigned short* Wot = (unsigned short*)(w + (70u << 20));
  float* Linv         = (float*)(w + (72u << 20));

  hipLaunchKernelGGL(k_cvt_x,  dim3(4096),    dim3(256), 0, stream, x, xb);
  hipLaunchKernelGGL(k_wT,     dim3(16, 64),  dim3(256), 0, stream, Wq, Wk, Wv, Wo, Wt, Wot);
  hipLaunchKernelGGL(k_qkv,    dim3(64, 24),  dim3(256), 0, stream, xb, Wt, Qb, Kb, Vt);
  hipLaunchKernelGGL(k_colsum, dim3(64, 16),  dim3(256), 0, stream, Qb, Kb, Linv);
  hipLaunchKernelGGL(k_vscale, dim3(4096),    dim3(256), 0, stream, Vt, Linv);
  hipLaunchKernelGGL(k_attn,   dim3(64, 8),   dim3(256), 0, stream, Qb, Kb, Vt, Att);
  hipLaunchKernelGGL(k_oproj,  dim3(64, 8),   dim3(256), 0, stream, Att, Wot, bo, out);
}

// Round 4
// 226.804 us; speedup vs baseline: 1.3832x; 1.1657x over previous
//
#include <hip/hip_runtime.h>
#include <stdint.h>

// Problem constants
#define Bn 4
#define Tn 2048
#define En 1024
#define Hn 16
#define HSn 64
#define BHn (Bn*Hn)   // 64
#define NRn (Bn*Tn)   // 8192

// exp(x/32) = exp2(x * 0.03125 * log2(e))
#define CEXP 0.0450840831f

typedef __attribute__((ext_vector_type(8))) short short8;
typedef __attribute__((ext_vector_type(4))) float f32x4;
typedef __attribute__((ext_vector_type(16))) float f32x16;
typedef __attribute__((ext_vector_type(4))) unsigned int uint4w;

__device__ __forceinline__ unsigned short f2b(float f){
  union { float f; unsigned int u; } c; c.f = f;
  unsigned int u = c.u + 0x7FFFu + ((c.u >> 16) & 1u);
  return (unsigned short)(u >> 16);
}
__device__ __forceinline__ float b2f(unsigned short s){
  union { unsigned int u; float f; } c; c.u = ((unsigned int)s) << 16;
  return c.f;
}
__device__ __forceinline__ unsigned int cvtpk(float lo, float hi){
  unsigned int r;
  asm("v_cvt_pk_bf16_f32 %0, %1, %2" : "=v"(r) : "v"(lo), "v"(hi));
  return r;
}
__device__ __forceinline__ f32x4 mfma16(short8 a, short8 b, f32x4 c){
  return __builtin_amdgcn_mfma_f32_16x16x32_bf16(a, b, c, 0, 0, 0);
}
__device__ __forceinline__ f32x16 mfma32(short8 a, short8 b, f32x16 c){
  return __builtin_amdgcn_mfma_f32_32x32x16_bf16(a, b, c, 0, 0, 0);
}
__device__ __forceinline__ void gl16(const void* g, void* s){
  __builtin_amdgcn_global_load_lds((const __attribute__((address_space(1))) unsigned int*)g,
                                   (__attribute__((address_space(3))) unsigned int*)s, 16, 0, 0);
}

// ---------------- kernel 0: x fp32 -> bf16 ----------------
__global__ void k_cvt_x(const float* __restrict__ x, unsigned short* __restrict__ xb){
  int i = (blockIdx.x * blockDim.x + threadIdx.x) * 8;
  float4 a = *(const float4*)(x + i);
  float4 b = *(const float4*)(x + i + 4);
  alignas(16) unsigned short o[8] = {f2b(a.x),f2b(a.y),f2b(a.z),f2b(a.w),
                                     f2b(b.x),f2b(b.y),f2b(b.z),f2b(b.w)};
  *(uint4w*)(xb + i) = *(const uint4w*)o;
}

// ---------------- kernel 0b: weight convert+transpose ----------------
__global__ void k_wT(const float* __restrict__ Wq, const float* __restrict__ Wk,
                     const float* __restrict__ Wv, const float* __restrict__ Wo,
                     unsigned short* __restrict__ Wt, unsigned short* __restrict__ Wot)
{
  __shared__ unsigned short Ls[64*80];
  const int tid = threadIdx.x;
  const int ey = blockIdx.x, jt = blockIdx.y;
  const int e0 = ey*64;
  const float* src; int R, c0; unsigned short* outp;
  if (jt < 48){
    int sel = jt >> 4, h = jt & 15;
    const float* W = (sel==0)?Wq:((sel==1)?Wk:Wv);
    src = W + h*(En*HSn); R = HSn; c0 = 0;
    outp = Wt + jt*64*En;
  } else {
    src = Wo; R = En; c0 = (jt-48)*64;
    outp = Wot + (jt-48)*64*En;
  }
  {
    const int e = tid >> 2, cq = (tid & 3)*16;
    const float* p = src + (e0 + e)*R + c0 + cq;
    float vv[16];
    *(float4*)&vv[0]  = *(const float4*)(p);
    *(float4*)&vv[4]  = *(const float4*)(p+4);
    *(float4*)&vv[8]  = *(const float4*)(p+8);
    *(float4*)&vv[12] = *(const float4*)(p+12);
#pragma unroll
    for (int i = 0; i < 16; i++) Ls[(cq+i)*80 + e] = f2b(vv[i]);
  }
  __syncthreads();
  {
    const int c8 = tid & 7, r = tid >> 3;
#pragma unroll
    for (int rr0 = 0; rr0 < 2; rr0++){
      int rr = r + rr0*32;
      *(uint4w*)(outp + rr*En + e0 + c8*8) = *(const uint4w*)&Ls[rr*80 + c8*8];
    }
  }
}

// ---------------- kernel 1: QKV projection GEMM (2-phase pipelined) ----------
// 128x128 tile, BK=64, double-buffered gl16 staging; STAGE(next) before
// compute(cur), one barrier per K-step. Q,K -> (B,H,T,64); V -> (B,H,64,T).
__global__ void __launch_bounds__(256, 2)
k_qkv(const unsigned short* __restrict__ xb,
      const unsigned short* __restrict__ Wt,
      unsigned short* __restrict__ Qb, unsigned short* __restrict__ Kb,
      unsigned short* __restrict__ Vt)
{
  __shared__ unsigned short As[2][128*64];
  __shared__ unsigned short Bs[2][128*64];
  const int tid = threadIdx.x, lane = tid & 63, w = tid >> 6;
  const int wr = w >> 1, wc = w & 1;
  const int mb = blockIdx.x, nb = blockIdx.y;
  const int n0 = nb*128;
  const int sel = n0 >> 10;
  const int nj0 = n0 & 1023;
  const int l15 = lane & 15, kc = lane >> 4;
  const int r8 = lane >> 3, c7 = lane & 7;

  const unsigned short* xbase = xb + (mb*128)*En;
  const unsigned short* wbase = Wt + n0*En;

  f32x4 acc[4][4];
#pragma unroll
  for (int i = 0; i < 4; i++)
#pragma unroll
    for (int j = 0; j < 4; j++) acc[i][j] = (f32x4){0.f,0.f,0.f,0.f};

  auto stage = [&](int buf, int k0){
#pragma unroll
    for (int i = 0; i < 4; i++){
      const int rb = w*32 + i*8;
      const int r = rb + r8;
      const int g = (c7 ^ r8) * 8;
      gl16(xbase + r*En + k0 + g, &As[buf][rb*64]);
      gl16(wbase + r*En + k0 + g, &Bs[buf][rb*64]);
    }
  };

  stage(0, 0);
  __syncthreads();

  for (int kt = 0; kt < 16; kt++){
    const int cur = kt & 1;
    if (kt < 15) stage(cur ^ 1, (kt + 1)*64);
    const unsigned short* Ac = &As[cur][0];
    const unsigned short* Bc = &Bs[cur][0];
#pragma unroll
    for (int ks = 0; ks < 2; ks++){
      short8 af[4], bf[4];
#pragma unroll
      for (int mf = 0; mf < 4; mf++){
        int ar = wr*64 + mf*16 + l15;
        af[mf] = *(const short8*)&Ac[ar*64 + (((ks*4 + kc) ^ (ar & 7))*8)];
      }
#pragma unroll
      for (int nf = 0; nf < 4; nf++){
        int br = wc*64 + nf*16 + l15;
        bf[nf] = *(const short8*)&Bc[br*64 + (((ks*4 + kc) ^ (br & 7))*8)];
      }
#pragma unroll
      for (int mf = 0; mf < 4; mf++)
#pragma unroll
        for (int nf = 0; nf < 4; nf++)
          acc[mf][nf] = mfma16(af[mf], bf[nf], acc[mf][nf]);
    }
    __syncthreads();
  }

  const int q4 = (lane >> 4)*4;
  const int bb = mb >> 4;
  const int tt0 = (mb*128) & 2047;

  if (sel == 2){
    // transpose 64x64 wave tile through LDS, store Vt rows coalesced (16B)
    unsigned short* tb = ((w < 2) ? &As[0][0] : &Bs[0][0]) + (w & 1)*8192;
#pragma unroll
    for (int nf = 0; nf < 4; nf++)
#pragma unroll
      for (int mf = 0; mf < 4; mf++){
        uint2 u;
        u.x = cvtpk(acc[mf][nf][0], acc[mf][nf][1]);
        u.y = cvtpk(acc[mf][nf][2], acc[mf][nf][3]);
        *(uint2*)&tb[(nf*16 + l15)*72 + mf*16 + q4] = u;
      }
    const int hh = (nj0 >> 6) + wc;
    unsigned short* vb = Vt + ((bb*Hn + hh)*HSn)*Tn + tt0 + wr*64;
#pragma unroll
    for (int i = 0; i < 8; i++){
      int rr = i*8 + r8;
      *(uint4w*)(vb + rr*Tn + c7*8) = *(const uint4w*)&tb[rr*72 + c7*8];
    }
  } else {
    unsigned short* Out = (sel == 1) ? Kb : Qb;
#pragma unroll
    for (int nf = 0; nf < 4; nf++){
      int jj = nj0 + wc*64 + nf*16 + l15;
      int hh = jj >> 6, dd = jj & 63;
#pragma unroll
      for (int mf = 0; mf < 4; mf++){
#pragma unroll
        for (int q = 0; q < 4; q++){
          int tt = tt0 + wr*64 + mf*16 + q4 + q;
          Out[((bb*Hn + hh)*Tn + tt)*HSn + dd] = f2b(acc[mf][nf][q]);
        }
      }
    }
  }
}

// ---------------- kernel 2: column exp-sums (softmax over QUERY axis) ----------
__global__ void k_colsum(const unsigned short* __restrict__ Qb,
                         const unsigned short* __restrict__ Kb,
                         float* __restrict__ Linv)
{
  __shared__ unsigned short Qs[2][128*64];
  __shared__ float Lred[64];
  const int bh = blockIdx.x, ipair = blockIdx.y;
  const int tid = threadIdx.x, lane = tid & 63, w = tid >> 6;
  const int l5 = lane >> 5, l31 = lane & 31;

  for (int ph = 0; ph < 2; ph++){
    const int sb = ph ? (31 - ipair) : ipair;
    const int s0 = sb * 64;

    short8 kf[2][4];
#pragma unroll
    for (int sf = 0; sf < 2; sf++){
      const unsigned short* kr = Kb + (bh*Tn + s0 + sf*32 + l31)*HSn + 8*l5;
#pragma unroll
      for (int ks = 0; ks < 4; ks++) kf[sf][ks] = *(const short8*)(kr + 16*ks);
    }

    float ls[2][16];
#pragma unroll
    for (int sf = 0; sf < 2; sf++)
#pragma unroll
      for (int r = 0; r < 16; r++) ls[sf][r] = 0.f;

    if (tid < 64) Lred[tid] = 0.f;

    const int t0s = (s0 >> 7) << 7;
    const int ntl = (Tn - t0s) >> 7;

    {
      const int c = lane & 7;
#pragma unroll
      for (int i = 0; i < 4; i++){
        int row = (w*4 + i)*8 + (lane >> 3);
        gl16(Qb + (bh*Tn + t0s + row)*HSn + ((c ^ (row & 7))*8), &Qs[0][(w*4 + i)*512]);
      }
    }
    asm volatile("s_waitcnt vmcnt(0)" ::: "memory");
    __syncthreads();

    for (int it = 0; it < ntl; it++){
      const int cur = it & 1;
      if (it + 1 < ntl){
        const int tn = t0s + (it + 1)*128;
        const int c = lane & 7;
#pragma unroll
        for (int i = 0; i < 4; i++){
          int row = (w*4 + i)*8 + (lane >> 3);
          gl16(Qb + (bh*Tn + tn + row)*HSn + ((c ^ (row & 7))*8), &Qs[cur^1][(w*4 + i)*512]);
        }
      }
      const int t0 = t0s + it*128;
      const int tw = t0 + 32*w;
      if (tw + 31 >= s0){
        f32x16 st[2];
#pragma unroll
        for (int sf = 0; sf < 2; sf++)
#pragma unroll
          for (int r = 0; r < 16; r++) st[sf][r] = 0.f;
        const int qrow = w*32 + l31;
        const unsigned short* Qc = &Qs[cur][qrow*64];
        const int sw = qrow & 7;
#pragma unroll
        for (int ks = 0; ks < 4; ks++){
          short8 qb = *(const short8*)&Qc[((l5 + 2*ks) ^ sw)*8];
          st[0] = mfma32(kf[0][ks], qb, st[0]);
          st[1] = mfma32(kf[1][ks], qb, st[1]);
        }
        const int tg = tw + l31;
        if (s0 + 63 <= tw){
#pragma unroll
          for (int sf = 0; sf < 2; sf++)
#pragma unroll
            for (int r = 0; r < 16; r++)
              ls[sf][r] += __builtin_amdgcn_exp2f(st[sf][r] * CEXP);
        } else {
#pragma unroll
          for (int sf = 0; sf < 2; sf++)
#pragma unroll
            for (int r = 0; r < 16; r++){
              int sg = s0 + 32*sf + (r & 3) + 8*(r >> 2) + 4*l5;
              float e = __builtin_amdgcn_exp2f(st[sf][r] * CEXP);
              ls[sf][r] += (tg >= sg) ? e : 0.f;
            }
        }
      }
      asm volatile("s_waitcnt vmcnt(0)" ::: "memory");
      __syncthreads();
    }

#pragma unroll
    for (int sf = 0; sf < 2; sf++)
#pragma unroll
      for (int r = 0; r < 16; r++){
        float v = ls[sf][r];
        v += __shfl_xor(v, 1);  v += __shfl_xor(v, 2);
        v += __shfl_xor(v, 4);  v += __shfl_xor(v, 8);
        v += __shfl_xor(v, 16);
        ls[sf][r] = v;
      }
    if (l31 == 0){
#pragma unroll
      for (int sf = 0; sf < 2; sf++)
#pragma unroll
        for (int r = 0; r < 16; r++){
          int sl = 32*sf + (r & 3) + 8*(r >> 2) + 4*l5;
          atomicAdd(&Lred[sl], ls[sf][r]);
        }
    }
    __syncthreads();
    if (tid < 64) Linv[bh*Tn + s0 + tid] = 1.0f / Lred[tid];
    if (ph == 0) __syncthreads();
  }
}

// ---------------- kernel 2b: Vt *= Linv ----------------
__global__ void k_vscale(unsigned short* __restrict__ Vt, const float* __restrict__ Linv){
  int i = (blockIdx.x * blockDim.x + threadIdx.x) * 8;
  int bh = i >> 17, t = i & 2047;
  short8 v = *(const short8*)(Vt + i);
  float4 L0 = *(const float4*)(Linv + bh*Tn + t);
  float4 L1 = *(const float4*)(Linv + bh*Tn + t + 4);
  unsigned int r0 = cvtpk(b2f((unsigned short)v[0])*L0.x, b2f((unsigned short)v[1])*L0.y);
  unsigned int r1 = cvtpk(b2f((unsigned short)v[2])*L0.z, b2f((unsigned short)v[3])*L0.w);
  unsigned int r2 = cvtpk(b2f((unsigned short)v[4])*L1.x, b2f((unsigned short)v[5])*L1.y);
  unsigned int r3 = cvtpk(b2f((unsigned short)v[6])*L1.z, b2f((unsigned short)v[7])*L1.w);
  uint4w o; o[0]=r0; o[1]=r1; o[2]=r2; o[3]=r3;
  *(uint4w*)(Vt + i) = o;
}

// ---------------- kernel 3: attention output ----------------
__global__ void k_attn(const unsigned short* __restrict__ Qb,
                       const unsigned short* __restrict__ Kb,
                       const unsigned short* __restrict__ Vlt,
                       unsigned short* __restrict__ Att)
{
  __shared__ unsigned short Ks[2][64*64];
  __shared__ unsigned short Vs[2][64*64];
  __shared__ unsigned short Ps[4][32*64];
  const int bh = blockIdx.x, ipair = blockIdx.y;
  const int tid = threadIdx.x, lane = tid & 63, w = tid >> 6;
  const int l5 = lane >> 5, l31 = lane & 31;
  const int c7 = lane & 7, r8 = lane >> 3;

  for (int ph = 0; ph < 2; ph++){
    const int tb = ph ? (15 - ipair) : ipair;
    const int t0 = tb * 128;
    const int tbase = t0 + w*32;
    const int nt = (t0 >> 6) + 2;

    short8 qf[4];
    {
      const unsigned short* qr = Qb + (bh*Tn + tbase + l31)*HSn + 8*l5;
#pragma unroll
      for (int ks = 0; ks < 4; ks++) qf[ks] = *(const short8*)(qr + 16*ks);
    }

    f32x16 oacc[2];
#pragma unroll
    for (int df = 0; df < 2; df++)
#pragma unroll
      for (int r = 0; r < 16; r++) oacc[df][r] = 0.f;

    {
#pragma unroll
      for (int i = 0; i < 2; i++){
        int row = (w*2 + i)*8 + r8;
        gl16(Kb  + (bh*Tn + row)*HSn + ((c7 ^ (row & 7))*8), &Ks[0][(w*2 + i)*512]);
        gl16(Vlt + (bh*HSn + row)*Tn + ((c7 ^ (row & 7))*8), &Vs[0][(w*2 + i)*512]);
      }
    }
    asm volatile("s_waitcnt vmcnt(0)" ::: "memory");
    __syncthreads();

    for (int it = 0; it < nt; it++){
      const int cur = it & 1;
      if (it + 1 < nt){
        const int sn = (it + 1)*64;
#pragma unroll
        for (int i = 0; i < 2; i++){
          int row = (w*2 + i)*8 + r8;
          gl16(Kb  + (bh*Tn + sn + row)*HSn + ((c7 ^ (row & 7))*8), &Ks[cur^1][(w*2 + i)*512]);
          gl16(Vlt + (bh*HSn + row)*Tn + sn + ((c7 ^ (row & 7))*8), &Vs[cur^1][(w*2 + i)*512]);
        }
      }
      const int s0 = it * 64;
      if (s0 <= tbase + 31){
        const unsigned short* Kc = &Ks[cur][0];
        const int sw = l31 & 7;
        f32x16 st[2];
#pragma unroll
        for (int sf = 0; sf < 2; sf++)
#pragma unroll
          for (int r = 0; r < 16; r++) st[sf][r] = 0.f;
#pragma unroll
        for (int ks = 0; ks < 4; ks++){
#pragma unroll
          for (int sf = 0; sf < 2; sf++){
            int row = sf*32 + l31;
            short8 ka = *(const short8*)&Kc[row*64 + (((l5 + 2*ks) ^ (row & 7))*8)];
            st[sf] = mfma32(ka, qf[ks], st[sf]);
          }
        }
        unsigned short* Pw = &Ps[w][0];
        const int tg = tbase + l31;
        if (s0 + 63 <= tbase){
#pragma unroll
          for (int sf = 0; sf < 2; sf++)
#pragma unroll
            for (int r2 = 0; r2 < 4; r2++){
              unsigned int a = cvtpk(__builtin_amdgcn_exp2f(st[sf][r2*4+0]*CEXP),
                                     __builtin_amdgcn_exp2f(st[sf][r2*4+1]*CEXP));
              unsigned int b = cvtpk(__builtin_amdgcn_exp2f(st[sf][r2*4+2]*CEXP),
                                     __builtin_amdgcn_exp2f(st[sf][r2*4+3]*CEXP));
              uint2 u; u.x = a; u.y = b;
              *(uint2*)&Pw[l31*64 + (((4*sf + r2) ^ sw)*8) + 4*l5] = u;
            }
        } else {
#pragma unroll
          for (int sf = 0; sf < 2; sf++)
#pragma unroll
            for (int r2 = 0; r2 < 4; r2++){
              int sg = s0 + 32*sf + 8*r2 + 4*l5;
              float p0 = (tg >= sg+0) ? __builtin_amdgcn_exp2f(st[sf][r2*4+0]*CEXP) : 0.f;
              float p1 = (tg >= sg+1) ? __builtin_amdgcn_exp2f(st[sf][r2*4+1]*CEXP) : 0.f;
              float p2 = (tg >= sg+2) ? __builtin_amdgcn_exp2f(st[sf][r2*4+2]*CEXP) : 0.f;
              float p3 = (tg >= sg+3) ? __builtin_amdgcn_exp2f(st[sf][r2*4+3]*CEXP) : 0.f;
              uint2 u; u.x = cvtpk(p0, p1); u.y = cvtpk(p2, p3);
              *(uint2*)&Pw[l31*64 + (((4*sf + r2) ^ sw)*8) + 4*l5] = u;
            }
        }
        const unsigned short* Vc = &Vs[cur][0];
#pragma unroll
        for (int ks = 0; ks < 4; ks++){
          short8 pb = *(const short8*)&Pw[l31*64 + (((2*ks + l5) ^ sw)*8)];
#pragma unroll
          for (int df = 0; df < 2; df++){
            int row = df*32 + l31;
            short8 va = *(const short8*)&Vc[row*64 + (((l5 + 2*ks) ^ (row & 7))*8)];
            oacc[df] = mfma32(va, pb, oacc[df]);
          }
        }
      }
      asm volatile("s_waitcnt vmcnt(0)" ::: "memory");
      __syncthreads();
    }

    {
      const int tg = tbase + l31;
      unsigned short* ob = Att + (bh*Tn + tg)*HSn;
#pragma unroll
      for (int df = 0; df < 2; df++)
#pragma unroll
        for (int r2 = 0; r2 < 4; r2++){
          uint2 u;
          u.x = cvtpk(oacc[df][r2*4+0], oacc[df][r2*4+1]);
          u.y = cvtpk(oacc[df][r2*4+2], oacc[df][r2*4+3]);
          *(uint2*)&ob[32*df + 8*r2 + 4*l5] = u;
        }
    }
  }
}

// ---------------- kernel 4: output projection (2-phase pipelined) ----------
__global__ void __launch_bounds__(256, 2)
k_oproj(const unsigned short* __restrict__ Att,
        const unsigned short* __restrict__ Wot,
        const float* __restrict__ bo, float* __restrict__ out)
{
  __shared__ unsigned short As[2][128*64];
  __shared__ unsigned short Bs[2][128*64];
  const int tid = threadIdx.x, lane = tid & 63, w = tid >> 6;
  const int wr = w >> 1, wc = w & 1;
  const int mb = blockIdx.x, nb = blockIdx.y;
  const int n0 = nb*128;
  const int l15 = lane & 15, kc = lane >> 4;
  const int r8 = lane >> 3, c7 = lane & 7;
  const int bb = mb >> 4;
  const int t0 = (mb*128) & 2047;

  f32x4 acc[4][4];
#pragma unroll
  for (int i = 0; i < 4; i++)
#pragma unroll
    for (int j = 0; j < 4; j++) acc[i][j] = (f32x4){0.f,0.f,0.f,0.f};

  const unsigned short* wbase = Wot + n0*En;

  auto stage = [&](int buf, int k0){
    const int hh = k0 >> 6;
    const unsigned short* abase = Att + ((bb*Hn + hh)*Tn + t0)*HSn;
#pragma unroll
    for (int i = 0; i < 4; i++){
      const int rb = w*32 + i*8;
      const int r = rb + r8;
      const int g = (c7 ^ r8) * 8;
      gl16(abase + r*HSn + g, &As[buf][rb*64]);
      gl16(wbase + r*En + k0 + g, &Bs[buf][rb*64]);
    }
  };

  stage(0, 0);
  __syncthreads();

  for (int kt = 0; kt < 16; kt++){
    const int cur = kt & 1;
    if (kt < 15) stage(cur ^ 1, (kt + 1)*64);
    const unsigned short* Ac = &As[cur][0];
    const unsigned short* Bc = &Bs[cur][0];
#pragma unroll
    for (int ks = 0; ks < 2; ks++){
      short8 af[4], bf[4];
#pragma unroll
      for (int mf = 0; mf < 4; mf++){
        int ar = wr*64 + mf*16 + l15;
        af[mf] = *(const short8*)&Ac[ar*64 + (((ks*4 + kc) ^ (ar & 7))*8)];
      }
#pragma unroll
      for (int nf = 0; nf < 4; nf++){
        int br = wc*64 + nf*16 + l15;
        bf[nf] = *(const short8*)&Bc[br*64 + (((ks*4 + kc) ^ (br & 7))*8)];
      }
#pragma unroll
      for (int mf = 0; mf < 4; mf++)
#pragma unroll
        for (int nf = 0; nf < 4; nf++)
          acc[mf][nf] = mfma16(af[mf], bf[nf], acc[mf][nf]);
    }
    __syncthreads();
  }

  const int q4 = (lane >> 4)*4;
#pragma unroll
  for (int nf = 0; nf < 4; nf++){
    int j = n0 + wc*64 + nf*16 + l15;
    float bias = bo[j];
#pragma unroll
    for (int mf = 0; mf < 4; mf++){
#pragma unroll
      for (int q = 0; q < 4; q++){
        int rr = mb*128 + wr*64 + mf*16 + q4 + q;
        out[rr*En + j] = acc[mf][nf][q] + bias;
      }
    }
  }
}

extern "C" void kernel_launch(void* const* d_in, const int* in_sizes, int n_in,
                              void* d_out, int out_size, void* d_ws, size_t ws_size,
                              hipStream_t stream)
{
  (void)in_sizes; (void)n_in; (void)out_size; (void)ws_size;
  const float* x  = (const float*)d_in[0];
  const float* Wq = (const float*)d_in[1];
  const float* Wk = (const float*)d_in[2];
  const float* Wv = (const float*)d_in[3];
  const float* Wo = (const float*)d_in[4];
  const float* bo = (const float*)d_in[5];
  float* out = (float*)d_out;

  // ws layout (MB): Qb[0,16) Kb[16,32) Vt[32,48) xb/Att[48,64) Wt[64,70) Wot[70,72) Linv[72,72.5)
  uint8_t* w = (uint8_t*)d_ws;
  unsigned short* Qb  = (unsigned short*)(w);
  unsigned short* Kb  = (unsigned short*)(w + (16u << 20));
  unsigned short* Vt  = (unsigned short*)(w + (32u << 20));
  unsigned short* xb  = (unsigned short*)(w + (48u << 20));
  unsigned short* Att = (unsigned short*)(w + (48u << 20));
  unsigned short* Wt  = (unsigned short*)(w + (64u << 20));
  unsigned short* Wot = (unsigned short*)(w + (70u << 20));
  float* Linv         = (float*)(w + (72u << 20));

  hipLaunchKernelGGL(k_cvt_x,  dim3(4096),    dim3(256), 0, stream, x, xb);
  hipLaunchKernelGGL(k_wT,     dim3(16, 64),  dim3(256), 0, stream, Wq, Wk, Wv, Wo, Wt, Wot);
  hipLaunchKernelGGL(k_qkv,    dim3(64, 24),  dim3(256), 0, stream, xb, Wt, Qb, Kb, Vt);
  hipLaunchKernelGGL(k_colsum, dim3(64, 16),  dim3(256), 0, stream, Qb, Kb, Linv);
  hipLaunchKernelGGL(k_vscale, dim3(4096),    dim3(256), 0, stream, Vt, Linv);
  hipLaunchKernelGGL(k_attn,   dim3(64, 8),   dim3(256), 0, stream, Qb, Kb, Vt, Att);
  hipLaunchKernelGGL(k_oproj,  dim3(64, 8),   dim3(256), 0, stream, Att, Wot, bo, out);
}

// Round 5
// 209.907 us; speedup vs baseline: 1.4945x; 1.0805x over previous
//
#include <hip/hip_runtime.h>
#include <stdint.h>

// Problem constants
#define Bn 4
#define Tn 2048
#define En 1024
#define Hn 16
#define HSn 64
#define BHn (Bn*Hn)   // 64
#define NRn (Bn*Tn)   // 8192

// exp(x/32) = exp2(x * 0.03125 * log2(e))
#define CEXP 0.0450840831f

typedef __attribute__((ext_vector_type(8))) short short8;
typedef __attribute__((ext_vector_type(4))) float f32x4;
typedef __attribute__((ext_vector_type(16))) float f32x16;
typedef __attribute__((ext_vector_type(4))) unsigned int uint4w;

__device__ __forceinline__ unsigned short f2b(float f){
  union { float f; unsigned int u; } c; c.f = f;
  unsigned int u = c.u + 0x7FFFu + ((c.u >> 16) & 1u);
  return (unsigned short)(u >> 16);
}
__device__ __forceinline__ float b2f(unsigned short s){
  union { unsigned int u; float f; } c; c.u = ((unsigned int)s) << 16;
  return c.f;
}
__device__ __forceinline__ unsigned int cvtpk(float lo, float hi){
  unsigned int r;
  asm("v_cvt_pk_bf16_f32 %0, %1, %2" : "=v"(r) : "v"(lo), "v"(hi));
  return r;
}
__device__ __forceinline__ f32x4 mfma16(short8 a, short8 b, f32x4 c){
  return __builtin_amdgcn_mfma_f32_16x16x32_bf16(a, b, c, 0, 0, 0);
}
__device__ __forceinline__ f32x16 mfma32(short8 a, short8 b, f32x16 c){
  return __builtin_amdgcn_mfma_f32_32x32x16_bf16(a, b, c, 0, 0, 0);
}
__device__ __forceinline__ void gl16(const void* g, void* s){
  __builtin_amdgcn_global_load_lds((const __attribute__((address_space(1))) unsigned int*)g,
                                   (__attribute__((address_space(3))) unsigned int*)s, 16, 0, 0);
}

// ---------------- kernel 0: x fp32 -> bf16 ----------------
__global__ void k_cvt_x(const float* __restrict__ x, unsigned short* __restrict__ xb){
  int i = (blockIdx.x * blockDim.x + threadIdx.x) * 8;
  float4 a = *(const float4*)(x + i);
  float4 b = *(const float4*)(x + i + 4);
  alignas(16) unsigned short o[8] = {f2b(a.x),f2b(a.y),f2b(a.z),f2b(a.w),
                                     f2b(b.x),f2b(b.y),f2b(b.z),f2b(b.w)};
  *(uint4w*)(xb + i) = *(const uint4w*)o;
}

// ---------------- kernel 0b: weight convert+transpose ----------------
__global__ void k_wT(const float* __restrict__ Wq, const float* __restrict__ Wk,
                     const float* __restrict__ Wv, const float* __restrict__ Wo,
                     unsigned short* __restrict__ Wt, unsigned short* __restrict__ Wot)
{
  __shared__ unsigned short Ls[64*80];
  const int tid = threadIdx.x;
  const int ey = blockIdx.x, jt = blockIdx.y;
  const int e0 = ey*64;
  const float* src; int R, c0; unsigned short* outp;
  if (jt < 48){
    int sel = jt >> 4, h = jt & 15;
    const float* W = (sel==0)?Wq:((sel==1)?Wk:Wv);
    src = W + h*(En*HSn); R = HSn; c0 = 0;
    outp = Wt + jt*64*En;
  } else {
    src = Wo; R = En; c0 = (jt-48)*64;
    outp = Wot + (jt-48)*64*En;
  }
  {
    const int e = tid >> 2, cq = (tid & 3)*16;
    const float* p = src + (e0 + e)*R + c0 + cq;
    float vv[16];
    *(float4*)&vv[0]  = *(const float4*)(p);
    *(float4*)&vv[4]  = *(const float4*)(p+4);
    *(float4*)&vv[8]  = *(const float4*)(p+8);
    *(float4*)&vv[12] = *(const float4*)(p+12);
#pragma unroll
    for (int i = 0; i < 16; i++) Ls[(cq+i)*80 + e] = f2b(vv[i]);
  }
  __syncthreads();
  {
    const int c8 = tid & 7, r = tid >> 3;
#pragma unroll
    for (int rr0 = 0; rr0 < 2; rr0++){
      int rr = r + rr0*32;
      *(uint4w*)(outp + rr*En + e0 + c8*8) = *(const uint4w*)&Ls[rr*80 + c8*8];
    }
  }
}

// ---------------- kernel 1: QKV projection GEMM (2-phase pipelined) ----------
__global__ void __launch_bounds__(256, 2)
k_qkv(const unsigned short* __restrict__ xb,
      const unsigned short* __restrict__ Wt,
      unsigned short* __restrict__ Qb, unsigned short* __restrict__ Kb,
      unsigned short* __restrict__ Vt)
{
  __shared__ unsigned short As[2][128*64];
  __shared__ unsigned short Bs[2][128*64];
  const int tid = threadIdx.x, lane = tid & 63, w = tid >> 6;
  const int wr = w >> 1, wc = w & 1;
  const int mb = blockIdx.x, nb = blockIdx.y;
  const int n0 = nb*128;
  const int sel = n0 >> 10;
  const int nj0 = n0 & 1023;
  const int l15 = lane & 15, kc = lane >> 4;
  const int r8 = lane >> 3, c7 = lane & 7;

  const unsigned short* xbase = xb + (mb*128)*En;
  const unsigned short* wbase = Wt + n0*En;

  f32x4 acc[4][4];
#pragma unroll
  for (int i = 0; i < 4; i++)
#pragma unroll
    for (int j = 0; j < 4; j++) acc[i][j] = (f32x4){0.f,0.f,0.f,0.f};

  auto stage = [&](int buf, int k0){
#pragma unroll
    for (int i = 0; i < 4; i++){
      const int rb = w*32 + i*8;
      const int r = rb + r8;
      const int g = (c7 ^ r8) * 8;
      gl16(xbase + r*En + k0 + g, &As[buf][rb*64]);
      gl16(wbase + r*En + k0 + g, &Bs[buf][rb*64]);
    }
  };

  stage(0, 0);
  __syncthreads();

  for (int kt = 0; kt < 16; kt++){
    const int cur = kt & 1;
    if (kt < 15) stage(cur ^ 1, (kt + 1)*64);
    const unsigned short* Ac = &As[cur][0];
    const unsigned short* Bc = &Bs[cur][0];
#pragma unroll
    for (int ks = 0; ks < 2; ks++){
      short8 af[4], bf[4];
#pragma unroll
      for (int mf = 0; mf < 4; mf++){
        int ar = wr*64 + mf*16 + l15;
        af[mf] = *(const short8*)&Ac[ar*64 + (((ks*4 + kc) ^ (ar & 7))*8)];
      }
#pragma unroll
      for (int nf = 0; nf < 4; nf++){
        int br = wc*64 + nf*16 + l15;
        bf[nf] = *(const short8*)&Bc[br*64 + (((ks*4 + kc) ^ (br & 7))*8)];
      }
      __builtin_amdgcn_s_setprio(1);
#pragma unroll
      for (int mf = 0; mf < 4; mf++)
#pragma unroll
        for (int nf = 0; nf < 4; nf++)
          acc[mf][nf] = mfma16(af[mf], bf[nf], acc[mf][nf]);
      __builtin_amdgcn_s_setprio(0);
    }
    __syncthreads();
  }

  const int q4 = (lane >> 4)*4;
  const int bb = mb >> 4;
  const int tt0 = (mb*128) & 2047;

  if (sel == 2){
    unsigned short* tb = ((w < 2) ? &As[0][0] : &Bs[0][0]) + (w & 1)*8192;
#pragma unroll
    for (int nf = 0; nf < 4; nf++)
#pragma unroll
      for (int mf = 0; mf < 4; mf++){
        uint2 u;
        u.x = cvtpk(acc[mf][nf][0], acc[mf][nf][1]);
        u.y = cvtpk(acc[mf][nf][2], acc[mf][nf][3]);
        *(uint2*)&tb[(nf*16 + l15)*72 + mf*16 + q4] = u;
      }
    const int hh = (nj0 >> 6) + wc;
    unsigned short* vb = Vt + ((bb*Hn + hh)*HSn)*Tn + tt0 + wr*64;
#pragma unroll
    for (int i = 0; i < 8; i++){
      int rr = i*8 + r8;
      *(uint4w*)(vb + rr*Tn + c7*8) = *(const uint4w*)&tb[rr*72 + c7*8];
    }
  } else {
    unsigned short* Out = (sel == 1) ? Kb : Qb;
#pragma unroll
    for (int nf = 0; nf < 4; nf++){
      int jj = nj0 + wc*64 + nf*16 + l15;
      int hh = jj >> 6, dd = jj & 63;
#pragma unroll
      for (int mf = 0; mf < 4; mf++){
#pragma unroll
        for (int q = 0; q < 4; q++){
          int tt = tt0 + wr*64 + mf*16 + q4 + q;
          Out[((bb*Hn + hh)*Tn + tt)*HSn + dd] = f2b(acc[mf][nf][q]);
        }
      }
    }
  }
}

// ---------------- kernel 2: column exp-sums (softmax over QUERY axis) ----------
__global__ void k_colsum(const unsigned short* __restrict__ Qb,
                         const unsigned short* __restrict__ Kb,
                         float* __restrict__ Linv)
{
  __shared__ unsigned short Qs[2][128*64];
  __shared__ float Lred[64];
  const int bh = blockIdx.x, ipair = blockIdx.y;
  const int tid = threadIdx.x, lane = tid & 63, w = tid >> 6;
  const int l5 = lane >> 5, l31 = lane & 31;

  for (int ph = 0; ph < 2; ph++){
    const int sb = ph ? (31 - ipair) : ipair;
    const int s0 = sb * 64;

    short8 kf[2][4];
#pragma unroll
    for (int sf = 0; sf < 2; sf++){
      const unsigned short* kr = Kb + (bh*Tn + s0 + sf*32 + l31)*HSn + 8*l5;
#pragma unroll
      for (int ks = 0; ks < 4; ks++) kf[sf][ks] = *(const short8*)(kr + 16*ks);
    }

    float ls[2][16];
#pragma unroll
    for (int sf = 0; sf < 2; sf++)
#pragma unroll
      for (int r = 0; r < 16; r++) ls[sf][r] = 0.f;

    if (tid < 64) Lred[tid] = 0.f;

    const int t0s = (s0 >> 7) << 7;
    const int ntl = (Tn - t0s) >> 7;

    {
      const int c = lane & 7;
#pragma unroll
      for (int i = 0; i < 4; i++){
        int row = (w*4 + i)*8 + (lane >> 3);
        gl16(Qb + (bh*Tn + t0s + row)*HSn + ((c ^ (row & 7))*8), &Qs[0][(w*4 + i)*512]);
      }
    }
    asm volatile("s_waitcnt vmcnt(0)" ::: "memory");
    __syncthreads();

    for (int it = 0; it < ntl; it++){
      const int cur = it & 1;
      if (it + 1 < ntl){
        const int tn = t0s + (it + 1)*128;
        const int c = lane & 7;
#pragma unroll
        for (int i = 0; i < 4; i++){
          int row = (w*4 + i)*8 + (lane >> 3);
          gl16(Qb + (bh*Tn + tn + row)*HSn + ((c ^ (row & 7))*8), &Qs[cur^1][(w*4 + i)*512]);
        }
      }
      const int t0 = t0s + it*128;
      const int tw = t0 + 32*w;
      if (tw + 31 >= s0){
        f32x16 st[2];
#pragma unroll
        for (int sf = 0; sf < 2; sf++)
#pragma unroll
          for (int r = 0; r < 16; r++) st[sf][r] = 0.f;
        const int qrow = w*32 + l31;
        const unsigned short* Qc = &Qs[cur][qrow*64];
        const int sw = qrow & 7;
        __builtin_amdgcn_s_setprio(1);
#pragma unroll
        for (int ks = 0; ks < 4; ks++){
          short8 qb = *(const short8*)&Qc[((l5 + 2*ks) ^ sw)*8];
          st[0] = mfma32(kf[0][ks], qb, st[0]);
          st[1] = mfma32(kf[1][ks], qb, st[1]);
        }
        __builtin_amdgcn_s_setprio(0);
        const int tg = tw + l31;
        if (s0 + 63 <= tw){
#pragma unroll
          for (int sf = 0; sf < 2; sf++)
#pragma unroll
            for (int r = 0; r < 16; r++)
              ls[sf][r] += __builtin_amdgcn_exp2f(st[sf][r] * CEXP);
        } else {
#pragma unroll
          for (int sf = 0; sf < 2; sf++)
#pragma unroll
            for (int r = 0; r < 16; r++){
              int sg = s0 + 32*sf + (r & 3) + 8*(r >> 2) + 4*l5;
              float e = __builtin_amdgcn_exp2f(st[sf][r] * CEXP);
              ls[sf][r] += (tg >= sg) ? e : 0.f;
            }
        }
      }
      asm volatile("s_waitcnt vmcnt(0)" ::: "memory");
      __syncthreads();
    }

#pragma unroll
    for (int sf = 0; sf < 2; sf++)
#pragma unroll
      for (int r = 0; r < 16; r++){
        float v = ls[sf][r];
        v += __shfl_xor(v, 1);  v += __shfl_xor(v, 2);
        v += __shfl_xor(v, 4);  v += __shfl_xor(v, 8);
        v += __shfl_xor(v, 16);
        ls[sf][r] = v;
      }
    if (l31 == 0){
#pragma unroll
      for (int sf = 0; sf < 2; sf++)
#pragma unroll
        for (int r = 0; r < 16; r++){
          int sl = 32*sf + (r & 3) + 8*(r >> 2) + 4*l5;
          atomicAdd(&Lred[sl], ls[sf][r]);
        }
    }
    __syncthreads();
    if (tid < 64) Linv[bh*Tn + s0 + tid] = 1.0f / Lred[tid];
    if (ph == 0) __syncthreads();
  }
}

// ---------------- kernel 2b: Vt *= Linv ----------------
__global__ void k_vscale(unsigned short* __restrict__ Vt, const float* __restrict__ Linv){
  int i = (blockIdx.x * blockDim.x + threadIdx.x) * 8;
  int bh = i >> 17, t = i & 2047;
  short8 v = *(const short8*)(Vt + i);
  float4 L0 = *(const float4*)(Linv + bh*Tn + t);
  float4 L1 = *(const float4*)(Linv + bh*Tn + t + 4);
  unsigned int r0 = cvtpk(b2f((unsigned short)v[0])*L0.x, b2f((unsigned short)v[1])*L0.y);
  unsigned int r1 = cvtpk(b2f((unsigned short)v[2])*L0.z, b2f((unsigned short)v[3])*L0.w);
  unsigned int r2 = cvtpk(b2f((unsigned short)v[4])*L1.x, b2f((unsigned short)v[5])*L1.y);
  unsigned int r3 = cvtpk(b2f((unsigned short)v[6])*L1.z, b2f((unsigned short)v[7])*L1.w);
  uint4w o; o[0]=r0; o[1]=r1; o[2]=r2; o[3]=r3;
  *(uint4w*)(Vt + i) = o;
}

// ---------------- kernel 3: attention output (in-register P exchange) --------
// Grid (bh, 16): one 128-t-block per block, heavy blocks first. No P LDS:
// after swapped QK^T, P redistributed to PV B-frags via cvt_pk + permlane32_swap.
__global__ void __launch_bounds__(256, 4)
k_attn(const unsigned short* __restrict__ Qb,
       const unsigned short* __restrict__ Kb,
       const unsigned short* __restrict__ Vlt,
       unsigned short* __restrict__ Att)
{
  __shared__ unsigned short Ks[2][64*64];
  __shared__ unsigned short Vs[2][64*64];
  const int bh = blockIdx.x;
  const int tb = 15 - blockIdx.y;          // heavy blocks dispatch first
  const int t0 = tb * 128;
  const int tid = threadIdx.x, lane = tid & 63, w = tid >> 6;
  const int l5 = lane >> 5, l31 = lane & 31;
  const int c7 = lane & 7, r8 = lane >> 3;
  const int tbase = t0 + w*32;
  const int nt = 2*tb + 2;

  // hoist Q b-frags (B[k=d][col=t] read from Q row-major)
  short8 qf[4];
  {
    const unsigned short* qr = Qb + (bh*Tn + tbase + l31)*HSn + 8*l5;
#pragma unroll
    for (int ks = 0; ks < 4; ks++) qf[ks] = *(const short8*)(qr + 16*ks);
  }

  f32x16 oacc[2];
#pragma unroll
  for (int df = 0; df < 2; df++)
#pragma unroll
    for (int r = 0; r < 16; r++) oacc[df][r] = 0.f;

  // stage tile 0
#pragma unroll
  for (int i = 0; i < 2; i++){
    int row = (w*2 + i)*8 + r8;
    gl16(Kb  + (bh*Tn + row)*HSn + ((c7 ^ (row & 7))*8), &Ks[0][(w*2 + i)*512]);
    gl16(Vlt + (bh*HSn + row)*Tn + ((c7 ^ (row & 7))*8), &Vs[0][(w*2 + i)*512]);
  }
  asm volatile("s_waitcnt vmcnt(0)" ::: "memory");
  __syncthreads();

  for (int it = 0; it < nt; it++){
    const int cur = it & 1;
    if (it + 1 < nt){
      const int sn = (it + 1)*64;
#pragma unroll
      for (int i = 0; i < 2; i++){
        int row = (w*2 + i)*8 + r8;
        gl16(Kb  + (bh*Tn + sn + row)*HSn + ((c7 ^ (row & 7))*8), &Ks[cur^1][(w*2 + i)*512]);
        gl16(Vlt + (bh*HSn + row)*Tn + sn + ((c7 ^ (row & 7))*8), &Vs[cur^1][(w*2 + i)*512]);
      }
    }
    const int s0 = it * 64;
    if (s0 <= tbase + 31){
      const unsigned short* Kc = &Ks[cur][0];
      // S^T = K·Q^T  (8 mfma32)
      f32x16 st[2];
#pragma unroll
      for (int sf = 0; sf < 2; sf++)
#pragma unroll
        for (int r = 0; r < 16; r++) st[sf][r] = 0.f;
      __builtin_amdgcn_s_setprio(1);
#pragma unroll
      for (int ks = 0; ks < 4; ks++){
#pragma unroll
        for (int sf = 0; sf < 2; sf++){
          int row = sf*32 + l31;
          short8 ka = *(const short8*)&Kc[row*64 + (((l5 + 2*ks) ^ (row & 7))*8)];
          st[sf] = mfma32(ka, qf[ks], st[sf]);
        }
      }
      __builtin_amdgcn_s_setprio(0);

      // P = exp2(S*CEXP), causal mask (t >= s)
      const int tg = tbase + l31;
      const bool interior = (s0 + 63 <= tbase);
#pragma unroll
      for (int sf = 0; sf < 2; sf++){
#pragma unroll
        for (int r = 0; r < 16; r++){
          float e = __builtin_amdgcn_exp2f(st[sf][r] * CEXP);
          if (!interior){
            int sg = s0 + 32*sf + (r & 3) + 8*(r >> 2) + 4*l5;
            e = (tg >= sg) ? e : 0.f;
          }
          st[sf][r] = e;
        }
      }

      // in-register redistribute: P rows -> PV B-frags
      // pb[sf*2+q] = {ax', ay', bx', by'} after permlane32_swap
      short8 pb[4];
#pragma unroll
      for (int sf = 0; sf < 2; sf++){
#pragma unroll
        for (int q = 0; q < 2; q++){
          unsigned int ax = cvtpk(st[sf][8*q+0], st[sf][8*q+1]);
          unsigned int ay = cvtpk(st[sf][8*q+2], st[sf][8*q+3]);
          unsigned int bx = cvtpk(st[sf][8*q+4], st[sf][8*q+5]);
          unsigned int by = cvtpk(st[sf][8*q+6], st[sf][8*q+7]);
          asm("v_permlane32_swap_b32 %0, %1" : "+v"(ax), "+v"(bx));
          asm("v_permlane32_swap_b32 %0, %1" : "+v"(ay), "+v"(by));
          union { unsigned int u[4]; short8 s; } pk;
          pk.u[0] = ax; pk.u[1] = ay; pk.u[2] = bx; pk.u[3] = by;
          pb[sf*2 + q] = pk.s;
        }
      }

      // PV: out^T += Vlt · P^T  (8 mfma32)
      const unsigned short* Vc = &Vs[cur][0];
      __builtin_amdgcn_s_setprio(1);
#pragma unroll
      for (int ks = 0; ks < 4; ks++){
#pragma unroll
        for (int df = 0; df < 2; df++){
          int row = df*32 + l31;
          short8 va = *(const short8*)&Vc[row*64 + (((l5 + 2*ks) ^ (row & 7))*8)];
          oacc[df] = mfma32(va, pb[ks], oacc[df]);
        }
      }
      __builtin_amdgcn_s_setprio(0);
    }
    asm volatile("s_waitcnt vmcnt(0)" ::: "memory");
    __syncthreads();
  }

  // store out^T fragment: lane holds 16 d-values for t = tbase+l31
  {
    const int tg = tbase + l31;
    unsigned short* ob = Att + (bh*Tn + tg)*HSn;
#pragma unroll
    for (int df = 0; df < 2; df++)
#pragma unroll
      for (int r2 = 0; r2 < 4; r2++){
        uint2 u;
        u.x = cvtpk(oacc[df][r2*4+0], oacc[df][r2*4+1]);
        u.y = cvtpk(oacc[df][r2*4+2], oacc[df][r2*4+3]);
        *(uint2*)&ob[32*df + 8*r2 + 4*l5] = u;
      }
  }
}

// ---------------- kernel 4: output projection (2-phase pipelined) ----------
__global__ void __launch_bounds__(256, 2)
k_oproj(const unsigned short* __restrict__ Att,
        const unsigned short* __restrict__ Wot,
        const float* __restrict__ bo, float* __restrict__ out)
{
  __shared__ unsigned short As[2][128*64];
  __shared__ unsigned short Bs[2][128*64];
  const int tid = threadIdx.x, lane = tid & 63, w = tid >> 6;
  const int wr = w >> 1, wc = w & 1;
  const int mb = blockIdx.x, nb = blockIdx.y;
  const int n0 = nb*128;
  const int l15 = lane & 15, kc = lane >> 4;
  const int r8 = lane >> 3, c7 = lane & 7;
  const int bb = mb >> 4;
  const int t0 = (mb*128) & 2047;

  f32x4 acc[4][4];
#pragma unroll
  for (int i = 0; i < 4; i++)
#pragma unroll
    for (int j = 0; j < 4; j++) acc[i][j] = (f32x4){0.f,0.f,0.f,0.f};

  const unsigned short* wbase = Wot + n0*En;

  auto stage = [&](int buf, int k0){
    const int hh = k0 >> 6;
    const unsigned short* abase = Att + ((bb*Hn + hh)*Tn + t0)*HSn;
#pragma unroll
    for (int i = 0; i < 4; i++){
      const int rb = w*32 + i*8;
      const int r = rb + r8;
      const int g = (c7 ^ r8) * 8;
      gl16(abase + r*HSn + g, &As[buf][rb*64]);
      gl16(wbase + r*En + k0 + g, &Bs[buf][rb*64]);
    }
  };

  stage(0, 0);
  __syncthreads();

  for (int kt = 0; kt < 16; kt++){
    const int cur = kt & 1;
    if (kt < 15) stage(cur ^ 1, (kt + 1)*64);
    const unsigned short* Ac = &As[cur][0];
    const unsigned short* Bc = &Bs[cur][0];
#pragma unroll
    for (int ks = 0; ks < 2; ks++){
      short8 af[4], bf[4];
#pragma unroll
      for (int mf = 0; mf < 4; mf++){
        int ar = wr*64 + mf*16 + l15;
        af[mf] = *(const short8*)&Ac[ar*64 + (((ks*4 + kc) ^ (ar & 7))*8)];
      }
#pragma unroll
      for (int nf = 0; nf < 4; nf++){
        int br = wc*64 + nf*16 + l15;
        bf[nf] = *(const short8*)&Bc[br*64 + (((ks*4 + kc) ^ (br & 7))*8)];
      }
      __builtin_amdgcn_s_setprio(1);
#pragma unroll
      for (int mf = 0; mf < 4; mf++)
#pragma unroll
        for (int nf = 0; nf < 4; nf++)
          acc[mf][nf] = mfma16(af[mf], bf[nf], acc[mf][nf]);
      __builtin_amdgcn_s_setprio(0);
    }
    __syncthreads();
  }

  const int q4 = (lane >> 4)*4;
#pragma unroll
  for (int nf = 0; nf < 4; nf++){
    int j = n0 + wc*64 + nf*16 + l15;
    float bias = bo[j];
#pragma unroll
    for (int mf = 0; mf < 4; mf++){
#pragma unroll
      for (int q = 0; q < 4; q++){
        int rr = mb*128 + wr*64 + mf*16 + q4 + q;
        out[rr*En + j] = acc[mf][nf][q] + bias;
      }
    }
  }
}

extern "C" void kernel_launch(void* const* d_in, const int* in_sizes, int n_in,
                              void* d_out, int out_size, void* d_ws, size_t ws_size,
                              hipStream_t stream)
{
  (void)in_sizes; (void)n_in; (void)out_size; (void)ws_size;
  const float* x  = (const float*)d_in[0];
  const float* Wq = (const float*)d_in[1];
  const float* Wk = (const float*)d_in[2];
  const float* Wv = (const float*)d_in[3];
  const float* Wo = (const float*)d_in[4];
  const float* bo = (const float*)d_in[5];
  float* out = (float*)d_out;

  // ws layout (MB): Qb[0,16) Kb[16,32) Vt[32,48) xb/Att[48,64) Wt[64,70) Wot[70,72) Linv[72,72.5)
  uint8_t* w = (uint8_t*)d_ws;
  unsigned short* Qb  = (unsigned short*)(w);
  unsigned short* Kb  = (unsigned short*)(w + (16u << 20));
  unsigned short* Vt  = (unsigned short*)(w + (32u << 20));
  unsigned short* xb  = (unsigned short*)(w + (48u << 20));
  unsigned short* Att = (unsigned short*)(w + (48u << 20));
  unsigned short* Wt  = (unsigned short*)(w + (64u << 20));
  unsigned short* Wot = (unsigned short*)(w + (70u << 20));
  float* Linv         = (float*)(w + (72u << 20));

  hipLaunchKernelGGL(k_cvt_x,  dim3(4096),    dim3(256), 0, stream, x, xb);
  hipLaunchKernelGGL(k_wT,     dim3(16, 64),  dim3(256), 0, stream, Wq, Wk, Wv, Wo, Wt, Wot);
  hipLaunchKernelGGL(k_qkv,    dim3(64, 24),  dim3(256), 0, stream, xb, Wt, Qb, Kb, Vt);
  hipLaunchKernelGGL(k_colsum, dim3(64, 16),  dim3(256), 0, stream, Qb, Kb, Linv);
  hipLaunchKernelGGL(k_vscale, dim3(4096),    dim3(256), 0, stream, Vt, Linv);
  hipLaunchKernelGGL(k_attn,   dim3(64, 16),  dim3(256), 0, stream, Qb, Kb, Vt, Att);
  hipLaunchKernelGGL(k_oproj,  dim3(64, 8),   dim3(256), 0, stream, Att, Wot, bo, out);
}

// Round 6
// 209.070 us; speedup vs baseline: 1.5005x; 1.0040x over previous
//
#include <hip/hip_runtime.h>
#include <stdint.h>

// Problem constants
#define Bn 4
#define Tn 2048
#define En 1024
#define Hn 16
#define HSn 64
#define BHn (Bn*Hn)   // 64
#define NRn (Bn*Tn)   // 8192

// exp(x/32) = exp2(x * 0.03125 * log2(e))
#define CEXP 0.0450840831f

typedef __attribute__((ext_vector_type(8))) short short8;
typedef __attribute__((ext_vector_type(4))) float f32x4;
typedef __attribute__((ext_vector_type(16))) float f32x16;
typedef __attribute__((ext_vector_type(4))) unsigned int uint4w;

__device__ __forceinline__ unsigned short f2b(float f){
  union { float f; unsigned int u; } c; c.f = f;
  unsigned int u = c.u + 0x7FFFu + ((c.u >> 16) & 1u);
  return (unsigned short)(u >> 16);
}
__device__ __forceinline__ float b2f(unsigned short s){
  union { unsigned int u; float f; } c; c.u = ((unsigned int)s) << 16;
  return c.f;
}
__device__ __forceinline__ unsigned int cvtpk(float lo, float hi){
  unsigned int r;
  asm("v_cvt_pk_bf16_f32 %0, %1, %2" : "=v"(r) : "v"(lo), "v"(hi));
  return r;
}
__device__ __forceinline__ f32x4 mfma16(short8 a, short8 b, f32x4 c){
  return __builtin_amdgcn_mfma_f32_16x16x32_bf16(a, b, c, 0, 0, 0);
}
__device__ __forceinline__ f32x16 mfma32(short8 a, short8 b, f32x16 c){
  return __builtin_amdgcn_mfma_f32_32x32x16_bf16(a, b, c, 0, 0, 0);
}
__device__ __forceinline__ void gl16(const void* g, void* s){
  __builtin_amdgcn_global_load_lds((const __attribute__((address_space(1))) unsigned int*)g,
                                   (__attribute__((address_space(3))) unsigned int*)s, 16, 0, 0);
}
#define FENCE()    asm volatile("" ::: "memory")
#define WAITV(N)   asm volatile("s_waitcnt vmcnt(" #N ")" ::: "memory")
#define SBAR()     __builtin_amdgcn_s_barrier()

// ---------------- kernel 0: x fp32 -> bf16 ----------------
__global__ void k_cvt_x(const float* __restrict__ x, unsigned short* __restrict__ xb){
  int i = (blockIdx.x * blockDim.x + threadIdx.x) * 8;
  float4 a = *(const float4*)(x + i);
  float4 b = *(const float4*)(x + i + 4);
  alignas(16) unsigned short o[8] = {f2b(a.x),f2b(a.y),f2b(a.z),f2b(a.w),
                                     f2b(b.x),f2b(b.y),f2b(b.z),f2b(b.w)};
  *(uint4w*)(xb + i) = *(const uint4w*)o;
}

// ---------------- kernel 0b: weight convert+transpose ----------------
__global__ void k_wT(const float* __restrict__ Wq, const float* __restrict__ Wk,
                     const float* __restrict__ Wv, const float* __restrict__ Wo,
                     unsigned short* __restrict__ Wt, unsigned short* __restrict__ Wot)
{
  __shared__ unsigned short Ls[64*80];
  const int tid = threadIdx.x;
  const int ey = blockIdx.x, jt = blockIdx.y;
  const int e0 = ey*64;
  const float* src; int R, c0; unsigned short* outp;
  if (jt < 48){
    int sel = jt >> 4, h = jt & 15;
    const float* W = (sel==0)?Wq:((sel==1)?Wk:Wv);
    src = W + h*(En*HSn); R = HSn; c0 = 0;
    outp = Wt + jt*64*En;
  } else {
    src = Wo; R = En; c0 = (jt-48)*64;
    outp = Wot + (jt-48)*64*En;
  }
  {
    const int e = tid >> 2, cq = (tid & 3)*16;
    const float* p = src + (e0 + e)*R + c0 + cq;
    float vv[16];
    *(float4*)&vv[0]  = *(const float4*)(p);
    *(float4*)&vv[4]  = *(const float4*)(p+4);
    *(float4*)&vv[8]  = *(const float4*)(p+8);
    *(float4*)&vv[12] = *(const float4*)(p+12);
#pragma unroll
    for (int i = 0; i < 16; i++) Ls[(cq+i)*80 + e] = f2b(vv[i]);
  }
  __syncthreads();
  {
    const int c8 = tid & 7, r = tid >> 3;
#pragma unroll
    for (int rr0 = 0; rr0 < 2; rr0++){
      int rr = r + rr0*32;
      *(uint4w*)(outp + rr*En + e0 + c8*8) = *(const uint4w*)&Ls[rr*80 + c8*8];
    }
  }
}

// ---------------- kernel 1: QKV projection GEMM (depth-2 counted-vmcnt) ------
__global__ void __launch_bounds__(256, 2)
k_qkv(const unsigned short* __restrict__ xb,
      const unsigned short* __restrict__ Wt,
      unsigned short* __restrict__ Qb, unsigned short* __restrict__ Kb,
      unsigned short* __restrict__ Vt)
{
  __shared__ unsigned short As[2][128*64];
  __shared__ unsigned short Bs[2][128*64];
  const int tid = threadIdx.x, lane = tid & 63, w = tid >> 6;
  const int wr = w >> 1, wc = w & 1;
  const int mb = blockIdx.x, nb = blockIdx.y;
  const int n0 = nb*128;
  const int sel = n0 >> 10;
  const int nj0 = n0 & 1023;
  const int l15 = lane & 15, kc = lane >> 4;
  const int r8 = lane >> 3, c7 = lane & 7;

  const unsigned short* xbase = xb + (mb*128)*En;
  const unsigned short* wbase = Wt + n0*En;

  f32x4 acc[4][4];
#pragma unroll
  for (int i = 0; i < 4; i++)
#pragma unroll
    for (int j = 0; j < 4; j++) acc[i][j] = (f32x4){0.f,0.f,0.f,0.f};

  auto stage = [&](int buf, int k0){
#pragma unroll
    for (int i = 0; i < 4; i++){
      const int rb = w*32 + i*8;
      const int r = rb + r8;
      const int g = (c7 ^ r8) * 8;
      gl16(xbase + r*En + k0 + g, &As[buf][rb*64]);
      gl16(wbase + r*En + k0 + g, &Bs[buf][rb*64]);
    }
  };
  auto compute = [&](int cur){
    const unsigned short* Ac = &As[cur][0];
    const unsigned short* Bc = &Bs[cur][0];
#pragma unroll
    for (int ks = 0; ks < 2; ks++){
      short8 af[4], bf[4];
#pragma unroll
      for (int mf = 0; mf < 4; mf++){
        int ar = wr*64 + mf*16 + l15;
        af[mf] = *(const short8*)&Ac[ar*64 + (((ks*4 + kc) ^ (ar & 7))*8)];
      }
#pragma unroll
      for (int nf = 0; nf < 4; nf++){
        int br = wc*64 + nf*16 + l15;
        bf[nf] = *(const short8*)&Bc[br*64 + (((ks*4 + kc) ^ (br & 7))*8)];
      }
      __builtin_amdgcn_s_setprio(1);
#pragma unroll
      for (int mf = 0; mf < 4; mf++)
#pragma unroll
        for (int nf = 0; nf < 4; nf++)
          acc[mf][nf] = mfma16(af[mf], bf[nf], acc[mf][nf]);
      __builtin_amdgcn_s_setprio(0);
    }
  };

  stage(0, 0);
  stage(1, 64);
  WAITV(8); SBAR();

  for (int kt = 0; kt < 16; kt++){
    const int cur = kt & 1;
    compute(cur);
    FENCE(); SBAR();
    if (kt < 14){
      stage(cur, (kt + 2)*64);
      WAITV(8); SBAR();
    } else if (kt == 14){
      WAITV(0); SBAR();
    }
  }
  __syncthreads();

  const int q4 = (lane >> 4)*4;
  const int bb = mb >> 4;
  const int tt0 = (mb*128) & 2047;

  if (sel == 2){
    unsigned short* tb = ((w < 2) ? &As[0][0] : &Bs[0][0]) + (w & 1)*8192;
#pragma unroll
    for (int nf = 0; nf < 4; nf++)
#pragma unroll
      for (int mf = 0; mf < 4; mf++){
        uint2 u;
        u.x = cvtpk(acc[mf][nf][0], acc[mf][nf][1]);
        u.y = cvtpk(acc[mf][nf][2], acc[mf][nf][3]);
        *(uint2*)&tb[(nf*16 + l15)*72 + mf*16 + q4] = u;
      }
    const int hh = (nj0 >> 6) + wc;
    unsigned short* vb = Vt + ((bb*Hn + hh)*HSn)*Tn + tt0 + wr*64;
#pragma unroll
    for (int i = 0; i < 8; i++){
      int rr = i*8 + r8;
      *(uint4w*)(vb + rr*Tn + c7*8) = *(const uint4w*)&tb[rr*72 + c7*8];
    }
  } else {
    unsigned short* Out = (sel == 1) ? Kb : Qb;
#pragma unroll
    for (int nf = 0; nf < 4; nf++){
      int jj = nj0 + wc*64 + nf*16 + l15;
      int hh = jj >> 6, dd = jj & 63;
#pragma unroll
      for (int mf = 0; mf < 4; mf++){
#pragma unroll
        for (int q = 0; q < 4; q++){
          int tt = tt0 + wr*64 + mf*16 + q4 + q;
          Out[((bb*Hn + hh)*Tn + tt)*HSn + dd] = f2b(acc[mf][nf][q]);
        }
      }
    }
  }
}

// ---------------- kernel 2: column exp-sums (depth-2 counted-vmcnt) ----------
__global__ void k_colsum(const unsigned short* __restrict__ Qb,
                         const unsigned short* __restrict__ Kb,
                         float* __restrict__ Linv)
{
  __shared__ unsigned short Qs[2][128*64];
  __shared__ float Lred[64];
  const int bh = blockIdx.x, ipair = blockIdx.y;
  const int tid = threadIdx.x, lane = tid & 63, w = tid >> 6;
  const int l5 = lane >> 5, l31 = lane & 31;

  for (int ph = 0; ph < 2; ph++){
    const int sb = ph ? (31 - ipair) : ipair;
    const int s0 = sb * 64;

    short8 kf[2][4];
#pragma unroll
    for (int sf = 0; sf < 2; sf++){
      const unsigned short* kr = Kb + (bh*Tn + s0 + sf*32 + l31)*HSn + 8*l5;
#pragma unroll
      for (int ks = 0; ks < 4; ks++) kf[sf][ks] = *(const short8*)(kr + 16*ks);
    }

    float ls[2][16];
#pragma unroll
    for (int sf = 0; sf < 2; sf++)
#pragma unroll
      for (int r = 0; r < 16; r++) ls[sf][r] = 0.f;

    if (tid < 64) Lred[tid] = 0.f;

    const int t0s = (s0 >> 7) << 7;
    const int ntl = (Tn - t0s) >> 7;

    auto stageQ = [&](int buf, int tg0){
      const int c = lane & 7;
#pragma unroll
      for (int i = 0; i < 4; i++){
        int row = (w*4 + i)*8 + (lane >> 3);
        gl16(Qb + (bh*Tn + tg0 + row)*HSn + ((c ^ (row & 7))*8), &Qs[buf][(w*4 + i)*512]);
      }
    };

    stageQ(0, t0s);
    if (ntl > 1){ stageQ(1, t0s + 128); WAITV(4); }
    else        { WAITV(0); }
    SBAR();

    for (int it = 0; it < ntl; it++){
      const int cur = it & 1;
      const int t0 = t0s + it*128;
      const int tw = t0 + 32*w;
      if (tw + 31 >= s0){
        f32x16 st[2];
#pragma unroll
        for (int sf = 0; sf < 2; sf++)
#pragma unroll
          for (int r = 0; r < 16; r++) st[sf][r] = 0.f;
        const int qrow = w*32 + l31;
        const unsigned short* Qc = &Qs[cur][qrow*64];
        const int sw = qrow & 7;
        __builtin_amdgcn_s_setprio(1);
#pragma unroll
        for (int ks = 0; ks < 4; ks++){
          short8 qb = *(const short8*)&Qc[((l5 + 2*ks) ^ sw)*8];
          st[0] = mfma32(kf[0][ks], qb, st[0]);
          st[1] = mfma32(kf[1][ks], qb, st[1]);
        }
        __builtin_amdgcn_s_setprio(0);
        const int tg = tw + l31;
        if (s0 + 63 <= tw){
#pragma unroll
          for (int sf = 0; sf < 2; sf++)
#pragma unroll
            for (int r = 0; r < 16; r++)
              ls[sf][r] += __builtin_amdgcn_exp2f(st[sf][r] * CEXP);
        } else {
#pragma unroll
          for (int sf = 0; sf < 2; sf++)
#pragma unroll
            for (int r = 0; r < 16; r++){
              int sg = s0 + 32*sf + (r & 3) + 8*(r >> 2) + 4*l5;
              float e = __builtin_amdgcn_exp2f(st[sf][r] * CEXP);
              ls[sf][r] += (tg >= sg) ? e : 0.f;
            }
        }
      }
      FENCE(); SBAR();
      if (it + 2 < ntl){
        stageQ(cur, t0s + (it + 2)*128);
        WAITV(4); SBAR();
      } else if (it + 2 == ntl){
        WAITV(0); SBAR();
      }
    }

#pragma unroll
    for (int sf = 0; sf < 2; sf++)
#pragma unroll
      for (int r = 0; r < 16; r++){
        float v = ls[sf][r];
        v += __shfl_xor(v, 1);  v += __shfl_xor(v, 2);
        v += __shfl_xor(v, 4);  v += __shfl_xor(v, 8);
        v += __shfl_xor(v, 16);
        ls[sf][r] = v;
      }
    if (l31 == 0){
#pragma unroll
      for (int sf = 0; sf < 2; sf++)
#pragma unroll
        for (int r = 0; r < 16; r++){
          int sl = 32*sf + (r & 3) + 8*(r >> 2) + 4*l5;
          atomicAdd(&Lred[sl], ls[sf][r]);
        }
    }
    __syncthreads();
    if (tid < 64) Linv[bh*Tn + s0 + tid] = 1.0f / Lred[tid];
    if (ph == 0) __syncthreads();
  }
}

// ---------------- kernel 2b: Vt *= Linv ----------------
__global__ void k_vscale(unsigned short* __restrict__ Vt, const float* __restrict__ Linv){
  int i = (blockIdx.x * blockDim.x + threadIdx.x) * 8;
  int bh = i >> 17, t = i & 2047;
  short8 v = *(const short8*)(Vt + i);
  float4 L0 = *(const float4*)(Linv + bh*Tn + t);
  float4 L1 = *(const float4*)(Linv + bh*Tn + t + 4);
  unsigned int r0 = cvtpk(b2f((unsigned short)v[0])*L0.x, b2f((unsigned short)v[1])*L0.y);
  unsigned int r1 = cvtpk(b2f((unsigned short)v[2])*L0.z, b2f((unsigned short)v[3])*L0.w);
  unsigned int r2 = cvtpk(b2f((unsigned short)v[4])*L1.x, b2f((unsigned short)v[5])*L1.y);
  unsigned int r3 = cvtpk(b2f((unsigned short)v[6])*L1.z, b2f((unsigned short)v[7])*L1.w);
  uint4w o; o[0]=r0; o[1]=r1; o[2]=r2; o[3]=r3;
  *(uint4w*)(Vt + i) = o;
}

// ---------------- kernel 3: attention output (depth-2 counted-vmcnt) ---------
__global__ void __launch_bounds__(256, 4)
k_attn(const unsigned short* __restrict__ Qb,
       const unsigned short* __restrict__ Kb,
       const unsigned short* __restrict__ Vlt,
       unsigned short* __restrict__ Att)
{
  __shared__ unsigned short Ks[2][64*64];
  __shared__ unsigned short Vs[2][64*64];
  const int bh = blockIdx.x;
  const int tb = 15 - blockIdx.y;          // heavy blocks dispatch first
  const int t0 = tb * 128;
  const int tid = threadIdx.x, lane = tid & 63, w = tid >> 6;
  const int l5 = lane >> 5, l31 = lane & 31;
  const int c7 = lane & 7, r8 = lane >> 3;
  const int tbase = t0 + w*32;
  const int nt = 2*tb + 2;

  short8 qf[4];
  {
    const unsigned short* qr = Qb + (bh*Tn + tbase + l31)*HSn + 8*l5;
#pragma unroll
    for (int ks = 0; ks < 4; ks++) qf[ks] = *(const short8*)(qr + 16*ks);
  }

  f32x16 oacc[2];
#pragma unroll
  for (int df = 0; df < 2; df++)
#pragma unroll
    for (int r = 0; r < 16; r++) oacc[df][r] = 0.f;

  auto stageKV = [&](int buf, int sn){
#pragma unroll
    for (int i = 0; i < 2; i++){
      int row = (w*2 + i)*8 + r8;
      gl16(Kb  + (bh*Tn + sn + row)*HSn + ((c7 ^ (row & 7))*8), &Ks[buf][(w*2 + i)*512]);
      gl16(Vlt + (bh*HSn + row)*Tn + sn + ((c7 ^ (row & 7))*8), &Vs[buf][(w*2 + i)*512]);
    }
  };

  stageKV(0, 0);
  stageKV(1, 64);
  WAITV(4); SBAR();

  for (int it = 0; it < nt; it++){
    const int cur = it & 1;
    const int s0 = it * 64;
    if (s0 <= tbase + 31){
      const unsigned short* Kc = &Ks[cur][0];
      f32x16 st[2];
#pragma unroll
      for (int sf = 0; sf < 2; sf++)
#pragma unroll
        for (int r = 0; r < 16; r++) st[sf][r] = 0.f;
      __builtin_amdgcn_s_setprio(1);
#pragma unroll
      for (int ks = 0; ks < 4; ks++){
#pragma unroll
        for (int sf = 0; sf < 2; sf++){
          int row = sf*32 + l31;
          short8 ka = *(const short8*)&Kc[row*64 + (((l5 + 2*ks) ^ (row & 7))*8)];
          st[sf] = mfma32(ka, qf[ks], st[sf]);
        }
      }
      __builtin_amdgcn_s_setprio(0);

      const int tg = tbase + l31;
      const bool interior = (s0 + 63 <= tbase);
#pragma unroll
      for (int sf = 0; sf < 2; sf++){
#pragma unroll
        for (int r = 0; r < 16; r++){
          float e = __builtin_amdgcn_exp2f(st[sf][r] * CEXP);
          if (!interior){
            int sg = s0 + 32*sf + (r & 3) + 8*(r >> 2) + 4*l5;
            e = (tg >= sg) ? e : 0.f;
          }
          st[sf][r] = e;
        }
      }

      short8 pb[4];
#pragma unroll
      for (int sf = 0; sf < 2; sf++){
#pragma unroll
        for (int q = 0; q < 2; q++){
          unsigned int ax = cvtpk(st[sf][8*q+0], st[sf][8*q+1]);
          unsigned int ay = cvtpk(st[sf][8*q+2], st[sf][8*q+3]);
          unsigned int bx = cvtpk(st[sf][8*q+4], st[sf][8*q+5]);
          unsigned int by = cvtpk(st[sf][8*q+6], st[sf][8*q+7]);
          asm("v_permlane32_swap_b32 %0, %1" : "+v"(ax), "+v"(bx));
          asm("v_permlane32_swap_b32 %0, %1" : "+v"(ay), "+v"(by));
          union { unsigned int u[4]; short8 s; } pk;
          pk.u[0] = ax; pk.u[1] = ay; pk.u[2] = bx; pk.u[3] = by;
          pb[sf*2 + q] = pk.s;
        }
      }

      const unsigned short* Vc = &Vs[cur][0];
      __builtin_amdgcn_s_setprio(1);
#pragma unroll
      for (int ks = 0; ks < 4; ks++){
#pragma unroll
        for (int df = 0; df < 2; df++){
          int row = df*32 + l31;
          short8 va = *(const short8*)&Vc[row*64 + (((l5 + 2*ks) ^ (row & 7))*8)];
          oacc[df] = mfma32(va, pb[ks], oacc[df]);
        }
      }
      __builtin_amdgcn_s_setprio(0);
    }
    FENCE(); SBAR();
    if (it + 2 < nt){
      stageKV(cur, (it + 2)*64);
      WAITV(4); SBAR();
    } else if (it + 2 == nt){
      WAITV(0); SBAR();
    }
  }

  {
    const int tg = tbase + l31;
    unsigned short* ob = Att + (bh*Tn + tg)*HSn;
#pragma unroll
    for (int df = 0; df < 2; df++)
#pragma unroll
      for (int r2 = 0; r2 < 4; r2++){
        uint2 u;
        u.x = cvtpk(oacc[df][r2*4+0], oacc[df][r2*4+1]);
        u.y = cvtpk(oacc[df][r2*4+2], oacc[df][r2*4+3]);
        *(uint2*)&ob[32*df + 8*r2 + 4*l5] = u;
      }
  }
}

// ---------------- kernel 4: output projection (depth-2 counted-vmcnt) --------
__global__ void __launch_bounds__(256, 2)
k_oproj(const unsigned short* __restrict__ Att,
        const unsigned short* __restrict__ Wot,
        const float* __restrict__ bo, float* __restrict__ out)
{
  __shared__ unsigned short As[2][128*64];
  __shared__ unsigned short Bs[2][128*64];
  const int tid = threadIdx.x, lane = tid & 63, w = tid >> 6;
  const int wr = w >> 1, wc = w & 1;
  const int mb = blockIdx.x, nb = blockIdx.y;
  const int n0 = nb*128;
  const int l15 = lane & 15, kc = lane >> 4;
  const int r8 = lane >> 3, c7 = lane & 7;
  const int bb = mb >> 4;
  const int t0 = (mb*128) & 2047;

  f32x4 acc[4][4];
#pragma unroll
  for (int i = 0; i < 4; i++)
#pragma unroll
    for (int j = 0; j < 4; j++) acc[i][j] = (f32x4){0.f,0.f,0.f,0.f};

  const unsigned short* wbase = Wot + n0*En;

  auto stage = [&](int buf, int k0){
    const int hh = k0 >> 6;
    const unsigned short* abase = Att + ((bb*Hn + hh)*Tn + t0)*HSn;
#pragma unroll
    for (int i = 0; i < 4; i++){
      const int rb = w*32 + i*8;
      const int r = rb + r8;
      const int g = (c7 ^ r8) * 8;
      gl16(abase + r*HSn + g, &As[buf][rb*64]);
      gl16(wbase + r*En + k0 + g, &Bs[buf][rb*64]);
    }
  };
  auto compute = [&](int cur){
    const unsigned short* Ac = &As[cur][0];
    const unsigned short* Bc = &Bs[cur][0];
#pragma unroll
    for (int ks = 0; ks < 2; ks++){
      short8 af[4], bf[4];
#pragma unroll
      for (int mf = 0; mf < 4; mf++){
        int ar = wr*64 + mf*16 + l15;
        af[mf] = *(const short8*)&Ac[ar*64 + (((ks*4 + kc) ^ (ar & 7))*8)];
      }
#pragma unroll
      for (int nf = 0; nf < 4; nf++){
        int br = wc*64 + nf*16 + l15;
        bf[nf] = *(const short8*)&Bc[br*64 + (((ks*4 + kc) ^ (br & 7))*8)];
      }
      __builtin_amdgcn_s_setprio(1);
#pragma unroll
      for (int mf = 0; mf < 4; mf++)
#pragma unroll
        for (int nf = 0; nf < 4; nf++)
          acc[mf][nf] = mfma16(af[mf], bf[nf], acc[mf][nf]);
      __builtin_amdgcn_s_setprio(0);
    }
  };

  stage(0, 0);
  stage(1, 64);
  WAITV(8); SBAR();

  for (int kt = 0; kt < 16; kt++){
    const int cur = kt & 1;
    compute(cur);
    FENCE(); SBAR();
    if (kt < 14){
      stage(cur, (kt + 2)*64);
      WAITV(8); SBAR();
    } else if (kt == 14){
      WAITV(0); SBAR();
    }
  }

  const int q4 = (lane >> 4)*4;
#pragma unroll
  for (int nf = 0; nf < 4; nf++){
    int j = n0 + wc*64 + nf*16 + l15;
    float bias = bo[j];
#pragma unroll
    for (int mf = 0; mf < 4; mf++){
#pragma unroll
      for (int q = 0; q < 4; q++){
        int rr = mb*128 + wr*64 + mf*16 + q4 + q;
        out[rr*En + j] = acc[mf][nf][q] + bias;
      }
    }
  }
}

extern "C" void kernel_launch(void* const* d_in, const int* in_sizes, int n_in,
                              void* d_out, int out_size, void* d_ws, size_t ws_size,
                              hipStream_t stream)
{
  (void)in_sizes; (void)n_in; (void)out_size; (void)ws_size;
  const float* x  = (const float*)d_in[0];
  const float* Wq = (const float*)d_in[1];
  const float* Wk = (const float*)d_in[2];
  const float* Wv = (const float*)d_in[3];
  const float* Wo = (const float*)d_in[4];
  const float* bo = (const float*)d_in[5];
  float* out = (float*)d_out;

  // ws layout (MB): Qb[0,16) Kb[16,32) Vt[32,48) xb/Att[48,64) Wt[64,70) Wot[70,72) Linv[72,72.5)
  uint8_t* w = (uint8_t*)d_ws;
  unsigned short* Qb  = (unsigned short*)(w);
  unsigned short* Kb  = (unsigned short*)(w + (16u << 20));
  unsigned short* Vt  = (unsigned short*)(w + (32u << 20));
  unsigned short* xb  = (unsigned short*)(w + (48u << 20));
  unsigned short* Att = (unsigned short*)(w + (48u << 20));
  unsigned short* Wt  = (unsigned short*)(w + (64u << 20));
  unsigned short* Wot = (unsigned short*)(w + (70u << 20));
  float* Linv         = (float*)(w + (72u << 20));

  hipLaunchKernelGGL(k_cvt_x,  dim3(4096),    dim3(256), 0, stream, x, xb);
  hipLaunchKernelGGL(k_wT,     dim3(16, 64),  dim3(256), 0, stream, Wq, Wk, Wv, Wo, Wt, Wot);
  hipLaunchKernelGGL(k_qkv,    dim3(64, 24),  dim3(256), 0, stream, xb, Wt, Qb, Kb, Vt);
  hipLaunchKernelGGL(k_colsum, dim3(64, 16),  dim3(256), 0, stream, Qb, Kb, Linv);
  hipLaunchKernelGGL(k_vscale, dim3(4096),    dim3(256), 0, stream, Vt, Linv);
  hipLaunchKernelGGL(k_attn,   dim3(64, 16),  dim3(256), 0, stream, Qb, Kb, Vt, Att);
  hipLaunchKernelGGL(k_oproj,  dim3(64, 8),   dim3(256), 0, stream, Att, Wot, bo, out);
}

// Round 7
// 207.965 us; speedup vs baseline: 1.5085x; 1.0053x over previous
//
#include <hip/hip_runtime.h>
#include <stdint.h>

// Problem constants
#define Bn 4
#define Tn 2048
#define En 1024
#define Hn 16
#define HSn 64
#define BHn (Bn*Hn)   // 64
#define NRn (Bn*Tn)   // 8192

// exp(x/32) = exp2(x * 0.03125 * log2(e))
#define CEXP 0.0450840831f

typedef __attribute__((ext_vector_type(8))) short short8;
typedef __attribute__((ext_vector_type(4))) float f32x4;
typedef __attribute__((ext_vector_type(16))) float f32x16;
typedef __attribute__((ext_vector_type(4))) unsigned int uint4w;

__device__ __forceinline__ unsigned short f2b(float f){
  union { float f; unsigned int u; } c; c.f = f;
  unsigned int u = c.u + 0x7FFFu + ((c.u >> 16) & 1u);
  return (unsigned short)(u >> 16);
}
__device__ __forceinline__ float b2f(unsigned short s){
  union { unsigned int u; float f; } c; c.u = ((unsigned int)s) << 16;
  return c.f;
}
__device__ __forceinline__ unsigned int cvtpk(float lo, float hi){
  unsigned int r;
  asm("v_cvt_pk_bf16_f32 %0, %1, %2" : "=v"(r) : "v"(lo), "v"(hi));
  return r;
}
__device__ __forceinline__ f32x4 mfma16(short8 a, short8 b, f32x4 c){
  return __builtin_amdgcn_mfma_f32_16x16x32_bf16(a, b, c, 0, 0, 0);
}
__device__ __forceinline__ f32x16 mfma32(short8 a, short8 b, f32x16 c){
  return __builtin_amdgcn_mfma_f32_32x32x16_bf16(a, b, c, 0, 0, 0);
}
__device__ __forceinline__ void gl16(const void* g, void* s){
  __builtin_amdgcn_global_load_lds((const __attribute__((address_space(1))) unsigned int*)g,
                                   (__attribute__((address_space(3))) unsigned int*)s, 16, 0, 0);
}
#define FENCE()    asm volatile("" ::: "memory")
#define WAITV(N)   asm volatile("s_waitcnt vmcnt(" #N ")" ::: "memory")
#define SBAR()     __builtin_amdgcn_s_barrier()

// ---------------- kernel 0: x fp32 -> bf16 ----------------
__global__ void k_cvt_x(const float* __restrict__ x, unsigned short* __restrict__ xb){
  int i = (blockIdx.x * blockDim.x + threadIdx.x) * 8;
  float4 a = *(const float4*)(x + i);
  float4 b = *(const float4*)(x + i + 4);
  alignas(16) unsigned short o[8] = {f2b(a.x),f2b(a.y),f2b(a.z),f2b(a.w),
                                     f2b(b.x),f2b(b.y),f2b(b.z),f2b(b.w)};
  *(uint4w*)(xb + i) = *(const uint4w*)o;
}

// ---------------- kernel 0b: weight convert+transpose ----------------
__global__ void k_wT(const float* __restrict__ Wq, const float* __restrict__ Wk,
                     const float* __restrict__ Wv, const float* __restrict__ Wo,
                     unsigned short* __restrict__ Wt, unsigned short* __restrict__ Wot)
{
  __shared__ unsigned short Ls[64*80];
  const int tid = threadIdx.x;
  const int ey = blockIdx.x, jt = blockIdx.y;
  const int e0 = ey*64;
  const float* src; int R, c0; unsigned short* outp;
  if (jt < 48){
    int sel = jt >> 4, h = jt & 15;
    const float* W = (sel==0)?Wq:((sel==1)?Wk:Wv);
    src = W + h*(En*HSn); R = HSn; c0 = 0;
    outp = Wt + jt*64*En;
  } else {
    src = Wo; R = En; c0 = (jt-48)*64;
    outp = Wot + (jt-48)*64*En;
  }
  {
    const int e = tid >> 2, cq = (tid & 3)*16;
    const float* p = src + (e0 + e)*R + c0 + cq;
    float vv[16];
    *(float4*)&vv[0]  = *(const float4*)(p);
    *(float4*)&vv[4]  = *(const float4*)(p+4);
    *(float4*)&vv[8]  = *(const float4*)(p+8);
    *(float4*)&vv[12] = *(const float4*)(p+12);
#pragma unroll
    for (int i = 0; i < 16; i++) Ls[(cq+i)*80 + e] = f2b(vv[i]);
  }
  __syncthreads();
  {
    const int c8 = tid & 7, r = tid >> 3;
#pragma unroll
    for (int rr0 = 0; rr0 < 2; rr0++){
      int rr = r + rr0*32;
      *(uint4w*)(outp + rr*En + e0 + c8*8) = *(const uint4w*)&Ls[rr*80 + c8*8];
    }
  }
}

// ---------------- kernel 1: QKV projection GEMM (depth-2 counted-vmcnt) ------
__global__ void __launch_bounds__(256, 2)
k_qkv(const unsigned short* __restrict__ xb,
      const unsigned short* __restrict__ Wt,
      unsigned short* __restrict__ Qb, unsigned short* __restrict__ Kb,
      unsigned short* __restrict__ Vt)
{
  __shared__ unsigned short As[2][128*64];
  __shared__ unsigned short Bs[2][128*64];
  const int tid = threadIdx.x, lane = tid & 63, w = tid >> 6;
  const int wr = w >> 1, wc = w & 1;
  const int mb = blockIdx.x, nb = blockIdx.y;
  const int n0 = nb*128;
  const int sel = n0 >> 10;
  const int nj0 = n0 & 1023;
  const int l15 = lane & 15, kc = lane >> 4;
  const int r8 = lane >> 3, c7 = lane & 7;

  const unsigned short* xbase = xb + (mb*128)*En;
  const unsigned short* wbase = Wt + n0*En;

  f32x4 acc[4][4];
#pragma unroll
  for (int i = 0; i < 4; i++)
#pragma unroll
    for (int j = 0; j < 4; j++) acc[i][j] = (f32x4){0.f,0.f,0.f,0.f};

  auto stage = [&](int buf, int k0){
#pragma unroll
    for (int i = 0; i < 4; i++){
      const int rb = w*32 + i*8;
      const int r = rb + r8;
      const int g = (c7 ^ r8) * 8;
      gl16(xbase + r*En + k0 + g, &As[buf][rb*64]);
      gl16(wbase + r*En + k0 + g, &Bs[buf][rb*64]);
    }
  };
  auto compute = [&](int cur){
    const unsigned short* Ac = &As[cur][0];
    const unsigned short* Bc = &Bs[cur][0];
#pragma unroll
    for (int ks = 0; ks < 2; ks++){
      short8 af[4], bf[4];
#pragma unroll
      for (int mf = 0; mf < 4; mf++){
        int ar = wr*64 + mf*16 + l15;
        af[mf] = *(const short8*)&Ac[ar*64 + (((ks*4 + kc) ^ (ar & 7))*8)];
      }
#pragma unroll
      for (int nf = 0; nf < 4; nf++){
        int br = wc*64 + nf*16 + l15;
        bf[nf] = *(const short8*)&Bc[br*64 + (((ks*4 + kc) ^ (br & 7))*8)];
      }
      __builtin_amdgcn_s_setprio(1);
#pragma unroll
      for (int mf = 0; mf < 4; mf++)
#pragma unroll
        for (int nf = 0; nf < 4; nf++)
          acc[mf][nf] = mfma16(af[mf], bf[nf], acc[mf][nf]);
      __builtin_amdgcn_s_setprio(0);
    }
  };

  stage(0, 0);
  stage(1, 64);
  WAITV(8); SBAR();

  for (int kt = 0; kt < 16; kt++){
    const int cur = kt & 1;
    compute(cur);
    FENCE(); SBAR();
    if (kt < 14){
      stage(cur, (kt + 2)*64);
      WAITV(8); SBAR();
    } else if (kt == 14){
      WAITV(0); SBAR();
    }
  }
  __syncthreads();

  const int q4 = (lane >> 4)*4;
  const int bb = mb >> 4;
  const int tt0 = (mb*128) & 2047;

  if (sel == 2){
    unsigned short* tb = ((w < 2) ? &As[0][0] : &Bs[0][0]) + (w & 1)*8192;
#pragma unroll
    for (int nf = 0; nf < 4; nf++)
#pragma unroll
      for (int mf = 0; mf < 4; mf++){
        uint2 u;
        u.x = cvtpk(acc[mf][nf][0], acc[mf][nf][1]);
        u.y = cvtpk(acc[mf][nf][2], acc[mf][nf][3]);
        *(uint2*)&tb[(nf*16 + l15)*72 + mf*16 + q4] = u;
      }
    const int hh = (nj0 >> 6) + wc;
    unsigned short* vb = Vt + ((bb*Hn + hh)*HSn)*Tn + tt0 + wr*64;
#pragma unroll
    for (int i = 0; i < 8; i++){
      int rr = i*8 + r8;
      *(uint4w*)(vb + rr*Tn + c7*8) = *(const uint4w*)&tb[rr*72 + c7*8];
    }
  } else {
    unsigned short* Out = (sel == 1) ? Kb : Qb;
#pragma unroll
    for (int nf = 0; nf < 4; nf++){
      int jj = nj0 + wc*64 + nf*16 + l15;
      int hh = jj >> 6, dd = jj & 63;
#pragma unroll
      for (int mf = 0; mf < 4; mf++){
#pragma unroll
        for (int q = 0; q < 4; q++){
          int tt = tt0 + wr*64 + mf*16 + q4 + q;
          Out[((bb*Hn + hh)*Tn + tt)*HSn + dd] = f2b(acc[mf][nf][q]);
        }
      }
    }
  }
}

// ---------------- kernel 2: column exp-sums + fused V-scale -------------------
// 3-buffer, 1 barrier/iter, counted vmcnt. After Lred final, scales Vt columns.
__global__ void __launch_bounds__(256, 3)
k_colsum(const unsigned short* __restrict__ Qb,
         const unsigned short* __restrict__ Kb,
         unsigned short* __restrict__ Vt,
         float* __restrict__ Linv)
{
  __shared__ unsigned short Qs[3][128*64];   // 48KB
  __shared__ float Lred[64];
  const int bh = blockIdx.x, ipair = blockIdx.y;
  const int tid = threadIdx.x, lane = tid & 63, w = tid >> 6;
  const int l5 = lane >> 5, l31 = lane & 31;
  const int r8 = lane >> 3, c7 = lane & 7;

  for (int ph = 0; ph < 2; ph++){
    const int sb = ph ? (31 - ipair) : ipair;
    const int s0 = sb * 64;

    short8 kf[2][4];
#pragma unroll
    for (int sf = 0; sf < 2; sf++){
      const unsigned short* kr = Kb + (bh*Tn + s0 + sf*32 + l31)*HSn + 8*l5;
#pragma unroll
      for (int ks = 0; ks < 4; ks++) kf[sf][ks] = *(const short8*)(kr + 16*ks);
    }

    float ls[2][16];
#pragma unroll
    for (int sf = 0; sf < 2; sf++)
#pragma unroll
      for (int r = 0; r < 16; r++) ls[sf][r] = 0.f;

    if (tid < 64) Lred[tid] = 0.f;

    const int t0s = (s0 >> 7) << 7;
    const int ntl = (Tn - t0s) >> 7;

    auto stageQ = [&](int buf, int tg0){
#pragma unroll
      for (int i = 0; i < 4; i++){
        int row = (w*4 + i)*8 + r8;
        gl16(Qb + (bh*Tn + tg0 + row)*HSn + ((c7 ^ (row & 7))*8), &Qs[buf][(w*4 + i)*512]);
      }
    };

    stageQ(0, t0s);
    if (ntl > 1) stageQ(1, t0s + 128);

    for (int it = 0; it < ntl; it++){
      if (it + 1 < ntl){ WAITV(4); } else { WAITV(0); }
      FENCE(); SBAR(); FENCE();
      if (it + 2 < ntl) stageQ((it + 2) % 3, t0s + (it + 2)*128);

      const int cur = it % 3;
      const int t0 = t0s + it*128;
      const int tw = t0 + 32*w;
      if (tw + 31 >= s0){
        f32x16 st[2];
#pragma unroll
        for (int sf = 0; sf < 2; sf++)
#pragma unroll
          for (int r = 0; r < 16; r++) st[sf][r] = 0.f;
        const int qrow = w*32 + l31;
        const unsigned short* Qc = &Qs[cur][qrow*64];
        const int sw = qrow & 7;
        __builtin_amdgcn_s_setprio(1);
#pragma unroll
        for (int ks = 0; ks < 4; ks++){
          short8 qb = *(const short8*)&Qc[((l5 + 2*ks) ^ sw)*8];
          st[0] = mfma32(kf[0][ks], qb, st[0]);
          st[1] = mfma32(kf[1][ks], qb, st[1]);
        }
        __builtin_amdgcn_s_setprio(0);
        const int tg = tw + l31;
        if (s0 + 63 <= tw){
#pragma unroll
          for (int sf = 0; sf < 2; sf++)
#pragma unroll
            for (int r = 0; r < 16; r++)
              ls[sf][r] += __builtin_amdgcn_exp2f(st[sf][r] * CEXP);
        } else {
#pragma unroll
          for (int sf = 0; sf < 2; sf++)
#pragma unroll
            for (int r = 0; r < 16; r++){
              int sg = s0 + 32*sf + (r & 3) + 8*(r >> 2) + 4*l5;
              float e = __builtin_amdgcn_exp2f(st[sf][r] * CEXP);
              ls[sf][r] += (tg >= sg) ? e : 0.f;
            }
        }
      }
    }

#pragma unroll
    for (int sf = 0; sf < 2; sf++)
#pragma unroll
      for (int r = 0; r < 16; r++){
        float v = ls[sf][r];
        v += __shfl_xor(v, 1);  v += __shfl_xor(v, 2);
        v += __shfl_xor(v, 4);  v += __shfl_xor(v, 8);
        v += __shfl_xor(v, 16);
        ls[sf][r] = v;
      }
    if (l31 == 0){
#pragma unroll
      for (int sf = 0; sf < 2; sf++)
#pragma unroll
        for (int r = 0; r < 16; r++){
          int sl = 32*sf + (r & 3) + 8*(r >> 2) + 4*l5;
          atomicAdd(&Lred[sl], ls[sf][r]);
        }
    }
    __syncthreads();
    if (tid < 64) Linv[bh*Tn + s0 + tid] = 1.0f / Lred[tid];

    // fused V-scale: this block owns columns [s0, s0+64) of Vt for this bh
    {
      const int d = tid >> 2, cq = (tid & 3)*16;
      unsigned short* vp = Vt + ((size_t)(bh*HSn + d))*Tn + s0 + cq;
      short8 v0 = *(const short8*)vp;
      short8 v1 = *(const short8*)(vp + 8);
      float inv[16];
#pragma unroll
      for (int j = 0; j < 16; j++) inv[j] = 1.0f / Lred[cq + j];
      uint4w o0, o1;
      o0[0] = cvtpk(b2f((unsigned short)v0[0])*inv[0],  b2f((unsigned short)v0[1])*inv[1]);
      o0[1] = cvtpk(b2f((unsigned short)v0[2])*inv[2],  b2f((unsigned short)v0[3])*inv[3]);
      o0[2] = cvtpk(b2f((unsigned short)v0[4])*inv[4],  b2f((unsigned short)v0[5])*inv[5]);
      o0[3] = cvtpk(b2f((unsigned short)v0[6])*inv[6],  b2f((unsigned short)v0[7])*inv[7]);
      o1[0] = cvtpk(b2f((unsigned short)v1[0])*inv[8],  b2f((unsigned short)v1[1])*inv[9]);
      o1[1] = cvtpk(b2f((unsigned short)v1[2])*inv[10], b2f((unsigned short)v1[3])*inv[11]);
      o1[2] = cvtpk(b2f((unsigned short)v1[4])*inv[12], b2f((unsigned short)v1[5])*inv[13]);
      o1[3] = cvtpk(b2f((unsigned short)v1[6])*inv[14], b2f((unsigned short)v1[7])*inv[15]);
      *(uint4w*)vp       = o0;
      *(uint4w*)(vp + 8) = o1;
    }
    if (ph == 0) __syncthreads();
  }
}

// ---------------- kernel 3: attention output (3-buffer, 1 barrier/iter) ------
__global__ void __launch_bounds__(256, 3)
k_attn(const unsigned short* __restrict__ Qb,
       const unsigned short* __restrict__ Kb,
       const unsigned short* __restrict__ Vlt,
       unsigned short* __restrict__ Att)
{
  __shared__ unsigned short Ks[3][64*64];   // 24KB
  __shared__ unsigned short Vs[3][64*64];   // 24KB
  const int bh = blockIdx.x;
  const int tb = 15 - blockIdx.y;          // heavy blocks dispatch first
  const int t0 = tb * 128;
  const int tid = threadIdx.x, lane = tid & 63, w = tid >> 6;
  const int l5 = lane >> 5, l31 = lane & 31;
  const int c7 = lane & 7, r8 = lane >> 3;
  const int tbase = t0 + w*32;
  const int nt = 2*tb + 2;

  short8 qf[4];
  {
    const unsigned short* qr = Qb + (bh*Tn + tbase + l31)*HSn + 8*l5;
#pragma unroll
    for (int ks = 0; ks < 4; ks++) qf[ks] = *(const short8*)(qr + 16*ks);
  }

  f32x16 oacc[2];
#pragma unroll
  for (int df = 0; df < 2; df++)
#pragma unroll
    for (int r = 0; r < 16; r++) oacc[df][r] = 0.f;

  auto stageKV = [&](int buf, int sn){
#pragma unroll
    for (int i = 0; i < 2; i++){
      int row = (w*2 + i)*8 + r8;
      gl16(Kb  + (bh*Tn + sn + row)*HSn + ((c7 ^ (row & 7))*8), &Ks[buf][(w*2 + i)*512]);
      gl16(Vlt + (bh*HSn + row)*Tn + sn + ((c7 ^ (row & 7))*8), &Vs[buf][(w*2 + i)*512]);
    }
  };

  stageKV(0, 0);
  if (nt > 1) stageKV(1, 64);

  for (int it = 0; it < nt; it++){
    if (it + 1 < nt){ WAITV(4); } else { WAITV(0); }
    FENCE(); SBAR(); FENCE();
    if (it + 2 < nt) stageKV((it + 2) % 3, (it + 2)*64);

    const int cur = it % 3;
    const int s0 = it * 64;
    if (s0 <= tbase + 31){
      const unsigned short* Kc = &Ks[cur][0];
      f32x16 st[2];
#pragma unroll
      for (int sf = 0; sf < 2; sf++)
#pragma unroll
        for (int r = 0; r < 16; r++) st[sf][r] = 0.f;
      __builtin_amdgcn_s_setprio(1);
#pragma unroll
      for (int ks = 0; ks < 4; ks++){
#pragma unroll
        for (int sf = 0; sf < 2; sf++){
          int row = sf*32 + l31;
          short8 ka = *(const short8*)&Kc[row*64 + (((l5 + 2*ks) ^ (row & 7))*8)];
          st[sf] = mfma32(ka, qf[ks], st[sf]);
        }
      }
      __builtin_amdgcn_s_setprio(0);

      const int tg = tbase + l31;
      const bool interior = (s0 + 63 <= tbase);
#pragma unroll
      for (int sf = 0; sf < 2; sf++){
#pragma unroll
        for (int r = 0; r < 16; r++){
          float e = __builtin_amdgcn_exp2f(st[sf][r] * CEXP);
          if (!interior){
            int sg = s0 + 32*sf + (r & 3) + 8*(r >> 2) + 4*l5;
            e = (tg >= sg) ? e : 0.f;
          }
          st[sf][r] = e;
        }
      }

      short8 pb[4];
#pragma unroll
      for (int sf = 0; sf < 2; sf++){
#pragma unroll
        for (int q = 0; q < 2; q++){
          unsigned int ax = cvtpk(st[sf][8*q+0], st[sf][8*q+1]);
          unsigned int ay = cvtpk(st[sf][8*q+2], st[sf][8*q+3]);
          unsigned int bx = cvtpk(st[sf][8*q+4], st[sf][8*q+5]);
          unsigned int by = cvtpk(st[sf][8*q+6], st[sf][8*q+7]);
          asm("v_permlane32_swap_b32 %0, %1" : "+v"(ax), "+v"(bx));
          asm("v_permlane32_swap_b32 %0, %1" : "+v"(ay), "+v"(by));
          union { unsigned int u[4]; short8 s; } pk;
          pk.u[0] = ax; pk.u[1] = ay; pk.u[2] = bx; pk.u[3] = by;
          pb[sf*2 + q] = pk.s;
        }
      }

      const unsigned short* Vc = &Vs[cur][0];
      __builtin_amdgcn_s_setprio(1);
#pragma unroll
      for (int ks = 0; ks < 4; ks++){
#pragma unroll
        for (int df = 0; df < 2; df++){
          int row = df*32 + l31;
          short8 va = *(const short8*)&Vc[row*64 + (((l5 + 2*ks) ^ (row & 7))*8)];
          oacc[df] = mfma32(va, pb[ks], oacc[df]);
        }
      }
      __builtin_amdgcn_s_setprio(0);
    }
  }

  {
    const int tg = tbase + l31;
    unsigned short* ob = Att + (bh*Tn + tg)*HSn;
#pragma unroll
    for (int df = 0; df < 2; df++)
#pragma unroll
      for (int r2 = 0; r2 < 4; r2++){
        uint2 u;
        u.x = cvtpk(oacc[df][r2*4+0], oacc[df][r2*4+1]);
        u.y = cvtpk(oacc[df][r2*4+2], oacc[df][r2*4+3]);
        *(uint2*)&ob[32*df + 8*r2 + 4*l5] = u;
      }
  }
}

// ---------------- kernel 4: output projection (depth-2 counted-vmcnt) --------
__global__ void __launch_bounds__(256, 2)
k_oproj(const unsigned short* __restrict__ Att,
        const unsigned short* __restrict__ Wot,
        const float* __restrict__ bo, float* __restrict__ out)
{
  __shared__ unsigned short As[2][128*64];
  __shared__ unsigned short Bs[2][128*64];
  const int tid = threadIdx.x, lane = tid & 63, w = tid >> 6;
  const int wr = w >> 1, wc = w & 1;
  const int mb = blockIdx.x, nb = blockIdx.y;
  const int n0 = nb*128;
  const int l15 = lane & 15, kc = lane >> 4;
  const int r8 = lane >> 3, c7 = lane & 7;
  const int bb = mb >> 4;
  const int t0 = (mb*128) & 2047;

  f32x4 acc[4][4];
#pragma unroll
  for (int i = 0; i < 4; i++)
#pragma unroll
    for (int j = 0; j < 4; j++) acc[i][j] = (f32x4){0.f,0.f,0.f,0.f};

  const unsigned short* wbase = Wot + n0*En;

  auto stage = [&](int buf, int k0){
    const int hh = k0 >> 6;
    const unsigned short* abase = Att + ((bb*Hn + hh)*Tn + t0)*HSn;
#pragma unroll
    for (int i = 0; i < 4; i++){
      const int rb = w*32 + i*8;
      const int r = rb + r8;
      const int g = (c7 ^ r8) * 8;
      gl16(abase + r*HSn + g, &As[buf][rb*64]);
      gl16(wbase + r*En + k0 + g, &Bs[buf][rb*64]);
    }
  };
  auto compute = [&](int cur){
    const unsigned short* Ac = &As[cur][0];
    const unsigned short* Bc = &Bs[cur][0];
#pragma unroll
    for (int ks = 0; ks < 2; ks++){
      short8 af[4], bf[4];
#pragma unroll
      for (int mf = 0; mf < 4; mf++){
        int ar = wr*64 + mf*16 + l15;
        af[mf] = *(const short8*)&Ac[ar*64 + (((ks*4 + kc) ^ (ar & 7))*8)];
      }
#pragma unroll
      for (int nf = 0; nf < 4; nf++){
        int br = wc*64 + nf*16 + l15;
        bf[nf] = *(const short8*)&Bc[br*64 + (((ks*4 + kc) ^ (br & 7))*8)];
      }
      __builtin_amdgcn_s_setprio(1);
#pragma unroll
      for (int mf = 0; mf < 4; mf++)
#pragma unroll
        for (int nf = 0; nf < 4; nf++)
          acc[mf][nf] = mfma16(af[mf], bf[nf], acc[mf][nf]);
      __builtin_amdgcn_s_setprio(0);
    }
  };

  stage(0, 0);
  stage(1, 64);
  WAITV(8); SBAR();

  for (int kt = 0; kt < 16; kt++){
    const int cur = kt & 1;
    compute(cur);
    FENCE(); SBAR();
    if (kt < 14){
      stage(cur, (kt + 2)*64);
      WAITV(8); SBAR();
    } else if (kt == 14){
      WAITV(0); SBAR();
    }
  }

  const int q4 = (lane >> 4)*4;
#pragma unroll
  for (int nf = 0; nf < 4; nf++){
    int j = n0 + wc*64 + nf*16 + l15;
    float bias = bo[j];
#pragma unroll
    for (int mf = 0; mf < 4; mf++){
#pragma unroll
      for (int q = 0; q < 4; q++){
        int rr = mb*128 + wr*64 + mf*16 + q4 + q;
        out[rr*En + j] = acc[mf][nf][q] + bias;
      }
    }
  }
}

extern "C" void kernel_launch(void* const* d_in, const int* in_sizes, int n_in,
                              void* d_out, int out_size, void* d_ws, size_t ws_size,
                              hipStream_t stream)
{
  (void)in_sizes; (void)n_in; (void)out_size; (void)ws_size;
  const float* x  = (const float*)d_in[0];
  const float* Wq = (const float*)d_in[1];
  const float* Wk = (const float*)d_in[2];
  const float* Wv = (const float*)d_in[3];
  const float* Wo = (const float*)d_in[4];
  const float* bo = (const float*)d_in[5];
  float* out = (float*)d_out;

  // ws layout (MB): Qb[0,16) Kb[16,32) Vt[32,48) xb/Att[48,64) Wt[64,70) Wot[70,72) Linv[72,72.5)
  uint8_t* w = (uint8_t*)d_ws;
  unsigned short* Qb  = (unsigned short*)(w);
  unsigned short* Kb  = (unsigned short*)(w + (16u << 20));
  unsigned short* Vt  = (unsigned short*)(w + (32u << 20));
  unsigned short* xb  = (unsigned short*)(w + (48u << 20));
  unsigned short* Att = (unsigned short*)(w + (48u << 20));
  unsigned short* Wt  = (unsigned short*)(w + (64u << 20));
  unsigned short* Wot = (unsigned short*)(w + (70u << 20));
  float* Linv         = (float*)(w + (72u << 20));

  hipLaunchKernelGGL(k_cvt_x,  dim3(4096),    dim3(256), 0, stream, x, xb);
  hipLaunchKernelGGL(k_wT,     dim3(16, 64),  dim3(256), 0, stream, Wq, Wk, Wv, Wo, Wt, Wot);
  hipLaunchKernelGGL(k_qkv,    dim3(64, 24),  dim3(256), 0, stream, xb, Wt, Qb, Kb, Vt);
  hipLaunchKernelGGL(k_colsum, dim3(64, 16),  dim3(256), 0, stream, Qb, Kb, Vt, Linv);
  hipLaunchKernelGGL(k_attn,   dim3(64, 16),  dim3(256), 0, stream, Qb, Kb, Vt, Att);
  hipLaunchKernelGGL(k_oproj,  dim3(64, 8),   dim3(256), 0, stream, Att, Wot, bo, out);
}

// Round 8
// 199.231 us; speedup vs baseline: 1.5746x; 1.0438x over previous
//
#include <hip/hip_runtime.h>
#include <stdint.h>

// Problem constants
#define Bn 4
#define Tn 2048
#define En 1024
#define Hn 16
#define HSn 64
#define BHn (Bn*Hn)   // 64
#define NRn (Bn*Tn)   // 8192

// exp(x/32) = exp2(x * 0.03125 * log2(e)); folded into Wq at k_wT time.
#define CEXP 0.0450840831f

typedef __attribute__((ext_vector_type(8))) short short8;
typedef __attribute__((ext_vector_type(4))) float f32x4;
typedef __attribute__((ext_vector_type(16))) float f32x16;
typedef __attribute__((ext_vector_type(4))) unsigned int uint4w;

__device__ __forceinline__ unsigned short f2b(float f){
  union { float f; unsigned int u; } c; c.f = f;
  unsigned int u = c.u + 0x7FFFu + ((c.u >> 16) & 1u);
  return (unsigned short)(u >> 16);
}
__device__ __forceinline__ float b2f(unsigned short s){
  union { unsigned int u; float f; } c; c.u = ((unsigned int)s) << 16;
  return c.f;
}
__device__ __forceinline__ unsigned int cvtpk(float lo, float hi){
  unsigned int r;
  asm("v_cvt_pk_bf16_f32 %0, %1, %2" : "=v"(r) : "v"(lo), "v"(hi));
  return r;
}
__device__ __forceinline__ f32x4 mfma16(short8 a, short8 b, f32x4 c){
  return __builtin_amdgcn_mfma_f32_16x16x32_bf16(a, b, c, 0, 0, 0);
}
__device__ __forceinline__ f32x16 mfma32(short8 a, short8 b, f32x16 c){
  return __builtin_amdgcn_mfma_f32_32x32x16_bf16(a, b, c, 0, 0, 0);
}
__device__ __forceinline__ void gl16(const void* g, void* s){
  __builtin_amdgcn_global_load_lds((const __attribute__((address_space(1))) unsigned int*)g,
                                   (__attribute__((address_space(3))) unsigned int*)s, 16, 0, 0);
}
#define FENCE()    asm volatile("" ::: "memory")
#define WAITV(N)   asm volatile("s_waitcnt vmcnt(" #N ")" ::: "memory")
#define SBAR()     __builtin_amdgcn_s_barrier()

// ---------------- kernel 0: x fp32 -> bf16 ----------------
__global__ void k_cvt_x(const float* __restrict__ x, unsigned short* __restrict__ xb){
  int i = (blockIdx.x * blockDim.x + threadIdx.x) * 8;
  float4 a = *(const float4*)(x + i);
  float4 b = *(const float4*)(x + i + 4);
  alignas(16) unsigned short o[8] = {f2b(a.x),f2b(a.y),f2b(a.z),f2b(a.w),
                                     f2b(b.x),f2b(b.y),f2b(b.z),f2b(b.w)};
  *(uint4w*)(xb + i) = *(const uint4w*)o;
}

// ---------------- kernel 0b: weight convert+transpose (Wq pre-scaled) --------
__global__ void k_wT(const float* __restrict__ Wq, const float* __restrict__ Wk,
                     const float* __restrict__ Wv, const float* __restrict__ Wo,
                     unsigned short* __restrict__ Wt, unsigned short* __restrict__ Wot)
{
  __shared__ unsigned short Ls[64*80];
  const int tid = threadIdx.x;
  const int ey = blockIdx.x, jt = blockIdx.y;
  const int e0 = ey*64;
  const float* src; int R, c0; unsigned short* outp; float sc = 1.0f;
  if (jt < 48){
    int sel = jt >> 4, h = jt & 15;
    const float* W = (sel==0)?Wq:((sel==1)?Wk:Wv);
    if (sel == 0) sc = CEXP;          // fold exp2 conversion+1/32 into Q
    src = W + h*(En*HSn); R = HSn; c0 = 0;
    outp = Wt + jt*64*En;
  } else {
    src = Wo; R = En; c0 = (jt-48)*64;
    outp = Wot + (jt-48)*64*En;
  }
  {
    const int e = tid >> 2, cq = (tid & 3)*16;
    const float* p = src + (e0 + e)*R + c0 + cq;
    float vv[16];
    *(float4*)&vv[0]  = *(const float4*)(p);
    *(float4*)&vv[4]  = *(const float4*)(p+4);
    *(float4*)&vv[8]  = *(const float4*)(p+8);
    *(float4*)&vv[12] = *(const float4*)(p+12);
#pragma unroll
    for (int i = 0; i < 16; i++) Ls[(cq+i)*80 + e] = f2b(vv[i]*sc);
  }
  __syncthreads();
  {
    const int c8 = tid & 7, r = tid >> 3;
#pragma unroll
    for (int rr0 = 0; rr0 < 2; rr0++){
      int rr = r + rr0*32;
      *(uint4w*)(outp + rr*En + e0 + c8*8) = *(const uint4w*)&Ls[rr*80 + c8*8];
    }
  }
}

// ---------------- kernel 1: QKV projection GEMM (depth-2 counted-vmcnt) ------
__global__ void __launch_bounds__(256, 2)
k_qkv(const unsigned short* __restrict__ xb,
      const unsigned short* __restrict__ Wt,
      unsigned short* __restrict__ Qb, unsigned short* __restrict__ Kb,
      unsigned short* __restrict__ Vt)
{
  __shared__ unsigned short As[2][128*64];
  __shared__ unsigned short Bs[2][128*64];
  const int tid = threadIdx.x, lane = tid & 63, w = tid >> 6;
  const int wr = w >> 1, wc = w & 1;
  const int mb = blockIdx.x, nb = blockIdx.y;
  const int n0 = nb*128;
  const int sel = n0 >> 10;
  const int nj0 = n0 & 1023;
  const int l15 = lane & 15, kc = lane >> 4;
  const int r8 = lane >> 3, c7 = lane & 7;

  const unsigned short* xbase = xb + (mb*128)*En;
  const unsigned short* wbase = Wt + n0*En;

  f32x4 acc[4][4];
#pragma unroll
  for (int i = 0; i < 4; i++)
#pragma unroll
    for (int j = 0; j < 4; j++) acc[i][j] = (f32x4){0.f,0.f,0.f,0.f};

  auto stage = [&](int buf, int k0){
#pragma unroll
    for (int i = 0; i < 4; i++){
      const int rb = w*32 + i*8;
      const int r = rb + r8;
      const int g = (c7 ^ r8) * 8;
      gl16(xbase + r*En + k0 + g, &As[buf][rb*64]);
      gl16(wbase + r*En + k0 + g, &Bs[buf][rb*64]);
    }
  };
  auto compute = [&](int cur){
    const unsigned short* Ac = &As[cur][0];
    const unsigned short* Bc = &Bs[cur][0];
#pragma unroll
    for (int ks = 0; ks < 2; ks++){
      short8 af[4], bf[4];
#pragma unroll
      for (int mf = 0; mf < 4; mf++){
        int ar = wr*64 + mf*16 + l15;
        af[mf] = *(const short8*)&Ac[ar*64 + (((ks*4 + kc) ^ (ar & 7))*8)];
      }
#pragma unroll
      for (int nf = 0; nf < 4; nf++){
        int br = wc*64 + nf*16 + l15;
        bf[nf] = *(const short8*)&Bc[br*64 + (((ks*4 + kc) ^ (br & 7))*8)];
      }
      __builtin_amdgcn_s_setprio(1);
#pragma unroll
      for (int mf = 0; mf < 4; mf++)
#pragma unroll
        for (int nf = 0; nf < 4; nf++)
          acc[mf][nf] = mfma16(af[mf], bf[nf], acc[mf][nf]);
      __builtin_amdgcn_s_setprio(0);
    }
  };

  stage(0, 0);
  stage(1, 64);
  WAITV(8); SBAR();

  for (int kt = 0; kt < 16; kt++){
    const int cur = kt & 1;
    compute(cur);
    FENCE(); SBAR();
    if (kt < 14){
      stage(cur, (kt + 2)*64);
      WAITV(8); SBAR();
    } else if (kt == 14){
      WAITV(0); SBAR();
    }
  }
  __syncthreads();

  const int q4 = (lane >> 4)*4;
  const int bb = mb >> 4;
  const int tt0 = (mb*128) & 2047;

  if (sel == 2){
    unsigned short* tb = ((w < 2) ? &As[0][0] : &Bs[0][0]) + (w & 1)*8192;
#pragma unroll
    for (int nf = 0; nf < 4; nf++)
#pragma unroll
      for (int mf = 0; mf < 4; mf++){
        uint2 u;
        u.x = cvtpk(acc[mf][nf][0], acc[mf][nf][1]);
        u.y = cvtpk(acc[mf][nf][2], acc[mf][nf][3]);
        *(uint2*)&tb[(nf*16 + l15)*72 + mf*16 + q4] = u;
      }
    const int hh = (nj0 >> 6) + wc;
    unsigned short* vb = Vt + ((bb*Hn + hh)*HSn)*Tn + tt0 + wr*64;
#pragma unroll
    for (int i = 0; i < 8; i++){
      int rr = i*8 + r8;
      *(uint4w*)(vb + rr*Tn + c7*8) = *(const uint4w*)&tb[rr*72 + c7*8];
    }
  } else {
    unsigned short* Out = (sel == 1) ? Kb : Qb;
#pragma unroll
    for (int nf = 0; nf < 4; nf++){
      int jj = nj0 + wc*64 + nf*16 + l15;
      int hh = jj >> 6, dd = jj & 63;
#pragma unroll
      for (int mf = 0; mf < 4; mf++){
#pragma unroll
        for (int q = 0; q < 4; q++){
          int tt = tt0 + wr*64 + mf*16 + q4 + q;
          Out[((bb*Hn + hh)*Tn + tt)*HSn + dd] = f2b(acc[mf][nf][q]);
        }
      }
    }
  }
}

// ---------------- kernel 2: column exp-sums + fused V-scale -------------------
// XCD-grouped: grid (8, 256); bh = x*8 + (y&7) pins all of a bh to one XCD.
// Streams t-tiles in REVERSE so all blocks of a bh read the same tiles together
// (suffix-aligned) -> Q served from L2 (per-XCD set = 8 bh x 256KB = 2MB).
__global__ void __launch_bounds__(256, 3)
k_colsum(const unsigned short* __restrict__ Qb,
         const unsigned short* __restrict__ Kb,
         unsigned short* __restrict__ Vt,
         float* __restrict__ Linv)
{
  __shared__ unsigned short Qs[3][128*64];   // 48KB
  __shared__ float Lred[64];
  const int bh = blockIdx.x*8 + (blockIdx.y & 7);
  const int sb = blockIdx.y >> 3;            // heavy (low sb) dispatched first
  const int s0 = sb * 64;
  const int tid = threadIdx.x, lane = tid & 63, w = tid >> 6;
  const int l5 = lane >> 5, l31 = lane & 31;
  const int r8 = lane >> 3, c7 = lane & 7;

  short8 kf[2][4];
#pragma unroll
  for (int sf = 0; sf < 2; sf++){
    const unsigned short* kr = Kb + (bh*Tn + s0 + sf*32 + l31)*HSn + 8*l5;
#pragma unroll
    for (int ks = 0; ks < 4; ks++) kf[sf][ks] = *(const short8*)(kr + 16*ks);
  }

  float ls[2][16];
#pragma unroll
  for (int sf = 0; sf < 2; sf++)
#pragma unroll
    for (int r = 0; r < 16; r++) ls[sf][r] = 0.f;

  if (tid < 64) Lred[tid] = 0.f;

  const int t0s = (s0 >> 7) << 7;
  const int ntl = (Tn - t0s) >> 7;

  auto stageQ = [&](int buf, int tg0){
#pragma unroll
    for (int i = 0; i < 4; i++){
      int row = (w*4 + i)*8 + r8;
      gl16(Qb + (bh*Tn + tg0 + row)*HSn + ((c7 ^ (row & 7))*8), &Qs[buf][(w*4 + i)*512]);
    }
  };

  // reverse stream: tile index tl = ntl-1-j
  stageQ(0, t0s + (ntl-1)*128);
  if (ntl > 1) stageQ(1, t0s + (ntl-2)*128);

  for (int j = 0; j < ntl; j++){
    if (j + 1 < ntl){ WAITV(4); } else { WAITV(0); }
    FENCE(); SBAR(); FENCE();
    if (j + 2 < ntl) stageQ((j + 2) % 3, t0s + (ntl-3-j)*128);

    const int cur = j % 3;
    const int t0 = t0s + (ntl-1-j)*128;
    const int tw = t0 + 32*w;
    if (tw + 31 >= s0){
      f32x16 st[2];
#pragma unroll
      for (int sf = 0; sf < 2; sf++)
#pragma unroll
        for (int r = 0; r < 16; r++) st[sf][r] = 0.f;
      const int qrow = w*32 + l31;
      const unsigned short* Qc = &Qs[cur][qrow*64];
      const int sw = qrow & 7;
      __builtin_amdgcn_s_setprio(1);
#pragma unroll
      for (int ks = 0; ks < 4; ks++){
        short8 qb = *(const short8*)&Qc[((l5 + 2*ks) ^ sw)*8];
        st[0] = mfma32(kf[0][ks], qb, st[0]);
        st[1] = mfma32(kf[1][ks], qb, st[1]);
      }
      __builtin_amdgcn_s_setprio(0);
      const int tg = tw + l31;
      if (s0 + 63 <= tw){
#pragma unroll
        for (int sf = 0; sf < 2; sf++)
#pragma unroll
          for (int r = 0; r < 16; r++)
            ls[sf][r] += __builtin_amdgcn_exp2f(st[sf][r]);
      } else {
#pragma unroll
        for (int sf = 0; sf < 2; sf++)
#pragma unroll
          for (int r = 0; r < 16; r++){
            int sg = s0 + 32*sf + (r & 3) + 8*(r >> 2) + 4*l5;
            float e = __builtin_amdgcn_exp2f(st[sf][r]);
            ls[sf][r] += (tg >= sg) ? e : 0.f;
          }
      }
    }
  }

#pragma unroll
  for (int sf = 0; sf < 2; sf++)
#pragma unroll
    for (int r = 0; r < 16; r++){
      float v = ls[sf][r];
      v += __shfl_xor(v, 1);  v += __shfl_xor(v, 2);
      v += __shfl_xor(v, 4);  v += __shfl_xor(v, 8);
      v += __shfl_xor(v, 16);
      ls[sf][r] = v;
    }
  if (l31 == 0){
#pragma unroll
    for (int sf = 0; sf < 2; sf++)
#pragma unroll
      for (int r = 0; r < 16; r++){
        int sl = 32*sf + (r & 3) + 8*(r >> 2) + 4*l5;
        atomicAdd(&Lred[sl], ls[sf][r]);
      }
  }
  __syncthreads();
  if (tid < 64) Linv[bh*Tn + s0 + tid] = 1.0f / Lred[tid];

  // fused V-scale: this block owns columns [s0, s0+64) of Vt for this bh
  {
    const int d = tid >> 2, cq = (tid & 3)*16;
    unsigned short* vp = Vt + ((size_t)(bh*HSn + d))*Tn + s0 + cq;
    short8 v0 = *(const short8*)vp;
    short8 v1 = *(const short8*)(vp + 8);
    float inv[16];
#pragma unroll
    for (int j = 0; j < 16; j++) inv[j] = 1.0f / Lred[cq + j];
    uint4w o0, o1;
    o0[0] = cvtpk(b2f((unsigned short)v0[0])*inv[0],  b2f((unsigned short)v0[1])*inv[1]);
    o0[1] = cvtpk(b2f((unsigned short)v0[2])*inv[2],  b2f((unsigned short)v0[3])*inv[3]);
    o0[2] = cvtpk(b2f((unsigned short)v0[4])*inv[4],  b2f((unsigned short)v0[5])*inv[5]);
    o0[3] = cvtpk(b2f((unsigned short)v0[6])*inv[6],  b2f((unsigned short)v0[7])*inv[7]);
    o1[0] = cvtpk(b2f((unsigned short)v1[0])*inv[8],  b2f((unsigned short)v1[1])*inv[9]);
    o1[1] = cvtpk(b2f((unsigned short)v1[2])*inv[10], b2f((unsigned short)v1[3])*inv[11]);
    o1[2] = cvtpk(b2f((unsigned short)v1[4])*inv[12], b2f((unsigned short)v1[5])*inv[13]);
    o1[3] = cvtpk(b2f((unsigned short)v1[6])*inv[14], b2f((unsigned short)v1[7])*inv[15]);
    *(uint4w*)vp       = o0;
    *(uint4w*)(vp + 8) = o1;
  }
}

// ---------------- kernel 3: attention output (XCD-grouped, 3-buffer) ---------
// grid (8, 128): bh = x*8 + (y&7) -> one XCD per bh (K+V set = 8 x 512KB = 4MB
// per XCD); forward s-streaming is prefix-aligned across that bh's blocks.
__global__ void __launch_bounds__(256, 3)
k_attn(const unsigned short* __restrict__ Qb,
       const unsigned short* __restrict__ Kb,
       const unsigned short* __restrict__ Vlt,
       unsigned short* __restrict__ Att)
{
  __shared__ unsigned short Ks[3][64*64];   // 24KB
  __shared__ unsigned short Vs[3][64*64];   // 24KB
  const int bh = blockIdx.x*8 + (blockIdx.y & 7);
  const int tb = 15 - (blockIdx.y >> 3);    // heavy blocks dispatch first
  const int t0 = tb * 128;
  const int tid = threadIdx.x, lane = tid & 63, w = tid >> 6;
  const int l5 = lane >> 5, l31 = lane & 31;
  const int c7 = lane & 7, r8 = lane >> 3;
  const int tbase = t0 + w*32;
  const int nt = 2*tb + 2;

  short8 qf[4];
  {
    const unsigned short* qr = Qb + (bh*Tn + tbase + l31)*HSn + 8*l5;
#pragma unroll
    for (int ks = 0; ks < 4; ks++) qf[ks] = *(const short8*)(qr + 16*ks);
  }

  f32x16 oacc[2];
#pragma unroll
  for (int df = 0; df < 2; df++)
#pragma unroll
    for (int r = 0; r < 16; r++) oacc[df][r] = 0.f;

  auto stageKV = [&](int buf, int sn){
#pragma unroll
    for (int i = 0; i < 2; i++){
      int row = (w*2 + i)*8 + r8;
      gl16(Kb  + (bh*Tn + sn + row)*HSn + ((c7 ^ (row & 7))*8), &Ks[buf][(w*2 + i)*512]);
      gl16(Vlt + (bh*HSn + row)*Tn + sn + ((c7 ^ (row & 7))*8), &Vs[buf][(w*2 + i)*512]);
    }
  };

  stageKV(0, 0);
  if (nt > 1) stageKV(1, 64);

  for (int it = 0; it < nt; it++){
    if (it + 1 < nt){ WAITV(4); } else { WAITV(0); }
    FENCE(); SBAR(); FENCE();
    if (it + 2 < nt) stageKV((it + 2) % 3, (it + 2)*64);

    const int cur = it % 3;
    const int s0 = it * 64;
    if (s0 <= tbase + 31){
      const unsigned short* Kc = &Ks[cur][0];
      f32x16 st[2];
#pragma unroll
      for (int sf = 0; sf < 2; sf++)
#pragma unroll
        for (int r = 0; r < 16; r++) st[sf][r] = 0.f;
      __builtin_amdgcn_s_setprio(1);
#pragma unroll
      for (int ks = 0; ks < 4; ks++){
#pragma unroll
        for (int sf = 0; sf < 2; sf++){
          int row = sf*32 + l31;
          short8 ka = *(const short8*)&Kc[row*64 + (((l5 + 2*ks) ^ (row & 7))*8)];
          st[sf] = mfma32(ka, qf[ks], st[sf]);
        }
      }
      __builtin_amdgcn_s_setprio(0);

      const int tg = tbase + l31;
      const bool interior = (s0 + 63 <= tbase);
#pragma unroll
      for (int sf = 0; sf < 2; sf++){
#pragma unroll
        for (int r = 0; r < 16; r++){
          float e = __builtin_amdgcn_exp2f(st[sf][r]);
          if (!interior){
            int sg = s0 + 32*sf + (r & 3) + 8*(r >> 2) + 4*l5;
            e = (tg >= sg) ? e : 0.f;
          }
          st[sf][r] = e;
        }
      }

      short8 pb[4];
#pragma unroll
      for (int sf = 0; sf < 2; sf++){
#pragma unroll
        for (int q = 0; q < 2; q++){
          unsigned int ax = cvtpk(st[sf][8*q+0], st[sf][8*q+1]);
          unsigned int ay = cvtpk(st[sf][8*q+2], st[sf][8*q+3]);
          unsigned int bx = cvtpk(st[sf][8*q+4], st[sf][8*q+5]);
          unsigned int by = cvtpk(st[sf][8*q+6], st[sf][8*q+7]);
          asm("v_permlane32_swap_b32 %0, %1" : "+v"(ax), "+v"(bx));
          asm("v_permlane32_swap_b32 %0, %1" : "+v"(ay), "+v"(by));
          union { unsigned int u[4]; short8 s; } pk;
          pk.u[0] = ax; pk.u[1] = ay; pk.u[2] = bx; pk.u[3] = by;
          pb[sf*2 + q] = pk.s;
        }
      }

      const unsigned short* Vc = &Vs[cur][0];
      __builtin_amdgcn_s_setprio(1);
#pragma unroll
      for (int ks = 0; ks < 4; ks++){
#pragma unroll
        for (int df = 0; df < 2; df++){
          int row = df*32 + l31;
          short8 va = *(const short8*)&Vc[row*64 + (((l5 + 2*ks) ^ (row & 7))*8)];
          oacc[df] = mfma32(va, pb[ks], oacc[df]);
        }
      }
      __builtin_amdgcn_s_setprio(0);
    }
  }

  {
    const int tg = tbase + l31;
    unsigned short* ob = Att + (bh*Tn + tg)*HSn;
#pragma unroll
    for (int df = 0; df < 2; df++)
#pragma unroll
      for (int r2 = 0; r2 < 4; r2++){
        uint2 u;
        u.x = cvtpk(oacc[df][r2*4+0], oacc[df][r2*4+1]);
        u.y = cvtpk(oacc[df][r2*4+2], oacc[df][r2*4+3]);
        *(uint2*)&ob[32*df + 8*r2 + 4*l5] = u;
      }
  }
}

// ---------------- kernel 4: output projection (depth-2 counted-vmcnt) --------
__global__ void __launch_bounds__(256, 2)
k_oproj(const unsigned short* __restrict__ Att,
        const unsigned short* __restrict__ Wot,
        const float* __restrict__ bo, float* __restrict__ out)
{
  __shared__ unsigned short As[2][128*64];
  __shared__ unsigned short Bs[2][128*64];
  const int tid = threadIdx.x, lane = tid & 63, w = tid >> 6;
  const int wr = w >> 1, wc = w & 1;
  const int mb = blockIdx.x, nb = blockIdx.y;
  const int n0 = nb*128;
  const int l15 = lane & 15, kc = lane >> 4;
  const int r8 = lane >> 3, c7 = lane & 7;
  const int bb = mb >> 4;
  const int t0 = (mb*128) & 2047;

  f32x4 acc[4][4];
#pragma unroll
  for (int i = 0; i < 4; i++)
#pragma unroll
    for (int j = 0; j < 4; j++) acc[i][j] = (f32x4){0.f,0.f,0.f,0.f};

  const unsigned short* wbase = Wot + n0*En;

  auto stage = [&](int buf, int k0){
    const int hh = k0 >> 6;
    const unsigned short* abase = Att + ((bb*Hn + hh)*Tn + t0)*HSn;
#pragma unroll
    for (int i = 0; i < 4; i++){
      const int rb = w*32 + i*8;
      const int r = rb + r8;
      const int g = (c7 ^ r8) * 8;
      gl16(abase + r*HSn + g, &As[buf][rb*64]);
      gl16(wbase + r*En + k0 + g, &Bs[buf][rb*64]);
    }
  };
  auto compute = [&](int cur){
    const unsigned short* Ac = &As[cur][0];
    const unsigned short* Bc = &Bs[cur][0];
#pragma unroll
    for (int ks = 0; ks < 2; ks++){
      short8 af[4], bf[4];
#pragma unroll
      for (int mf = 0; mf < 4; mf++){
        int ar = wr*64 + mf*16 + l15;
        af[mf] = *(const short8*)&Ac[ar*64 + (((ks*4 + kc) ^ (ar & 7))*8)];
      }
#pragma unroll
      for (int nf = 0; nf < 4; nf++){
        int br = wc*64 + nf*16 + l15;
        bf[nf] = *(const short8*)&Bc[br*64 + (((ks*4 + kc) ^ (br & 7))*8)];
      }
      __builtin_amdgcn_s_setprio(1);
#pragma unroll
      for (int mf = 0; mf < 4; mf++)
#pragma unroll
        for (int nf = 0; nf < 4; nf++)
          acc[mf][nf] = mfma16(af[mf], bf[nf], acc[mf][nf]);
      __builtin_amdgcn_s_setprio(0);
    }
  };

  stage(0, 0);
  stage(1, 64);
  WAITV(8); SBAR();

  for (int kt = 0; kt < 16; kt++){
    const int cur = kt & 1;
    compute(cur);
    FENCE(); SBAR();
    if (kt < 14){
      stage(cur, (kt + 2)*64);
      WAITV(8); SBAR();
    } else if (kt == 14){
      WAITV(0); SBAR();
    }
  }

  const int q4 = (lane >> 4)*4;
#pragma unroll
  for (int nf = 0; nf < 4; nf++){
    int j = n0 + wc*64 + nf*16 + l15;
    float bias = bo[j];
#pragma unroll
    for (int mf = 0; mf < 4; mf++){
#pragma unroll
      for (int q = 0; q < 4; q++){
        int rr = mb*128 + wr*64 + mf*16 + q4 + q;
        out[rr*En + j] = acc[mf][nf][q] + bias;
      }
    }
  }
}

extern "C" void kernel_launch(void* const* d_in, const int* in_sizes, int n_in,
                              void* d_out, int out_size, void* d_ws, size_t ws_size,
                              hipStream_t stream)
{
  (void)in_sizes; (void)n_in; (void)out_size; (void)ws_size;
  const float* x  = (const float*)d_in[0];
  const float* Wq = (const float*)d_in[1];
  const float* Wk = (const float*)d_in[2];
  const float* Wv = (const float*)d_in[3];
  const float* Wo = (const float*)d_in[4];
  const float* bo = (const float*)d_in[5];
  float* out = (float*)d_out;

  // ws layout (MB): Qb[0,16) Kb[16,32) Vt[32,48) xb/Att[48,64) Wt[64,70) Wot[70,72) Linv[72,72.5)
  uint8_t* w = (uint8_t*)d_ws;
  unsigned short* Qb  = (unsigned short*)(w);
  unsigned short* Kb  = (unsigned short*)(w + (16u << 20));
  unsigned short* Vt  = (unsigned short*)(w + (32u << 20));
  unsigned short* xb  = (unsigned short*)(w + (48u << 20));
  unsigned short* Att = (unsigned short*)(w + (48u << 20));
  unsigned short* Wt  = (unsigned short*)(w + (64u << 20));
  unsigned short* Wot = (unsigned short*)(w + (70u << 20));
  float* Linv         = (float*)(w + (72u << 20));

  hipLaunchKernelGGL(k_cvt_x,  dim3(4096),    dim3(256), 0, stream, x, xb);
  hipLaunchKernelGGL(k_wT,     dim3(16, 64),  dim3(256), 0, stream, Wq, Wk, Wv, Wo, Wt, Wot);
  hipLaunchKernelGGL(k_qkv,    dim3(64, 24),  dim3(256), 0, stream, xb, Wt, Qb, Kb, Vt);
  hipLaunchKernelGGL(k_colsum, dim3(8, 256),  dim3(256), 0, stream, Qb, Kb, Vt, Linv);
  hipLaunchKernelGGL(k_attn,   dim3(8, 128),  dim3(256), 0, stream, Qb, Kb, Vt, Att);
  hipLaunchKernelGGL(k_oproj,  dim3(64, 8),   dim3(256), 0, stream, Att, Wot, bo, out);
}